// Round 11
// baseline (277.096 us; speedup 1.0000x reference)
//
#include <hip/hip_runtime.h>
#include <math.h>

#define NSLOPE 0.2f

typedef unsigned short ushort_t;
typedef __attribute__((ext_vector_type(8))) short bf16x8;
typedef __attribute__((ext_vector_type(8))) unsigned short ushort8;
typedef __attribute__((ext_vector_type(4))) float f32x4;

__device__ __forceinline__ float elu1(float x) { return x > 0.f ? x : expm1f(x); }

__device__ __forceinline__ ushort_t f2bf(float f) {
  union { float f; unsigned int u; } v; v.f = f;
  unsigned int r = v.u + 0x7fffu + ((v.u >> 16) & 1u);
  return (ushort_t)(r >> 16);
}
__device__ __forceinline__ float bf2f(ushort_t u) {
  union { unsigned int i; float f; } v; v.i = ((unsigned int)u) << 16; return v.f;
}

// ================= device bodies =================

__device__ void dev_build_w(int idx,
                            const float* __restrict__ W1in, const float* __restrict__ W1out,
                            const float* __restrict__ W2in, const float* __restrict__ W2out,
                            const float* __restrict__ Went,
                            ushort_t* __restrict__ wcat1, ushort_t* __restrict__ wcat2,
                            ushort_t* __restrict__ wentb) {
  const int S1 = 832 * 128, S2 = 832 * 256, S3 = 256 * 128;
  if (idx < S1) {
    int ro = idx >> 7, k = idx & 127;
    float val = 0.f;
    if (ro < 800 && k < 100) {
      int o = ro / 200, cc = ro - o * 200;
      const float* W = (o < 2) ? W1in : W1out;
      val = W[(size_t)cc * 300 + (o & 1) * 100 + k];
    }
    wcat1[idx] = f2bf(val);
  } else if (idx < S1 + S2) {
    int i2 = idx - S1;
    int ro = i2 >> 8, k = i2 & 255;
    float val = 0.f;
    if (ro < 800 && k < 200) {
      int o = ro / 200, cc = ro - o * 200;
      const float* W = (o < 2) ? W2in : W2out;
      val = W[(size_t)cc * 500 + (o & 1) * 200 + k];
    }
    wcat2[i2] = f2bf(val);
  } else if (idx < S1 + S2 + S3) {
    int i3 = idx - S1 - S2;
    int ro = i3 >> 7, k = i3 & 127;
    float val = (ro < 200 && k < 100) ? Went[ro * 100 + k] : 0.f;
    wentb[i3] = f2bf(val);
  }
}

__device__ void dev_makeu(int idx,
                          const float* __restrict__ W1in, const float* __restrict__ a1in,
                          const float* __restrict__ W1out, const float* __restrict__ a1out,
                          const float* __restrict__ W2in, const float* __restrict__ a2in,
                          const float* __restrict__ W2out, const float* __restrict__ a2out,
                          float* __restrict__ u1in, float* __restrict__ u1out,
                          float* __restrict__ u2in, float* __restrict__ u2out) {
  if (idx >= 3200) return;
  const float* W; const float* avec; float* u; int Kp, local;
  if (idx < 600)       { W = W1in;  avec = a1in;  u = u1in;  Kp = 300; local = idx; }
  else if (idx < 1200) { W = W1out; avec = a1out; u = u1out; Kp = 300; local = idx - 600; }
  else if (idx < 2200) { W = W2in;  avec = a2in;  u = u2in;  Kp = 500; local = idx - 1200; }
  else                 { W = W2out; avec = a2out; u = u2out; Kp = 500; local = idx - 2200; }
  int h = local / Kp, kp = local - h * Kp;
  const float* Wb = W + (size_t)(h * 100) * Kp + kp;
  const float* ab = avec + h * 100;
  float s = 0.f;
  for (int k = 0; k < 100; ++k) s += ab[k] * Wb[(size_t)k * Kp];
  u[local] = s;
}

__device__ void dev_l2norm_q(int bb, int tid, const float* __restrict__ x,
                             ushort_t* __restrict__ xnb,
                             const float* __restrict__ u1in, const float* __restrict__ u1out,
                             float* __restrict__ qA, float* __restrict__ qB,
                             float* __restrict__ qC, float* __restrict__ qD, int N) {
  int wid = bb * 4 + (tid >> 6);
  int lane = tid & 63;
  if (wid >= N) return;
  const float* p = x + (size_t)wid * 100;
  float v0 = p[lane];
  bool t2 = lane < 36;
  float v1 = t2 ? p[lane + 64] : 0.f;
  float ss = v0 * v0 + v1 * v1;
#pragma unroll
  for (int m = 1; m < 64; m <<= 1) ss += __shfl_xor(ss, m, 64);
  float inv = 1.f / fmaxf(sqrtf(ss), 1e-12f);
  float a0 = v0 * inv, a1 = v1 * inv;
  ushort_t* ob = xnb + (size_t)wid * 128;
  ob[lane] = f2bf(a0);
  ob[64 + lane] = t2 ? f2bf(a1) : (ushort_t)0;
  int k0 = lane, k1 = 64 + lane;
  float s[8];
  s[0] = a0 * u1in[k0]        + (t2 ? a1 * u1in[k1]        : 0.f);
  s[1] = a0 * u1in[300 + k0]  + (t2 ? a1 * u1in[300 + k1]  : 0.f);
  s[2] = a0 * u1in[100 + k0]  + (t2 ? a1 * u1in[100 + k1]  : 0.f);
  s[3] = a0 * u1in[400 + k0]  + (t2 ? a1 * u1in[400 + k1]  : 0.f);
  s[4] = a0 * u1out[k0]       + (t2 ? a1 * u1out[k1]       : 0.f);
  s[5] = a0 * u1out[300 + k0] + (t2 ? a1 * u1out[300 + k1] : 0.f);
  s[6] = a0 * u1out[100 + k0] + (t2 ? a1 * u1out[100 + k1] : 0.f);
  s[7] = a0 * u1out[400 + k0] + (t2 ? a1 * u1out[400 + k1] : 0.f);
#pragma unroll
  for (int m = 1; m < 64; m <<= 1) {
#pragma unroll
    for (int i = 0; i < 8; ++i) s[i] += __shfl_xor(s[i], m, 64);
  }
  if (lane == 0) {
    qA[wid * 2] = s[0]; qA[wid * 2 + 1] = s[1];
    qB[wid * 2] = s[2]; qB[wid * 2 + 1] = s[3];
    qC[wid * 2] = s[4]; qC[wid * 2 + 1] = s[5];
    qD[wid * 2] = s[6]; qD[wid * 2 + 1] = s[7];
  }
}

__device__ void dev_qrel2(int bb, int tid, const float* __restrict__ g,
                          const float* __restrict__ u1in, const float* __restrict__ u1out,
                          const float* __restrict__ u2in, const float* __restrict__ u2out,
                          float* __restrict__ q3i1, float* __restrict__ q3o1,
                          float* __restrict__ q3i2, float* __restrict__ q3o2, int Mn) {
  int wid = bb * 4 + (tid >> 6);
  int lane = tid & 63;
  if (wid >= 2 * Mn) return;
  int lay = wid >= Mn;
  int m = wid - lay * Mn;
  const float* uin  = lay ? u2in  : u1in;
  const float* uout = lay ? u2out : u1out;
  int Kp = lay ? 500 : 300;
  int off3 = lay ? 400 : 200;
  float* q3i = lay ? q3i2 : q3i1;
  float* q3o = lay ? q3o2 : q3o1;
  const float* a = g + (size_t)m * 100;
  float s[4] = {0.f, 0.f, 0.f, 0.f};
  for (int k = lane; k < 100; k += 64) {
    float av = a[k];
    s[0] += av * uin[off3 + k];
    s[1] += av * uin[Kp + off3 + k];
    s[2] += av * uout[off3 + k];
    s[3] += av * uout[Kp + off3 + k];
  }
#pragma unroll
  for (int mm = 1; mm < 64; mm <<= 1) {
#pragma unroll
    for (int i = 0; i < 4; ++i) s[i] += __shfl_xor(s[i], mm, 64);
  }
  if (lane == 0) {
    q3i[m * 2] = s[0]; q3i[m * 2 + 1] = s[1];
    q3o[m * 2] = s[2]; q3o[m * 2 + 1] = s[3];
  }
}

__device__ void dev_count(int bb, int tid, const int* __restrict__ row,
                          const int* __restrict__ col,
                          int* __restrict__ cntIn, int* __restrict__ cntOut, int E) {
  int e = bb * 256 + tid;
  if (e >= E) return;
  atomicAdd(&cntIn[col[e]], 1);
  atomicAdd(&cntOut[row[e]], 1);
}

__device__ void dev_edge_e(int bb, int tid,
                           const int* __restrict__ row, const int* __restrict__ col,
                           const int* __restrict__ ety,
                           const float* __restrict__ qA, const float* __restrict__ qB,
                           const float* __restrict__ q3i,
                           const float* __restrict__ qC, const float* __restrict__ qD,
                           const float* __restrict__ q3o,
                           const int* __restrict__ invIn, const int* __restrict__ invOut,
                           float2* __restrict__ eIc, float2* __restrict__ eOc, int E) {
  int e = bb * 256 + tid;
  if (e >= E) return;
  int r = row[e], c = col[e], t = ety[e];
  float2 vA = *(const float2*)(qA + (size_t)r * 2);
  float2 vB = *(const float2*)(qB + (size_t)c * 2);
  float2 v3 = *(const float2*)(q3i + (size_t)t * 2);
  float2 vC = *(const float2*)(qC + (size_t)r * 2);
  float2 vD = *(const float2*)(qD + (size_t)c * 2);
  float2 v4 = *(const float2*)(q3o + (size_t)t * 2);
  float a0 = vA.x + vB.x + v3.x, a1 = vA.y + vB.y + v3.y;
  float b0 = vC.x + vD.x + v4.x, b1 = vC.y + vD.y + v4.y;
  float2 rI, rO;
  rI.x = expf(-(a0 > 0.f ? a0 : NSLOPE * a0));
  rI.y = expf(-(a1 > 0.f ? a1 : NSLOPE * a1));
  rO.x = expf(-(b0 > 0.f ? b0 : NSLOPE * b0));
  rO.y = expf(-(b1 > 0.f ? b1 : NSLOPE * b1));
  eIc[invIn[e]] = rI;
  eOc[invOut[e]] = rO;
}

// 128x128 MFMA GEMM tile; 4 waves each owning a 64x64 quadrant (4x4 of 16x16x32).
__device__ void dev_mfma128(int bx, int by, int tid,
                            ushort_t* __restrict__ smA, ushort_t* __restrict__ smB,
                            const ushort_t* __restrict__ Ab, int lda,
                            const ushort_t* __restrict__ Bb, int Kpad, int Brows,
                            int R, int NC, int OUTW, const float* __restrict__ bias,
                            float* __restrict__ C0,
                            ushort_t* __restrict__ Bd0, ushort_t* __restrict__ Bd1,
                            ushort_t* __restrict__ Bd2, ushort_t* __restrict__ Bd3) {
  const int lane = tid & 63;
  const int w = tid >> 6;
  const int wm = w >> 1, wn = w & 1;
  const int m0 = by * 128, n0 = bx * 128;
  const int srow = tid >> 1;          // 128 rows, 2 threads/row
  const int sq4 = (tid & 1) * 4;      // starting 8-elem slot (0 or 4)
  const int sw = srow & 7;
  const bool aok = (m0 + srow) < R;
  const bool bok = (n0 + srow) < Brows;
  const ushort_t* Ag = Ab + (size_t)(m0 + srow) * lda + sq4 * 8;
  const ushort_t* Bg = Bb + (size_t)(n0 + srow) * Kpad + sq4 * 8;
  const int hi = lane >> 4;
  f32x4 acc[4][4] = {};
  for (int k0 = 0; k0 < Kpad; k0 += 64) {
    ushort8 z = {0, 0, 0, 0, 0, 0, 0, 0};
    ushort8 a[4], b[4];
#pragma unroll
    for (int j2 = 0; j2 < 4; ++j2) {
      a[j2] = z; b[j2] = z;
      if (aok) a[j2] = *(const ushort8*)(Ag + k0 + j2 * 8);
      if (bok) b[j2] = *(const ushort8*)(Bg + k0 + j2 * 8);
    }
    __syncthreads();
#pragma unroll
    for (int j2 = 0; j2 < 4; ++j2) {
      int so = srow * 64 + (((sq4 + j2) ^ sw) << 3);
      *(ushort8*)(smA + so) = a[j2];
      *(ushort8*)(smB + so) = b[j2];
    }
    __syncthreads();
#pragma unroll
    for (int ks = 0; ks < 2; ++ks) {
      bf16x8 aF[4], bF[4];
#pragma unroll
      for (int f = 0; f < 4; ++f) {
        int rowA = wm * 64 + f * 16 + (lane & 15);
        aF[f] = *(const bf16x8*)(smA + rowA * 64 + ((((ks << 2) + hi) ^ (rowA & 7)) << 3));
        int rowB = wn * 64 + f * 16 + (lane & 15);
        bF[f] = *(const bf16x8*)(smB + rowB * 64 + ((((ks << 2) + hi) ^ (rowB & 7)) << 3));
      }
#pragma unroll
      for (int fr = 0; fr < 4; ++fr)
#pragma unroll
        for (int fc = 0; fc < 4; ++fc)
          acc[fr][fc] = __builtin_amdgcn_mfma_f32_16x16x32_bf16(aF[fr], bF[fc], acc[fr][fc], 0, 0, 0);
    }
  }
  ushort_t* Bds[4] = {Bd0, Bd1, Bd2, Bd3};
#pragma unroll
  for (int fr = 0; fr < 4; ++fr) {
    int rr0 = m0 + wm * 64 + fr * 16 + (lane >> 4) * 4;
#pragma unroll
    for (int fc = 0; fc < 4; ++fc) {
      int cc = n0 + wn * 64 + fc * 16 + (lane & 15);
      if (cc < NC) {
        int o = cc / OUTW;
        int c2 = cc - o * OUTW;
        float bv = bias ? bias[c2] : 0.f;
        ushort_t* Bd = Bds[o];
        if (Bd) {
#pragma unroll
          for (int reg = 0; reg < 4; ++reg) {
            int r = rr0 + reg;
            if (r < R) Bd[(size_t)r * OUTW + c2] = f2bf(acc[fr][fc][reg] + bv);
          }
        } else {
#pragma unroll
          for (int reg = 0; reg < 4; ++reg) {
            int r = rr0 + reg;
            if (r < R) C0[(size_t)r * OUTW + c2] = acc[fr][fc][reg] + bv;
          }
        }
      }
    }
  }
}

template <int NOUT, int BF>
__device__ void dev_gemm_multi(int bx, int by, int tid, float4 (*As)[25],
                               const float* __restrict__ A, int lda,
                               const float* __restrict__ W0, const float* __restrict__ W1,
                               int ldw,
                               const float* __restrict__ b0, const float* __restrict__ b1,
                               void* __restrict__ C0v, void* __restrict__ C1v, int R) {
  const int K4 = 25;
  int row0 = by * 32;
  {
    int r = tid >> 3;
    int rr = row0 + r;
    const float4* Ar = (const float4*)(A + (size_t)rr * lda);
    for (int k4 = (tid & 7); k4 < K4; k4 += 8)
      As[r][k4] = (rr < R) ? Ar[k4] : make_float4(0.f, 0.f, 0.f, 0.f);
  }
  __syncthreads();
  int c = bx * 64 + (tid & 63);
  if (c < 200) {
    int rb = (tid >> 6) << 3;
    const float4* Wr[NOUT];
    Wr[0] = (const float4*)(W0 + (size_t)c * ldw);
    if (NOUT > 1) Wr[1] = (const float4*)(W1 + (size_t)c * ldw);
    float acc[NOUT][8];
#pragma unroll
    for (int o = 0; o < NOUT; ++o)
#pragma unroll
      for (int i = 0; i < 8; ++i) acc[o][i] = 0.f;
#pragma unroll 2
    for (int k4 = 0; k4 < K4; ++k4) {
      float4 a[8];
#pragma unroll
      for (int i = 0; i < 8; ++i) a[i] = As[rb + i][k4];
#pragma unroll
      for (int o = 0; o < NOUT; ++o) {
        float4 wv = Wr[o][k4];
#pragma unroll
        for (int i = 0; i < 8; ++i)
          acc[o][i] += a[i].x * wv.x + a[i].y * wv.y + a[i].z * wv.z + a[i].w * wv.w;
      }
    }
    float bv[NOUT];
    bv[0] = b0 ? b0[c] : 0.f;
    if (NOUT > 1) bv[1] = b1 ? b1[c] : 0.f;
    void* Cp[NOUT];
    Cp[0] = C0v;
    if (NOUT > 1) Cp[1] = C1v;
#pragma unroll
    for (int i = 0; i < 8; ++i) {
      int rr = row0 + rb + i;
      if (rr < R) {
#pragma unroll
        for (int o = 0; o < NOUT; ++o) {
          float val = acc[o][i] + bv[o];
          if (BF) ((ushort_t*)Cp[o])[(size_t)rr * 200 + c] = f2bf(val);
          else    ((float*)Cp[o])[(size_t)rr * 200 + c] = val;
        }
      }
    }
  }
}

// ================= kernels =================

__global__ __launch_bounds__(256) void MEGA0(
    const float* W1in, const float* W1out, const float* W2in, const float* W2out,
    const float* Went,
    ushort_t* wcat1, ushort_t* wcat2, ushort_t* wentb,
    const float* a1in, const float* a1out, const float* a2in, const float* a2out,
    float* u1in, float* u1out, float* u2in, float* u2out,
    int* cntIn, int* cntOut, int N, int nb_bw, int nb_mk) {
  int b = blockIdx.x, tid = threadIdx.x;
  if (b < nb_bw) {
    dev_build_w(b * 256 + tid, W1in, W1out, W2in, W2out, Went, wcat1, wcat2, wentb);
  } else if (b < nb_bw + nb_mk) {
    dev_makeu((b - nb_bw) * 256 + tid, W1in, a1in, W1out, a1out, W2in, a2in, W2out, a2out,
              u1in, u1out, u2in, u2out);
  } else {
    int idx = (b - nb_bw - nb_mk) * 256 + tid;
    if (idx < N) cntIn[idx] = 0;
    else if (idx < 2 * N) cntOut[idx - N] = 0;
  }
}

__global__ __launch_bounds__(256) void MEGA1(
    const float* x, ushort_t* xnb, const float* u1in, const float* u1out,
    float* qA, float* qB, float* qC, float* qD, int N,
    const float* g, const float* u2in, const float* u2out,
    float* q3i1, float* q3o1, float* q3i2, float* q3o2, int Mn,
    const int* row, const int* col, int* cntIn, int* cntOut, int E,
    int nb_l2, int nb_qr) {
  int b = blockIdx.x, tid = threadIdx.x;
  if (b < nb_l2) {
    dev_l2norm_q(b, tid, x, xnb, u1in, u1out, qA, qB, qC, qD, N);
  } else if (b < nb_l2 + nb_qr) {
    dev_qrel2(b - nb_l2, tid, g, u1in, u1out, u2in, u2out, q3i1, q3o1, q3i2, q3o2, Mn);
  } else {
    dev_count(b - nb_l2 - nb_qr, tid, row, col, cntIn, cntOut, E);
  }
}

// ---- parallel 3-phase scan ----
__global__ __launch_bounds__(256) void k_scanA(const int* __restrict__ cntIn,
                                               const int* __restrict__ cntOut,
                                               int* __restrict__ part, int N, int nbc) {
  __shared__ int wsum[4];
  int b = blockIdx.x;
  const int* cnt = (b < nbc) ? cntIn : cntOut;
  int cb = (b < nbc) ? b : b - nbc;
  int idx = cb * 256 + threadIdx.x;
  int v = (idx < N) ? cnt[idx] : 0;
#pragma unroll
  for (int m = 1; m < 64; m <<= 1) v += __shfl_xor(v, m, 64);
  if ((threadIdx.x & 63) == 0) wsum[threadIdx.x >> 6] = v;
  __syncthreads();
  if (threadIdx.x == 0) part[b] = wsum[0] + wsum[1] + wsum[2] + wsum[3];
}

__global__ __launch_bounds__(256) void k_scanB(int* __restrict__ part,
                                               int* __restrict__ rsIn, int* __restrict__ rsOut,
                                               int nbc, int N) {
  __shared__ int buf[512];
  int t = threadIdx.x;
  buf[t]       = (t < nbc) ? part[t] : 0;
  buf[256 + t] = (t < nbc) ? part[nbc + t] : 0;
  __syncthreads();
  for (int off = 1; off < 256; off <<= 1) {
    int v0 = (t >= off) ? buf[t - off] : 0;
    int v1 = (t >= off) ? buf[256 + t - off] : 0;
    __syncthreads();
    buf[t] += v0; buf[256 + t] += v1;
    __syncthreads();
  }
  if (t < nbc) {
    part[t]       = (t == 0) ? 0 : buf[t - 1];
    part[nbc + t] = (t == 0) ? 0 : buf[256 + t - 1];
  }
  if (t == 0) { rsIn[N] = buf[nbc - 1]; rsOut[N] = buf[256 + nbc - 1]; }
}

__global__ __launch_bounds__(256) void k_scanC(const int* __restrict__ cntIn,
                                               const int* __restrict__ cntOut,
                                               const int* __restrict__ part,
                                               int* __restrict__ rsIn, int* __restrict__ rsOut,
                                               int* __restrict__ posIn, int* __restrict__ posOut,
                                               int N, int nbc) {
  __shared__ int buf[256];
  int b = blockIdx.x;
  const int* cnt = (b < nbc) ? cntIn : cntOut;
  int* rs  = (b < nbc) ? rsIn : rsOut;
  int* pos = (b < nbc) ? posIn : posOut;
  int cb = (b < nbc) ? b : b - nbc;
  int base = part[b];
  int t = threadIdx.x;
  int idx = cb * 256 + t;
  buf[t] = (idx < N) ? cnt[idx] : 0;
  __syncthreads();
  for (int off = 1; off < 256; off <<= 1) {
    int v = (t >= off) ? buf[t - off] : 0;
    __syncthreads();
    buf[t] += v;
    __syncthreads();
  }
  if (idx < N) {
    int excl = base + ((t == 0) ? 0 : buf[t - 1]);
    rs[idx] = excl; pos[idx] = excl;
  }
}

__global__ void k_fill(const int* __restrict__ row, const int* __restrict__ col,
                       const int* __restrict__ ety,
                       int* __restrict__ posIn, int* __restrict__ posOut,
                       int2* __restrict__ pinIn, int2* __restrict__ pinOut,
                       int* __restrict__ invIn, int* __restrict__ invOut, int E) {
  int e = blockIdx.x * blockDim.x + threadIdx.x;
  if (e >= E) return;
  int r = row[e], c = col[e], tt = ety[e];
  int p = atomicAdd(&posIn[c], 1);
  pinIn[p] = make_int2(r, tt);
  invIn[e] = p;
  int q = atomicAdd(&posOut[r], 1);
  pinOut[q] = make_int2(c, tt);
  invOut[e] = q;
}

__global__ __launch_bounds__(256) void MEGA2(
    const ushort_t* xnb, const ushort_t* wcat1,
    ushort_t* PAb, ushort_t* PBb, ushort_t* PCb, ushort_t* PDb, int N,
    const int* row, const int* col, const int* ety,
    const float* qA, const float* qB, const float* q3i1,
    const float* qC, const float* qD, const float* q3o1,
    const int* invIn, const int* invOut, float2* eIc, float2* eOc, int E,
    const float* g, const float* W1in200, const float* W1out200,
    const float* b1in, const float* b1out, ushort_t* P3ib, ushort_t* P3ob, int Mn,
    const ushort_t* wentb, const float* bent, float* hent,
    const float* Wrel, const float* brel, float* outg,
    int nb_mf, int nb_ee, int nb_gm, int nb_we) {
  __shared__ float4 shbuf4[2048];   // 32KB: smA|smB for mfma, aliased As for f32 gemm
  ushort_t* smA = (ushort_t*)shbuf4;
  ushort_t* smB = smA + 128 * 64;
  float4 (*As)[25] = (float4(*)[25])shbuf4;
  int b = blockIdx.x, tid = threadIdx.x;
  if (b < nb_mf) {
    dev_mfma128(b % 7, b / 7, tid, smA, smB, xnb, 128, wcat1, 128, 832, N, 800, 200,
                nullptr, nullptr, PAb, PBb, PCb, PDb);
  } else if ((b -= nb_mf) < nb_ee) {
    dev_edge_e(b, tid, row, col, ety, qA, qB, q3i1, qC, qD, q3o1,
               invIn, invOut, eIc, eOc, E);
  } else if ((b -= nb_ee) < nb_gm) {
    dev_gemm_multi<2, 1>(b & 3, b >> 2, tid, As, g, 100, W1in200, W1out200, 300,
                         b1in, b1out, P3ib, P3ob, Mn);
  } else if ((b -= nb_gm) < nb_we) {
    dev_mfma128(b & 1, b >> 1, tid, smA, smB, xnb, 128, wentb, 128, 256, N, 200, 200,
                bent, hent, nullptr, nullptr, nullptr, nullptr);
  } else {
    b -= nb_we;
    dev_gemm_multi<1, 0>(b & 3, b >> 2, tid, As, g, 100, Wrel, nullptr, 100,
                         brel, nullptr, outg, nullptr, Mn);
  }
}

__global__ __launch_bounds__(256) void MEGA3(
    const ushort_t* h1b, const ushort_t* wcat2,
    ushort_t* PAb, ushort_t* PBb, ushort_t* PCb, ushort_t* PDb, int N,
    const int* row, const int* col, const int* ety,
    const float* qA, const float* qB, const float* q3i2,
    const float* qC, const float* qD, const float* q3o2,
    const int* invIn, const int* invOut, float2* eIc, float2* eOc, int E,
    const float* g, const float* W2in400, const float* W2out400,
    const float* b2in, const float* b2out, ushort_t* P3ib, ushort_t* P3ob, int Mn,
    int nb_mf, int nb_ee) {
  __shared__ float4 shbuf4[2048];
  ushort_t* smA = (ushort_t*)shbuf4;
  ushort_t* smB = smA + 128 * 64;
  float4 (*As)[25] = (float4(*)[25])shbuf4;
  int b = blockIdx.x, tid = threadIdx.x;
  if (b < nb_mf) {
    dev_mfma128(b % 7, b / 7, tid, smA, smB, h1b, 256, wcat2, 256, 832, N, 800, 200,
                nullptr, nullptr, PAb, PBb, PCb, PDb);
  } else if ((b -= nb_mf) < nb_ee) {
    dev_edge_e(b, tid, row, col, ety, qA, qB, q3i2, qC, qD, q3o2,
               invIn, invOut, eIc, eOc, E);
  } else {
    b -= nb_ee;
    dev_gemm_multi<2, 1>(b & 3, b >> 2, tid, As, g, 100, W2in400, W2out400, 500,
                         b2in, b2out, P3ib, P3ob, Mn);
  }
}

// ---------------- fused per-node attention: single wave, interleaved dual-direction ----------------
__global__ void k_node_att(const int2* __restrict__ pinIn, const float2* __restrict__ eIc,
                           const int* __restrict__ rsIn,
                           const int2* __restrict__ pinOut, const float2* __restrict__ eOc,
                           const int* __restrict__ rsOut,
                           const ushort_t* __restrict__ PAb, const ushort_t* __restrict__ PBb,
                           const ushort_t* __restrict__ PCb, const ushort_t* __restrict__ PDb,
                           const ushort_t* __restrict__ P3ib, const ushort_t* __restrict__ P3ob,
                           const float* __restrict__ Wg, const float* __restrict__ bg,
                           const float* __restrict__ u2in, const float* __restrict__ u2out,
                           float* __restrict__ qA, float* __restrict__ qB,
                           float* __restrict__ qC, float* __restrict__ qD,
                           ushort_t* __restrict__ Hb,
                           const float* __restrict__ hent, float* __restrict__ outp, int N) {
  int wid  = (int)((blockIdx.x * (unsigned)blockDim.x + threadIdx.x) >> 6);
  int lane = threadIdx.x & 63;
  if (wid >= N) return;
  int n = wid;
  int half = lane >> 5, i = lane & 31;
  bool act = i < 25;
  int j = half * 100 + i * 4;
  int sIn = rsIn[n], degIn = rsIn[n + 1] - sIn;
  int sOut = rsOut[n], degOut = rsOut[n + 1] - sOut;
  float4 accIn = {0.f, 0.f, 0.f, 0.f}, accOut = {0.f, 0.f, 0.f, 0.f};
  float dI0 = 0.f, dI1 = 0.f, dO0 = 0.f, dO1 = 0.f;
  int mx = max(degIn, degOut);
  for (int b = 0; b < mx; b += 64) {
    int l = b + lane;
    float2 evI = {0.f, 0.f}, evO = {0.f, 0.f};
    int2 ptI = {0, 0}, ptO = {0, 0};
    if (l < degIn)  { evI = eIc[sIn + l];  ptI = pinIn[sIn + l]; }
    if (l < degOut) { evO = eOc[sOut + l]; ptO = pinOut[sOut + l]; }
    dI0 += evI.x; dI1 += evI.y; dO0 += evO.x; dO1 += evO.y;
    int mI = degIn - b;  if (mI > 64) mI = 64;
    int mO = degOut - b; if (mO > 64) mO = 64;
    int m2 = max(mI, mO);
    for (int jj = 0; jj < m2; ++jj) {
      float aI0 = __shfl(evI.x, jj, 64), aI1 = __shfl(evI.y, jj, 64);
      int rI = __shfl(ptI.x, jj, 64), tI = __shfl(ptI.y, jj, 64);
      float aO0 = __shfl(evO.x, jj, 64), aO1 = __shfl(evO.y, jj, 64);
      int rO = __shfl(ptO.x, jj, 64), tO = __shfl(ptO.y, jj, 64);
      if (act && jj < mI) {
        float wgt = half ? aI1 : aI0;
        ushort4 pa = *(const ushort4*)(PAb + (size_t)rI * 200 + j);
        ushort4 p3 = *(const ushort4*)(P3ib + (size_t)tI * 200 + j);
        accIn.x += wgt * (bf2f(pa.x) + bf2f(p3.x));
        accIn.y += wgt * (bf2f(pa.y) + bf2f(p3.y));
        accIn.z += wgt * (bf2f(pa.z) + bf2f(p3.z));
        accIn.w += wgt * (bf2f(pa.w) + bf2f(p3.w));
      }
      if (act && jj < mO) {
        float wgt = half ? aO1 : aO0;
        ushort4 pd = *(const ushort4*)(PDb + (size_t)rO * 200 + j);
        ushort4 p3 = *(const ushort4*)(P3ob + (size_t)tO * 200 + j);
        accOut.x += wgt * (bf2f(pd.x) + bf2f(p3.x));
        accOut.y += wgt * (bf2f(pd.y) + bf2f(p3.y));
        accOut.z += wgt * (bf2f(pd.z) + bf2f(p3.z));
        accOut.w += wgt * (bf2f(pd.w) + bf2f(p3.w));
      }
    }
  }
#pragma unroll
  for (int m = 1; m < 64; m <<= 1) {
    dI0 += __shfl_xor(dI0, m, 64); dI1 += __shfl_xor(dI1, m, 64);
    dO0 += __shfl_xor(dO0, m, 64); dO1 += __shfl_xor(dO1, m, 64);
  }
  float4 hin = {0.f, 0.f, 0.f, 0.f}, hout = {0.f, 0.f, 0.f, 0.f};
  if (degIn > 0 && act) {
    float invd = 1.f / (half ? dI1 : dI0);
    ushort4 ps = *(const ushort4*)(PBb + (size_t)n * 200 + j);
    hin.x = elu1(bf2f(ps.x) + accIn.x * invd);
    hin.y = elu1(bf2f(ps.y) + accIn.y * invd);
    hin.z = elu1(bf2f(ps.z) + accIn.z * invd);
    hin.w = elu1(bf2f(ps.w) + accIn.w * invd);
  }
  if (degOut > 0 && act) {
    float invd = 1.f / (half ? dO1 : dO0);
    ushort4 ps = *(const ushort4*)(PCb + (size_t)n * 200 + j);
    hout.x = elu1(bf2f(ps.x) + accOut.x * invd);
    hout.y = elu1(bf2f(ps.y) + accOut.y * invd);
    hout.z = elu1(bf2f(ps.z) + accOut.z * invd);
    hout.w = elu1(bf2f(ps.w) + accOut.w * invd);
  }
  float gp = 0.f;
  if (act) {
    int k = i * 4;
    gp = Wg[k] * hin.x + Wg[k + 1] * hin.y + Wg[k + 2] * hin.z + Wg[k + 3] * hin.w +
         Wg[100 + k] * hout.x + Wg[100 + k + 1] * hout.y +
         Wg[100 + k + 2] * hout.z + Wg[100 + k + 3] * hout.w;
  }
#pragma unroll
  for (int m = 1; m < 32; m <<= 1) gp += __shfl_xor(gp, m, 32);
  float al = 1.f / (1.f + expf(-(gp + bg[0])));
  float4 he;
  he.x = elu1(al * hin.x + (1.f - al) * hout.x);
  he.y = elu1(al * hin.y + (1.f - al) * hout.y);
  he.z = elu1(al * hin.z + (1.f - al) * hout.z);
  he.w = elu1(al * hin.w + (1.f - al) * hout.w);
  float ss = he.x * he.x + he.y * he.y + he.z * he.z + he.w * he.w;
#pragma unroll
  for (int m = 1; m < 32; m <<= 1) ss += __shfl_xor(ss, m, 32);
  float inv = 1.f / fmaxf(sqrtf(ss), 1e-12f);
  float4 o = {he.x * inv, he.y * inv, he.z * inv, he.w * inv};
  if (Hb) {
    if (act) {
      ushort4 ov; ov.x = f2bf(o.x); ov.y = f2bf(o.y); ov.z = f2bf(o.z); ov.w = f2bf(o.w);
      *(ushort4*)(Hb + (size_t)n * 256 + j) = ov;
    } else {
      int pi = half * 7 + (i - 25);
      ushort4 z = {0, 0, 0, 0};
      *(ushort4*)(Hb + (size_t)n * 256 + 200 + pi * 4) = z;
    }
  }
  if (outp) {
    float4 v = {0.f, 0.f, 0.f, 0.f};
    if (act) {
      float4 hv = *(const float4*)(hent + (size_t)n * 200 + j);
      v.x = hv.x + o.x; v.y = hv.y + o.y; v.z = hv.z + o.z; v.w = hv.w + o.w;
    }
    float s2 = v.x * v.x + v.y * v.y + v.z * v.z + v.w * v.w;
#pragma unroll
    for (int m = 1; m < 32; m <<= 1) s2 += __shfl_xor(s2, m, 32);
    float inv2 = 1.f / fmaxf(sqrtf(s2), 1e-12f);
    if (act) {
      float4 ov = {v.x * inv2, v.y * inv2, v.z * inv2, v.w * inv2};
      *(float4*)(outp + (size_t)n * 200 + j) = ov;
    }
  }
  if (u2in) {
    float4 ov = act ? o : make_float4(0.f, 0.f, 0.f, 0.f);
    float s[8];
#pragma unroll
    for (int h = 0; h < 2; ++h) {
      float4 uA = *(const float4*)(u2in + h * 500 + j);
      float4 uB = *(const float4*)(u2in + h * 500 + 200 + j);
      float4 uC = *(const float4*)(u2out + h * 500 + j);
      float4 uD = *(const float4*)(u2out + h * 500 + 200 + j);
      s[0 + h] = ov.x * uA.x + ov.y * uA.y + ov.z * uA.z + ov.w * uA.w;
      s[2 + h] = ov.x * uB.x + ov.y * uB.y + ov.z * uB.z + ov.w * uB.w;
      s[4 + h] = ov.x * uC.x + ov.y * uC.y + ov.z * uC.z + ov.w * uC.w;
      s[6 + h] = ov.x * uD.x + ov.y * uD.y + ov.z * uD.z + ov.w * uD.w;
    }
#pragma unroll
    for (int m = 1; m < 64; m <<= 1) {
#pragma unroll
      for (int ii = 0; ii < 8; ++ii) s[ii] += __shfl_xor(s[ii], m, 64);
    }
    if (lane == 0) {
      qA[n * 2] = s[0]; qA[n * 2 + 1] = s[1];
      qB[n * 2] = s[2]; qB[n * 2 + 1] = s[3];
      qC[n * 2] = s[4]; qC[n * 2 + 1] = s[5];
      qD[n * 2] = s[6]; qD[n * 2 + 1] = s[7];
    }
  }
}

extern "C" void kernel_launch(void* const* d_in, const int* in_sizes, int n_in,
                              void* d_out, int out_size, void* d_ws, size_t ws_size,
                              hipStream_t stream) {
  const float* x    = (const float*)d_in[0];
  const float* g    = (const float*)d_in[1];
  const float* W1in = (const float*)d_in[2];
  const float* b1in = (const float*)d_in[3];
  const float* a1in = (const float*)d_in[4];
  const float* W1out= (const float*)d_in[5];
  const float* b1out= (const float*)d_in[6];
  const float* a1out= (const float*)d_in[7];
  const float* Wa1  = (const float*)d_in[8];
  const float* ba1  = (const float*)d_in[9];
  const float* W2in = (const float*)d_in[10];
  const float* b2in = (const float*)d_in[11];
  const float* a2in = (const float*)d_in[12];
  const float* W2out= (const float*)d_in[13];
  const float* b2out= (const float*)d_in[14];
  const float* a2out= (const float*)d_in[15];
  const float* Wa2  = (const float*)d_in[16];
  const float* ba2  = (const float*)d_in[17];
  const float* Went = (const float*)d_in[18];
  const float* bent = (const float*)d_in[19];
  const float* Wrel = (const float*)d_in[20];
  const float* brel = (const float*)d_in[21];
  const int*  eidx  = (const int*)d_in[22];
  const int*  ety   = (const int*)d_in[23];

  const int N = in_sizes[0] / 100;
  const int M = in_sizes[1] / 100;
  const int E = in_sizes[23];
  const int* row = eidx;
  const int* col = eidx + E;
  float* out = (float*)d_out;

  float* ws = (float*)d_ws;
  size_t off = 0;
  auto alloc = [&](size_t nf) { float* p = ws + off; off += (nf + 3) & ~(size_t)3; return p; };
  ushort_t* PAb = (ushort_t*)alloc((size_t)N * 100);
  ushort_t* PBb = (ushort_t*)alloc((size_t)N * 100);
  ushort_t* PCb = (ushort_t*)alloc((size_t)N * 100);
  ushort_t* PDb = (ushort_t*)alloc((size_t)N * 100);
  ushort_t* P3ib = (ushort_t*)alloc((size_t)M * 100);
  ushort_t* P3ob = (ushort_t*)alloc((size_t)M * 100);
  ushort_t* xnb = (ushort_t*)alloc((size_t)N * 64);
  ushort_t* h1b = (ushort_t*)alloc((size_t)N * 128);
  ushort_t* wcat1 = (ushort_t*)alloc((size_t)832 * 64);
  ushort_t* wcat2 = (ushort_t*)alloc((size_t)832 * 128);
  ushort_t* wentb = (ushort_t*)alloc((size_t)256 * 64);
  float* qA  = alloc((size_t)N * 2);
  float* qB  = alloc((size_t)N * 2);
  float* qC  = alloc((size_t)N * 2);
  float* qD  = alloc((size_t)N * 2);
  float* q3i1 = alloc((size_t)M * 2);
  float* q3o1 = alloc((size_t)M * 2);
  float* q3i2 = alloc((size_t)M * 2);
  float* q3o2 = alloc((size_t)M * 2);
  float2* eIc = (float2*)alloc((size_t)E * 2);
  float2* eOc = (float2*)alloc((size_t)E * 2);
  int2* pinIn  = (int2*)alloc((size_t)E * 2);
  int2* pinOut = (int2*)alloc((size_t)E * 2);
  int* invIn  = (int*)alloc((size_t)E);
  int* invOut = (int*)alloc((size_t)E);
  float* hent = alloc((size_t)N * 200);
  float* u1in  = alloc(600);
  float* u1out = alloc(600);
  float* u2in  = alloc(1000);
  float* u2out = alloc(1000);
  int* cntIn  = (int*)alloc((size_t)N);
  int* cntOut = (int*)alloc((size_t)N);
  int* rsIn   = (int*)alloc((size_t)N + 1);
  int* rsOut  = (int*)alloc((size_t)N + 1);
  int* posIn  = (int*)alloc((size_t)N);
  int* posOut = (int*)alloc((size_t)N);
  int* part   = (int*)alloc((size_t)512);

  const int gN4 = (N + 3) / 4;
  const int gE  = (E + 255) / 256;
  const int mT128 = (N + 127) / 128;
  const int nbc = (N + 255) / 256;

  const int nb_bw = (832 * 128 + 832 * 256 + 256 * 128 + 255) / 256;
  const int nb_mk = 13;
  const int nb_z  = (2 * N + 255) / 256;
  const int nb_l2 = gN4;
  const int nb_qr = (2 * M + 3) / 4;
  const int nb_mf = 7 * mT128;
  const int nb_gm = 4 * ((M + 31) / 32);
  const int nb_we = 2 * mT128;

  MEGA0<<<nb_bw + nb_mk + nb_z, 256, 0, stream>>>(
      W1in, W1out, W2in, W2out, Went, wcat1, wcat2, wentb,
      a1in, a1out, a2in, a2out, u1in, u1out, u2in, u2out,
      cntIn, cntOut, N, nb_bw, nb_mk);

  MEGA1<<<nb_l2 + nb_qr + gE, 256, 0, stream>>>(
      x, xnb, u1in, u1out, qA, qB, qC, qD, N,
      g, u2in, u2out, q3i1, q3o1, q3i2, q3o2, M,
      row, col, cntIn, cntOut, E, nb_l2, nb_qr);

  k_scanA<<<2 * nbc, 256, 0, stream>>>(cntIn, cntOut, part, N, nbc);
  k_scanB<<<1, 256, 0, stream>>>(part, rsIn, rsOut, nbc, N);
  k_scanC<<<2 * nbc, 256, 0, stream>>>(cntIn, cntOut, part, rsIn, rsOut, posIn, posOut, N, nbc);
  k_fill<<<gE, 256, 0, stream>>>(row, col, ety, posIn, posOut, pinIn, pinOut, invIn, invOut, E);

  MEGA2<<<nb_mf + gE + nb_gm + nb_we + nb_gm, 256, 0, stream>>>(
      xnb, wcat1, PAb, PBb, PCb, PDb, N,
      row, col, ety, qA, qB, q3i1, qC, qD, q3o1, invIn, invOut, eIc, eOc, E,
      g, W1in + 200, W1out + 200, b1in, b1out, P3ib, P3ob, M,
      wentb, bent, hent, Wrel, brel, out + (size_t)N * 200,
      nb_mf, gE, nb_gm, nb_we);

  k_node_att<<<gN4, 256, 0, stream>>>(pinIn, eIc, rsIn, pinOut, eOc, rsOut,
                                      PAb, PBb, PCb, PDb, P3ib, P3ob, Wa1, ba1,
                                      u2in, u2out, qA, qB, qC, qD,
                                      h1b, nullptr, nullptr, N);

  MEGA3<<<nb_mf + gE + nb_gm, 256, 0, stream>>>(
      h1b, wcat2, PAb, PBb, PCb, PDb, N,
      row, col, ety, qA, qB, q3i2, qC, qD, q3o2, invIn, invOut, eIc, eOc, E,
      g, W2in + 400, W2out + 400, b2in, b2out, P3ib, P3ob, M,
      nb_mf, gE);

  k_node_att<<<gN4, 256, 0, stream>>>(pinIn, eIc, rsIn, pinOut, eOc, rsOut,
                                      PAb, PBb, PCb, PDb, P3ib, P3ob, Wa2, ba2,
                                      nullptr, nullptr, qA, qB, qC, qD,
                                      nullptr, hent, out, N);
}

// Round 12
// 200.299 us; speedup vs baseline: 1.3834x; 1.3834x over previous
//
#include <hip/hip_runtime.h>
#include <math.h>

#define NSLOPE 0.2f

typedef unsigned short ushort_t;
typedef __attribute__((ext_vector_type(8))) short bf16x8;
typedef __attribute__((ext_vector_type(8))) unsigned short ushort8;
typedef __attribute__((ext_vector_type(4))) float f32x4;

__device__ __forceinline__ float elu1(float x) { return x > 0.f ? x : expm1f(x); }

__device__ __forceinline__ ushort_t f2bf(float f) {
  union { float f; unsigned int u; } v; v.f = f;
  unsigned int r = v.u + 0x7fffu + ((v.u >> 16) & 1u);
  return (ushort_t)(r >> 16);
}
__device__ __forceinline__ float bf2f(ushort_t u) {
  union { unsigned int i; float f; } v; v.i = ((unsigned int)u) << 16; return v.f;
}

// ================= device bodies =================

__device__ void dev_build_w(int idx,
                            const float* __restrict__ W1in, const float* __restrict__ W1out,
                            const float* __restrict__ W2in, const float* __restrict__ W2out,
                            const float* __restrict__ Went,
                            ushort_t* __restrict__ wcat1, ushort_t* __restrict__ wcat2,
                            ushort_t* __restrict__ wentb) {
  const int S1 = 832 * 128, S2 = 832 * 256, S3 = 256 * 128;
  if (idx < S1) {
    int ro = idx >> 7, k = idx & 127;
    float val = 0.f;
    if (ro < 800 && k < 100) {
      int o = ro / 200, cc = ro - o * 200;
      const float* W = (o < 2) ? W1in : W1out;
      val = W[(size_t)cc * 300 + (o & 1) * 100 + k];
    }
    wcat1[idx] = f2bf(val);
  } else if (idx < S1 + S2) {
    int i2 = idx - S1;
    int ro = i2 >> 8, k = i2 & 255;
    float val = 0.f;
    if (ro < 800 && k < 200) {
      int o = ro / 200, cc = ro - o * 200;
      const float* W = (o < 2) ? W2in : W2out;
      val = W[(size_t)cc * 500 + (o & 1) * 200 + k];
    }
    wcat2[i2] = f2bf(val);
  } else if (idx < S1 + S2 + S3) {
    int i3 = idx - S1 - S2;
    int ro = i3 >> 7, k = i3 & 127;
    float val = (ro < 200 && k < 100) ? Went[ro * 100 + k] : 0.f;
    wentb[i3] = f2bf(val);
  }
}

__device__ void dev_makeu(int idx,
                          const float* __restrict__ W1in, const float* __restrict__ a1in,
                          const float* __restrict__ W1out, const float* __restrict__ a1out,
                          const float* __restrict__ W2in, const float* __restrict__ a2in,
                          const float* __restrict__ W2out, const float* __restrict__ a2out,
                          float* __restrict__ u1in, float* __restrict__ u1out,
                          float* __restrict__ u2in, float* __restrict__ u2out) {
  if (idx >= 3200) return;
  const float* W; const float* avec; float* u; int Kp, local;
  if (idx < 600)       { W = W1in;  avec = a1in;  u = u1in;  Kp = 300; local = idx; }
  else if (idx < 1200) { W = W1out; avec = a1out; u = u1out; Kp = 300; local = idx - 600; }
  else if (idx < 2200) { W = W2in;  avec = a2in;  u = u2in;  Kp = 500; local = idx - 1200; }
  else                 { W = W2out; avec = a2out; u = u2out; Kp = 500; local = idx - 2200; }
  int h = local / Kp, kp = local - h * Kp;
  const float* Wb = W + (size_t)(h * 100) * Kp + kp;
  const float* ab = avec + h * 100;
  float s = 0.f;
  for (int k = 0; k < 100; ++k) s += ab[k] * Wb[(size_t)k * Kp];
  u[local] = s;
}

__device__ void dev_l2norm_q(int bb, int tid, const float* __restrict__ x,
                             ushort_t* __restrict__ xnb,
                             const float* __restrict__ u1in, const float* __restrict__ u1out,
                             float* __restrict__ qA, float* __restrict__ qB,
                             float* __restrict__ qC, float* __restrict__ qD, int N) {
  int wid = bb * 4 + (tid >> 6);
  int lane = tid & 63;
  if (wid >= N) return;
  const float* p = x + (size_t)wid * 100;
  float v0 = p[lane];
  bool t2 = lane < 36;
  float v1 = t2 ? p[lane + 64] : 0.f;
  float ss = v0 * v0 + v1 * v1;
#pragma unroll
  for (int m = 1; m < 64; m <<= 1) ss += __shfl_xor(ss, m, 64);
  float inv = 1.f / fmaxf(sqrtf(ss), 1e-12f);
  float a0 = v0 * inv, a1 = v1 * inv;
  ushort_t* ob = xnb + (size_t)wid * 128;
  ob[lane] = f2bf(a0);
  ob[64 + lane] = t2 ? f2bf(a1) : (ushort_t)0;
  int k0 = lane, k1 = 64 + lane;
  float s[8];
  s[0] = a0 * u1in[k0]        + (t2 ? a1 * u1in[k1]        : 0.f);
  s[1] = a0 * u1in[300 + k0]  + (t2 ? a1 * u1in[300 + k1]  : 0.f);
  s[2] = a0 * u1in[100 + k0]  + (t2 ? a1 * u1in[100 + k1]  : 0.f);
  s[3] = a0 * u1in[400 + k0]  + (t2 ? a1 * u1in[400 + k1]  : 0.f);
  s[4] = a0 * u1out[k0]       + (t2 ? a1 * u1out[k1]       : 0.f);
  s[5] = a0 * u1out[300 + k0] + (t2 ? a1 * u1out[300 + k1] : 0.f);
  s[6] = a0 * u1out[100 + k0] + (t2 ? a1 * u1out[100 + k1] : 0.f);
  s[7] = a0 * u1out[400 + k0] + (t2 ? a1 * u1out[400 + k1] : 0.f);
#pragma unroll
  for (int m = 1; m < 64; m <<= 1) {
#pragma unroll
    for (int i = 0; i < 8; ++i) s[i] += __shfl_xor(s[i], m, 64);
  }
  if (lane == 0) {
    qA[wid * 2] = s[0]; qA[wid * 2 + 1] = s[1];
    qB[wid * 2] = s[2]; qB[wid * 2 + 1] = s[3];
    qC[wid * 2] = s[4]; qC[wid * 2 + 1] = s[5];
    qD[wid * 2] = s[6]; qD[wid * 2 + 1] = s[7];
  }
}

__device__ void dev_qrel2(int bb, int tid, const float* __restrict__ g,
                          const float* __restrict__ u1in, const float* __restrict__ u1out,
                          const float* __restrict__ u2in, const float* __restrict__ u2out,
                          float* __restrict__ q3i1, float* __restrict__ q3o1,
                          float* __restrict__ q3i2, float* __restrict__ q3o2, int Mn) {
  int wid = bb * 4 + (tid >> 6);
  int lane = tid & 63;
  if (wid >= 2 * Mn) return;
  int lay = wid >= Mn;
  int m = wid - lay * Mn;
  const float* uin  = lay ? u2in  : u1in;
  const float* uout = lay ? u2out : u1out;
  int Kp = lay ? 500 : 300;
  int off3 = lay ? 400 : 200;
  float* q3i = lay ? q3i2 : q3i1;
  float* q3o = lay ? q3o2 : q3o1;
  const float* a = g + (size_t)m * 100;
  float s[4] = {0.f, 0.f, 0.f, 0.f};
  for (int k = lane; k < 100; k += 64) {
    float av = a[k];
    s[0] += av * uin[off3 + k];
    s[1] += av * uin[Kp + off3 + k];
    s[2] += av * uout[off3 + k];
    s[3] += av * uout[Kp + off3 + k];
  }
#pragma unroll
  for (int mm = 1; mm < 64; mm <<= 1) {
#pragma unroll
    for (int i = 0; i < 4; ++i) s[i] += __shfl_xor(s[i], mm, 64);
  }
  if (lane == 0) {
    q3i[m * 2] = s[0]; q3i[m * 2 + 1] = s[1];
    q3o[m * 2] = s[2]; q3o[m * 2 + 1] = s[3];
  }
}

__device__ void dev_count(int bb, int tid, const int* __restrict__ row,
                          const int* __restrict__ col,
                          int* __restrict__ cntIn, int* __restrict__ cntOut, int E) {
  int e = bb * 256 + tid;
  if (e >= E) return;
  atomicAdd(&cntIn[col[e]], 1);
  atomicAdd(&cntOut[row[e]], 1);
}

__device__ void dev_edge_e(int bb, int tid,
                           const int* __restrict__ row, const int* __restrict__ col,
                           const int* __restrict__ ety,
                           const float* __restrict__ qA, const float* __restrict__ qB,
                           const float* __restrict__ q3i,
                           const float* __restrict__ qC, const float* __restrict__ qD,
                           const float* __restrict__ q3o,
                           const int* __restrict__ invIn, const int* __restrict__ invOut,
                           float2* __restrict__ eIc, float2* __restrict__ eOc, int E) {
  int e = bb * 256 + tid;
  if (e >= E) return;
  int r = row[e], c = col[e], t = ety[e];
  float2 vA = *(const float2*)(qA + (size_t)r * 2);
  float2 vB = *(const float2*)(qB + (size_t)c * 2);
  float2 v3 = *(const float2*)(q3i + (size_t)t * 2);
  float2 vC = *(const float2*)(qC + (size_t)r * 2);
  float2 vD = *(const float2*)(qD + (size_t)c * 2);
  float2 v4 = *(const float2*)(q3o + (size_t)t * 2);
  float a0 = vA.x + vB.x + v3.x, a1 = vA.y + vB.y + v3.y;
  float b0 = vC.x + vD.x + v4.x, b1 = vC.y + vD.y + v4.y;
  float2 rI, rO;
  rI.x = expf(-(a0 > 0.f ? a0 : NSLOPE * a0));
  rI.y = expf(-(a1 > 0.f ? a1 : NSLOPE * a1));
  rO.x = expf(-(b0 > 0.f ? b0 : NSLOPE * b0));
  rO.y = expf(-(b1 > 0.f ? b1 : NSLOPE * b1));
  eIc[invIn[e]] = rI;
  eOc[invOut[e]] = rO;
}

// 64x64 MFMA GEMM tile (proven R8/R10 body)
__device__ void dev_mfma(int bx, int by, int tid,
                         ushort_t* __restrict__ smA, ushort_t* __restrict__ smB,
                         const ushort_t* __restrict__ Ab, int lda,
                         const ushort_t* __restrict__ Bb, int Kpad,
                         int R, int NC, int OUTW, const float* __restrict__ bias,
                         float* __restrict__ C0,
                         ushort_t* __restrict__ Bd0, ushort_t* __restrict__ Bd1,
                         ushort_t* __restrict__ Bd2, ushort_t* __restrict__ Bd3) {
  const int lane = tid & 63;
  const int w = tid >> 6;
  const int wm = w >> 1, wn = w & 1;
  const int m0 = by * 64;
  const int n0 = bx * 64;
  const int srow = tid >> 2;
  const int sq = tid & 3;
  const int sw3 = srow & 7;
  const int sbase = srow * 64;
  const int so0 = sbase + ((((sq << 1) + 0) ^ sw3) << 3);
  const int so1 = sbase + ((((sq << 1) + 1) ^ sw3) << 3);
  const bool aok = (m0 + srow) < R;
  const ushort_t* Ag = Ab + (size_t)(m0 + srow) * lda + sq * 16;
  const ushort_t* Bg = Bb + (size_t)(n0 + srow) * Kpad + sq * 16;
  const int lswz = lane & 7;
  const int hi = lane >> 4;
  const int rA0 = (wm * 32 + (lane & 15)) * 64;
  const int rB0 = (wn * 32 + (lane & 15)) * 64;
  f32x4 acc[2][2] = {};
  for (int k0 = 0; k0 < Kpad; k0 += 64) {
    ushort8 a0 = {0, 0, 0, 0, 0, 0, 0, 0}, a1 = {0, 0, 0, 0, 0, 0, 0, 0};
    if (aok) {
      a0 = *(const ushort8*)(Ag + k0);
      a1 = *(const ushort8*)(Ag + k0 + 8);
    }
    ushort8 b0 = *(const ushort8*)(Bg + k0);
    ushort8 b1 = *(const ushort8*)(Bg + k0 + 8);
    __syncthreads();
    *(ushort8*)(smA + so0) = a0;
    *(ushort8*)(smA + so1) = a1;
    *(ushort8*)(smB + so0) = b0;
    *(ushort8*)(smB + so1) = b1;
    __syncthreads();
#pragma unroll
    for (int ks = 0; ks < 2; ++ks) {
      int co = (((ks << 2) + hi) ^ lswz) << 3;
      bf16x8 aA = *(const bf16x8*)(smA + rA0 + co);
      bf16x8 aB = *(const bf16x8*)(smA + rA0 + 1024 + co);
      bf16x8 bA = *(const bf16x8*)(smB + rB0 + co);
      bf16x8 bB = *(const bf16x8*)(smB + rB0 + 1024 + co);
      acc[0][0] = __builtin_amdgcn_mfma_f32_16x16x32_bf16(aA, bA, acc[0][0], 0, 0, 0);
      acc[0][1] = __builtin_amdgcn_mfma_f32_16x16x32_bf16(aA, bB, acc[0][1], 0, 0, 0);
      acc[1][0] = __builtin_amdgcn_mfma_f32_16x16x32_bf16(aB, bA, acc[1][0], 0, 0, 0);
      acc[1][1] = __builtin_amdgcn_mfma_f32_16x16x32_bf16(aB, bB, acc[1][1], 0, 0, 0);
    }
  }
  ushort_t* Bds[4] = {Bd0, Bd1, Bd2, Bd3};
#pragma unroll
  for (int mt = 0; mt < 2; ++mt) {
    int rr0 = m0 + wm * 32 + mt * 16 + (lane >> 4) * 4;
#pragma unroll
    for (int nt = 0; nt < 2; ++nt) {
      int cc = n0 + wn * 32 + nt * 16 + (lane & 15);
      if (cc < NC) {
        int o = cc / OUTW;
        int c2 = cc - o * OUTW;
        float bv = bias ? bias[c2] : 0.f;
        ushort_t* Bd = Bds[o];
        if (Bd) {
#pragma unroll
          for (int reg = 0; reg < 4; ++reg) {
            int r = rr0 + reg;
            if (r < R) Bd[(size_t)r * OUTW + c2] = f2bf(acc[mt][nt][reg] + bv);
          }
        } else {
#pragma unroll
          for (int reg = 0; reg < 4; ++reg) {
            int r = rr0 + reg;
            if (r < R) C0[(size_t)r * OUTW + c2] = acc[mt][nt][reg] + bv;
          }
        }
      }
    }
  }
}

template <int NOUT, int BF>
__device__ void dev_gemm_multi(int bx, int by, int tid, float4 (*As)[25],
                               const float* __restrict__ A, int lda,
                               const float* __restrict__ W0, const float* __restrict__ W1,
                               int ldw,
                               const float* __restrict__ b0, const float* __restrict__ b1,
                               void* __restrict__ C0v, void* __restrict__ C1v, int R) {
  const int K4 = 25;
  int row0 = by * 32;
  {
    int r = tid >> 3;
    int rr = row0 + r;
    const float4* Ar = (const float4*)(A + (size_t)rr * lda);
    for (int k4 = (tid & 7); k4 < K4; k4 += 8)
      As[r][k4] = (rr < R) ? Ar[k4] : make_float4(0.f, 0.f, 0.f, 0.f);
  }
  __syncthreads();
  int c = bx * 64 + (tid & 63);
  if (c < 200) {
    int rb = (tid >> 6) << 3;
    const float4* Wr[NOUT];
    Wr[0] = (const float4*)(W0 + (size_t)c * ldw);
    if (NOUT > 1) Wr[1] = (const float4*)(W1 + (size_t)c * ldw);
    float acc[NOUT][8];
#pragma unroll
    for (int o = 0; o < NOUT; ++o)
#pragma unroll
      for (int i = 0; i < 8; ++i) acc[o][i] = 0.f;
#pragma unroll 2
    for (int k4 = 0; k4 < K4; ++k4) {
      float4 a[8];
#pragma unroll
      for (int i = 0; i < 8; ++i) a[i] = As[rb + i][k4];
#pragma unroll
      for (int o = 0; o < NOUT; ++o) {
        float4 wv = Wr[o][k4];
#pragma unroll
        for (int i = 0; i < 8; ++i)
          acc[o][i] += a[i].x * wv.x + a[i].y * wv.y + a[i].z * wv.z + a[i].w * wv.w;
      }
    }
    float bv[NOUT];
    bv[0] = b0 ? b0[c] : 0.f;
    if (NOUT > 1) bv[1] = b1 ? b1[c] : 0.f;
    void* Cp[NOUT];
    Cp[0] = C0v;
    if (NOUT > 1) Cp[1] = C1v;
#pragma unroll
    for (int i = 0; i < 8; ++i) {
      int rr = row0 + rb + i;
      if (rr < R) {
#pragma unroll
        for (int o = 0; o < NOUT; ++o) {
          float val = acc[o][i] + bv[o];
          if (BF) ((ushort_t*)Cp[o])[(size_t)rr * 200 + c] = f2bf(val);
          else    ((float*)Cp[o])[(size_t)rr * 200 + c] = val;
        }
      }
    }
  }
}

// ================= kernels =================

__global__ __launch_bounds__(256) void MEGA0(
    const float* W1in, const float* W1out, const float* W2in, const float* W2out,
    const float* Went,
    ushort_t* wcat1, ushort_t* wcat2, ushort_t* wentb,
    const float* a1in, const float* a1out, const float* a2in, const float* a2out,
    float* u1in, float* u1out, float* u2in, float* u2out,
    int* cntIn, int* cntOut, int N, int nb_bw, int nb_mk) {
  int b = blockIdx.x, tid = threadIdx.x;
  if (b < nb_bw) {
    dev_build_w(b * 256 + tid, W1in, W1out, W2in, W2out, Went, wcat1, wcat2, wentb);
  } else if (b < nb_bw + nb_mk) {
    dev_makeu((b - nb_bw) * 256 + tid, W1in, a1in, W1out, a1out, W2in, a2in, W2out, a2out,
              u1in, u1out, u2in, u2out);
  } else {
    int idx = (b - nb_bw - nb_mk) * 256 + tid;
    if (idx < N) cntIn[idx] = 0;
    else if (idx < 2 * N) cntOut[idx - N] = 0;
  }
}

__global__ __launch_bounds__(256) void MEGA1(
    const float* x, ushort_t* xnb, const float* u1in, const float* u1out,
    float* qA, float* qB, float* qC, float* qD, int N,
    const float* g, const float* u2in, const float* u2out,
    float* q3i1, float* q3o1, float* q3i2, float* q3o2, int Mn,
    const int* row, const int* col, int* cntIn, int* cntOut, int E,
    int nb_l2, int nb_qr) {
  int b = blockIdx.x, tid = threadIdx.x;
  if (b < nb_l2) {
    dev_l2norm_q(b, tid, x, xnb, u1in, u1out, qA, qB, qC, qD, N);
  } else if (b < nb_l2 + nb_qr) {
    dev_qrel2(b - nb_l2, tid, g, u1in, u1out, u2in, u2out, q3i1, q3o1, q3i2, q3o2, Mn);
  } else {
    dev_count(b - nb_l2 - nb_qr, tid, row, col, cntIn, cntOut, E);
  }
}

// ---- parallel 3-phase scan ----
__global__ __launch_bounds__(256) void k_scanA(const int* __restrict__ cntIn,
                                               const int* __restrict__ cntOut,
                                               int* __restrict__ part, int N, int nbc) {
  __shared__ int wsum[4];
  int b = blockIdx.x;
  const int* cnt = (b < nbc) ? cntIn : cntOut;
  int cb = (b < nbc) ? b : b - nbc;
  int idx = cb * 256 + threadIdx.x;
  int v = (idx < N) ? cnt[idx] : 0;
#pragma unroll
  for (int m = 1; m < 64; m <<= 1) v += __shfl_xor(v, m, 64);
  if ((threadIdx.x & 63) == 0) wsum[threadIdx.x >> 6] = v;
  __syncthreads();
  if (threadIdx.x == 0) part[b] = wsum[0] + wsum[1] + wsum[2] + wsum[3];
}

__global__ __launch_bounds__(256) void k_scanB(int* __restrict__ part,
                                               int* __restrict__ rsIn, int* __restrict__ rsOut,
                                               int nbc, int N) {
  __shared__ int buf[512];
  int t = threadIdx.x;
  buf[t]       = (t < nbc) ? part[t] : 0;
  buf[256 + t] = (t < nbc) ? part[nbc + t] : 0;
  __syncthreads();
  for (int off = 1; off < 256; off <<= 1) {
    int v0 = (t >= off) ? buf[t - off] : 0;
    int v1 = (t >= off) ? buf[256 + t - off] : 0;
    __syncthreads();
    buf[t] += v0; buf[256 + t] += v1;
    __syncthreads();
  }
  if (t < nbc) {
    part[t]       = (t == 0) ? 0 : buf[t - 1];
    part[nbc + t] = (t == 0) ? 0 : buf[256 + t - 1];
  }
  if (t == 0) { rsIn[N] = buf[nbc - 1]; rsOut[N] = buf[256 + nbc - 1]; }
}

__global__ __launch_bounds__(256) void k_scanC(const int* __restrict__ cntIn,
                                               const int* __restrict__ cntOut,
                                               const int* __restrict__ part,
                                               int* __restrict__ rsIn, int* __restrict__ rsOut,
                                               int* __restrict__ posIn, int* __restrict__ posOut,
                                               int N, int nbc) {
  __shared__ int buf[256];
  int b = blockIdx.x;
  const int* cnt = (b < nbc) ? cntIn : cntOut;
  int* rs  = (b < nbc) ? rsIn : rsOut;
  int* pos = (b < nbc) ? posIn : posOut;
  int cb = (b < nbc) ? b : b - nbc;
  int base = part[b];
  int t = threadIdx.x;
  int idx = cb * 256 + t;
  buf[t] = (idx < N) ? cnt[idx] : 0;
  __syncthreads();
  for (int off = 1; off < 256; off <<= 1) {
    int v = (t >= off) ? buf[t - off] : 0;
    __syncthreads();
    buf[t] += v;
    __syncthreads();
  }
  if (idx < N) {
    int excl = base + ((t == 0) ? 0 : buf[t - 1]);
    rs[idx] = excl; pos[idx] = excl;
  }
}

__global__ void k_fill(const int* __restrict__ row, const int* __restrict__ col,
                       const int* __restrict__ ety,
                       int* __restrict__ posIn, int* __restrict__ posOut,
                       int2* __restrict__ pinIn, int2* __restrict__ pinOut,
                       int* __restrict__ invIn, int* __restrict__ invOut, int E) {
  int e = blockIdx.x * blockDim.x + threadIdx.x;
  if (e >= E) return;
  int r = row[e], c = col[e], tt = ety[e];
  int p = atomicAdd(&posIn[c], 1);
  pinIn[p] = make_int2(r, tt);
  invIn[e] = p;
  int q = atomicAdd(&posOut[r], 1);
  pinOut[q] = make_int2(c, tt);
  invOut[e] = q;
}

__global__ __launch_bounds__(256) void MEGA2(
    const ushort_t* xnb, const ushort_t* wcat1,
    ushort_t* PAb, ushort_t* PBb, ushort_t* PCb, ushort_t* PDb, int N,
    const int* row, const int* col, const int* ety,
    const float* qA, const float* qB, const float* q3i1,
    const float* qC, const float* qD, const float* q3o1,
    const int* invIn, const int* invOut, float2* eIc, float2* eOc, int E,
    const float* g, const float* W1in200, const float* W1out200,
    const float* b1in, const float* b1out, ushort_t* P3ib, ushort_t* P3ob, int Mn,
    const ushort_t* wentb, const float* bent, float* hent,
    const float* Wrel, const float* brel, float* outg,
    int nb_mf, int nb_ee, int nb_gm, int nb_we) {
  __shared__ float4 shbuf4[1024];   // 16KB union: smA|smB (mfma) / As (f32 gemm)
  ushort_t* smA = (ushort_t*)shbuf4;
  ushort_t* smB = smA + 64 * 64;
  float4 (*As)[25] = (float4(*)[25])shbuf4;
  int b = blockIdx.x, tid = threadIdx.x;
  if (b < nb_mf) {
    dev_mfma(b % 13, b / 13, tid, smA, smB, xnb, 128, wcat1, 128, N, 800, 200, nullptr,
             nullptr, PAb, PBb, PCb, PDb);
  } else if ((b -= nb_mf) < nb_ee) {
    dev_edge_e(b, tid, row, col, ety, qA, qB, q3i1, qC, qD, q3o1,
               invIn, invOut, eIc, eOc, E);
  } else if ((b -= nb_ee) < nb_gm) {
    dev_gemm_multi<2, 1>(b & 3, b >> 2, tid, As, g, 100, W1in200, W1out200, 300,
                         b1in, b1out, P3ib, P3ob, Mn);
  } else if ((b -= nb_gm) < nb_we) {
    dev_mfma(b & 3, b >> 2, tid, smA, smB, xnb, 128, wentb, 128, N, 200, 200, bent,
             hent, nullptr, nullptr, nullptr, nullptr);
  } else {
    b -= nb_we;
    dev_gemm_multi<1, 0>(b & 3, b >> 2, tid, As, g, 100, Wrel, nullptr, 100,
                         brel, nullptr, outg, nullptr, Mn);
  }
}

__global__ __launch_bounds__(256) void MEGA3(
    const ushort_t* h1b, const ushort_t* wcat2,
    ushort_t* PAb, ushort_t* PBb, ushort_t* PCb, ushort_t* PDb, int N,
    const int* row, const int* col, const int* ety,
    const float* qA, const float* qB, const float* q3i2,
    const float* qC, const float* qD, const float* q3o2,
    const int* invIn, const int* invOut, float2* eIc, float2* eOc, int E,
    const float* g, const float* W2in400, const float* W2out400,
    const float* b2in, const float* b2out, ushort_t* P3ib, ushort_t* P3ob, int Mn,
    int nb_mf, int nb_ee) {
  __shared__ float4 shbuf4[1024];
  ushort_t* smA = (ushort_t*)shbuf4;
  ushort_t* smB = smA + 64 * 64;
  float4 (*As)[25] = (float4(*)[25])shbuf4;
  int b = blockIdx.x, tid = threadIdx.x;
  if (b < nb_mf) {
    dev_mfma(b % 13, b / 13, tid, smA, smB, h1b, 256, wcat2, 256, N, 800, 200, nullptr,
             nullptr, PAb, PBb, PCb, PDb);
  } else if ((b -= nb_mf) < nb_ee) {
    dev_edge_e(b, tid, row, col, ety, qA, qB, q3i2, qC, qD, q3o2,
               invIn, invOut, eIc, eOc, E);
  } else {
    b -= nb_ee;
    dev_gemm_multi<2, 1>(b & 3, b >> 2, tid, As, g, 100, W2in400, W2out400, 500,
                         b2in, b2out, P3ib, P3ob, Mn);
  }
}

// ---------------- fused per-node attention: single wave, interleaved dual-direction ----------------
__global__ void k_node_att(const int2* __restrict__ pinIn, const float2* __restrict__ eIc,
                           const int* __restrict__ rsIn,
                           const int2* __restrict__ pinOut, const float2* __restrict__ eOc,
                           const int* __restrict__ rsOut,
                           const ushort_t* __restrict__ PAb, const ushort_t* __restrict__ PBb,
                           const ushort_t* __restrict__ PCb, const ushort_t* __restrict__ PDb,
                           const ushort_t* __restrict__ P3ib, const ushort_t* __restrict__ P3ob,
                           const float* __restrict__ Wg, const float* __restrict__ bg,
                           const float* __restrict__ u2in, const float* __restrict__ u2out,
                           float* __restrict__ qA, float* __restrict__ qB,
                           float* __restrict__ qC, float* __restrict__ qD,
                           ushort_t* __restrict__ Hb,
                           const float* __restrict__ hent, float* __restrict__ outp, int N) {
  int wid  = (int)((blockIdx.x * (unsigned)blockDim.x + threadIdx.x) >> 6);
  int lane = threadIdx.x & 63;
  if (wid >= N) return;
  int n = wid;
  int half = lane >> 5, i = lane & 31;
  bool act = i < 25;
  int j = half * 100 + i * 4;
  int sIn = rsIn[n], degIn = rsIn[n + 1] - sIn;
  int sOut = rsOut[n], degOut = rsOut[n + 1] - sOut;
  float4 accIn = {0.f, 0.f, 0.f, 0.f}, accOut = {0.f, 0.f, 0.f, 0.f};
  float dI0 = 0.f, dI1 = 0.f, dO0 = 0.f, dO1 = 0.f;
  int mx = max(degIn, degOut);
  for (int b = 0; b < mx; b += 64) {
    int l = b + lane;
    float2 evI = {0.f, 0.f}, evO = {0.f, 0.f};
    int2 ptI = {0, 0}, ptO = {0, 0};
    if (l < degIn)  { evI = eIc[sIn + l];  ptI = pinIn[sIn + l]; }
    if (l < degOut) { evO = eOc[sOut + l]; ptO = pinOut[sOut + l]; }
    dI0 += evI.x; dI1 += evI.y; dO0 += evO.x; dO1 += evO.y;
    int mI = degIn - b;  if (mI > 64) mI = 64;
    int mO = degOut - b; if (mO > 64) mO = 64;
    int m2 = max(mI, mO);
    for (int jj = 0; jj < m2; ++jj) {
      float aI0 = __shfl(evI.x, jj, 64), aI1 = __shfl(evI.y, jj, 64);
      int rI = __shfl(ptI.x, jj, 64), tI = __shfl(ptI.y, jj, 64);
      float aO0 = __shfl(evO.x, jj, 64), aO1 = __shfl(evO.y, jj, 64);
      int rO = __shfl(ptO.x, jj, 64), tO = __shfl(ptO.y, jj, 64);
      if (act && jj < mI) {
        float wgt = half ? aI1 : aI0;
        ushort4 pa = *(const ushort4*)(PAb + (size_t)rI * 200 + j);
        ushort4 p3 = *(const ushort4*)(P3ib + (size_t)tI * 200 + j);
        accIn.x += wgt * (bf2f(pa.x) + bf2f(p3.x));
        accIn.y += wgt * (bf2f(pa.y) + bf2f(p3.y));
        accIn.z += wgt * (bf2f(pa.z) + bf2f(p3.z));
        accIn.w += wgt * (bf2f(pa.w) + bf2f(p3.w));
      }
      if (act && jj < mO) {
        float wgt = half ? aO1 : aO0;
        ushort4 pd = *(const ushort4*)(PDb + (size_t)rO * 200 + j);
        ushort4 p3 = *(const ushort4*)(P3ob + (size_t)tO * 200 + j);
        accOut.x += wgt * (bf2f(pd.x) + bf2f(p3.x));
        accOut.y += wgt * (bf2f(pd.y) + bf2f(p3.y));
        accOut.z += wgt * (bf2f(pd.z) + bf2f(p3.z));
        accOut.w += wgt * (bf2f(pd.w) + bf2f(p3.w));
      }
    }
  }
#pragma unroll
  for (int m = 1; m < 64; m <<= 1) {
    dI0 += __shfl_xor(dI0, m, 64); dI1 += __shfl_xor(dI1, m, 64);
    dO0 += __shfl_xor(dO0, m, 64); dO1 += __shfl_xor(dO1, m, 64);
  }
  float4 hin = {0.f, 0.f, 0.f, 0.f}, hout = {0.f, 0.f, 0.f, 0.f};
  if (degIn > 0 && act) {
    float invd = 1.f / (half ? dI1 : dI0);
    ushort4 ps = *(const ushort4*)(PBb + (size_t)n * 200 + j);
    hin.x = elu1(bf2f(ps.x) + accIn.x * invd);
    hin.y = elu1(bf2f(ps.y) + accIn.y * invd);
    hin.z = elu1(bf2f(ps.z) + accIn.z * invd);
    hin.w = elu1(bf2f(ps.w) + accIn.w * invd);
  }
  if (degOut > 0 && act) {
    float invd = 1.f / (half ? dO1 : dO0);
    ushort4 ps = *(const ushort4*)(PCb + (size_t)n * 200 + j);
    hout.x = elu1(bf2f(ps.x) + accOut.x * invd);
    hout.y = elu1(bf2f(ps.y) + accOut.y * invd);
    hout.z = elu1(bf2f(ps.z) + accOut.z * invd);
    hout.w = elu1(bf2f(ps.w) + accOut.w * invd);
  }
  float gp = 0.f;
  if (act) {
    int k = i * 4;
    gp = Wg[k] * hin.x + Wg[k + 1] * hin.y + Wg[k + 2] * hin.z + Wg[k + 3] * hin.w +
         Wg[100 + k] * hout.x + Wg[100 + k + 1] * hout.y +
         Wg[100 + k + 2] * hout.z + Wg[100 + k + 3] * hout.w;
  }
#pragma unroll
  for (int m = 1; m < 32; m <<= 1) gp += __shfl_xor(gp, m, 32);
  float al = 1.f / (1.f + expf(-(gp + bg[0])));
  float4 he;
  he.x = elu1(al * hin.x + (1.f - al) * hout.x);
  he.y = elu1(al * hin.y + (1.f - al) * hout.y);
  he.z = elu1(al * hin.z + (1.f - al) * hout.z);
  he.w = elu1(al * hin.w + (1.f - al) * hout.w);
  float ss = he.x * he.x + he.y * he.y + he.z * he.z + he.w * he.w;
#pragma unroll
  for (int m = 1; m < 32; m <<= 1) ss += __shfl_xor(ss, m, 32);
  float inv = 1.f / fmaxf(sqrtf(ss), 1e-12f);
  float4 o = {he.x * inv, he.y * inv, he.z * inv, he.w * inv};
  if (Hb) {
    if (act) {
      ushort4 ov; ov.x = f2bf(o.x); ov.y = f2bf(o.y); ov.z = f2bf(o.z); ov.w = f2bf(o.w);
      *(ushort4*)(Hb + (size_t)n * 256 + j) = ov;
    } else {
      int pi = half * 7 + (i - 25);
      ushort4 z = {0, 0, 0, 0};
      *(ushort4*)(Hb + (size_t)n * 256 + 200 + pi * 4) = z;
    }
  }
  if (outp) {
    float4 v = {0.f, 0.f, 0.f, 0.f};
    if (act) {
      float4 hv = *(const float4*)(hent + (size_t)n * 200 + j);
      v.x = hv.x + o.x; v.y = hv.y + o.y; v.z = hv.z + o.z; v.w = hv.w + o.w;
    }
    float s2 = v.x * v.x + v.y * v.y + v.z * v.z + v.w * v.w;
#pragma unroll
    for (int m = 1; m < 32; m <<= 1) s2 += __shfl_xor(s2, m, 32);
    float inv2 = 1.f / fmaxf(sqrtf(s2), 1e-12f);
    if (act) {
      float4 ov = {v.x * inv2, v.y * inv2, v.z * inv2, v.w * inv2};
      *(float4*)(outp + (size_t)n * 200 + j) = ov;
    }
  }
  if (u2in) {
    float4 ov = act ? o : make_float4(0.f, 0.f, 0.f, 0.f);
    float s[8];
#pragma unroll
    for (int h = 0; h < 2; ++h) {
      float4 uA = *(const float4*)(u2in + h * 500 + j);
      float4 uB = *(const float4*)(u2in + h * 500 + 200 + j);
      float4 uC = *(const float4*)(u2out + h * 500 + j);
      float4 uD = *(const float4*)(u2out + h * 500 + 200 + j);
      s[0 + h] = ov.x * uA.x + ov.y * uA.y + ov.z * uA.z + ov.w * uA.w;
      s[2 + h] = ov.x * uB.x + ov.y * uB.y + ov.z * uB.z + ov.w * uB.w;
      s[4 + h] = ov.x * uC.x + ov.y * uC.y + ov.z * uC.z + ov.w * uC.w;
      s[6 + h] = ov.x * uD.x + ov.y * uD.y + ov.z * uD.z + ov.w * uD.w;
    }
#pragma unroll
    for (int m = 1; m < 64; m <<= 1) {
#pragma unroll
      for (int ii = 0; ii < 8; ++ii) s[ii] += __shfl_xor(s[ii], m, 64);
    }
    if (lane == 0) {
      qA[n * 2] = s[0]; qA[n * 2 + 1] = s[1];
      qB[n * 2] = s[2]; qB[n * 2 + 1] = s[3];
      qC[n * 2] = s[4]; qC[n * 2 + 1] = s[5];
      qD[n * 2] = s[6]; qD[n * 2 + 1] = s[7];
    }
  }
}

extern "C" void kernel_launch(void* const* d_in, const int* in_sizes, int n_in,
                              void* d_out, int out_size, void* d_ws, size_t ws_size,
                              hipStream_t stream) {
  const float* x    = (const float*)d_in[0];
  const float* g    = (const float*)d_in[1];
  const float* W1in = (const float*)d_in[2];
  const float* b1in = (const float*)d_in[3];
  const float* a1in = (const float*)d_in[4];
  const float* W1out= (const float*)d_in[5];
  const float* b1out= (const float*)d_in[6];
  const float* a1out= (const float*)d_in[7];
  const float* Wa1  = (const float*)d_in[8];
  const float* ba1  = (const float*)d_in[9];
  const float* W2in = (const float*)d_in[10];
  const float* b2in = (const float*)d_in[11];
  const float* a2in = (const float*)d_in[12];
  const float* W2out= (const float*)d_in[13];
  const float* b2out= (const float*)d_in[14];
  const float* a2out= (const float*)d_in[15];
  const float* Wa2  = (const float*)d_in[16];
  const float* ba2  = (const float*)d_in[17];
  const float* Went = (const float*)d_in[18];
  const float* bent = (const float*)d_in[19];
  const float* Wrel = (const float*)d_in[20];
  const float* brel = (const float*)d_in[21];
  const int*  eidx  = (const int*)d_in[22];
  const int*  ety   = (const int*)d_in[23];

  const int N = in_sizes[0] / 100;
  const int M = in_sizes[1] / 100;
  const int E = in_sizes[23];
  const int* row = eidx;
  const int* col = eidx + E;
  float* out = (float*)d_out;

  float* ws = (float*)d_ws;
  size_t off = 0;
  auto alloc = [&](size_t nf) { float* p = ws + off; off += (nf + 3) & ~(size_t)3; return p; };
  ushort_t* PAb = (ushort_t*)alloc((size_t)N * 100);
  ushort_t* PBb = (ushort_t*)alloc((size_t)N * 100);
  ushort_t* PCb = (ushort_t*)alloc((size_t)N * 100);
  ushort_t* PDb = (ushort_t*)alloc((size_t)N * 100);
  ushort_t* P3ib = (ushort_t*)alloc((size_t)M * 100);
  ushort_t* P3ob = (ushort_t*)alloc((size_t)M * 100);
  ushort_t* xnb = (ushort_t*)alloc((size_t)N * 64);
  ushort_t* h1b = (ushort_t*)alloc((size_t)N * 128);
  ushort_t* wcat1 = (ushort_t*)alloc((size_t)832 * 64);
  ushort_t* wcat2 = (ushort_t*)alloc((size_t)832 * 128);
  ushort_t* wentb = (ushort_t*)alloc((size_t)256 * 64);
  float* qA  = alloc((size_t)N * 2);
  float* qB  = alloc((size_t)N * 2);
  float* qC  = alloc((size_t)N * 2);
  float* qD  = alloc((size_t)N * 2);
  float* q3i1 = alloc((size_t)M * 2);
  float* q3o1 = alloc((size_t)M * 2);
  float* q3i2 = alloc((size_t)M * 2);
  float* q3o2 = alloc((size_t)M * 2);
  float2* eIc = (float2*)alloc((size_t)E * 2);
  float2* eOc = (float2*)alloc((size_t)E * 2);
  int2* pinIn  = (int2*)alloc((size_t)E * 2);
  int2* pinOut = (int2*)alloc((size_t)E * 2);
  int* invIn  = (int*)alloc((size_t)E);
  int* invOut = (int*)alloc((size_t)E);
  float* hent = alloc((size_t)N * 200);
  float* u1in  = alloc(600);
  float* u1out = alloc(600);
  float* u2in  = alloc(1000);
  float* u2out = alloc(1000);
  int* cntIn  = (int*)alloc((size_t)N);
  int* cntOut = (int*)alloc((size_t)N);
  int* rsIn   = (int*)alloc((size_t)N + 1);
  int* rsOut  = (int*)alloc((size_t)N + 1);
  int* posIn  = (int*)alloc((size_t)N);
  int* posOut = (int*)alloc((size_t)N);
  int* part   = (int*)alloc((size_t)512);

  const int gN4 = (N + 3) / 4;
  const int gE  = (E + 255) / 256;
  const int mT  = (N + 63) / 64;
  const int nbc = (N + 255) / 256;

  const int nb_bw = (832 * 128 + 832 * 256 + 256 * 128 + 255) / 256;
  const int nb_mk = 13;
  const int nb_z  = (2 * N + 255) / 256;
  const int nb_l2 = gN4;
  const int nb_qr = (2 * M + 3) / 4;
  const int nb_mf = 13 * mT;
  const int nb_gm = 4 * ((M + 31) / 32);
  const int nb_we = 4 * mT;

  MEGA0<<<nb_bw + nb_mk + nb_z, 256, 0, stream>>>(
      W1in, W1out, W2in, W2out, Went, wcat1, wcat2, wentb,
      a1in, a1out, a2in, a2out, u1in, u1out, u2in, u2out,
      cntIn, cntOut, N, nb_bw, nb_mk);

  MEGA1<<<nb_l2 + nb_qr + gE, 256, 0, stream>>>(
      x, xnb, u1in, u1out, qA, qB, qC, qD, N,
      g, u2in, u2out, q3i1, q3o1, q3i2, q3o2, M,
      row, col, cntIn, cntOut, E, nb_l2, nb_qr);

  k_scanA<<<2 * nbc, 256, 0, stream>>>(cntIn, cntOut, part, N, nbc);
  k_scanB<<<1, 256, 0, stream>>>(part, rsIn, rsOut, nbc, N);
  k_scanC<<<2 * nbc, 256, 0, stream>>>(cntIn, cntOut, part, rsIn, rsOut, posIn, posOut, N, nbc);
  k_fill<<<gE, 256, 0, stream>>>(row, col, ety, posIn, posOut, pinIn, pinOut, invIn, invOut, E);

  MEGA2<<<nb_mf + gE + nb_gm + nb_we + nb_gm, 256, 0, stream>>>(
      xnb, wcat1, PAb, PBb, PCb, PDb, N,
      row, col, ety, qA, qB, q3i1, qC, qD, q3o1, invIn, invOut, eIc, eOc, E,
      g, W1in + 200, W1out + 200, b1in, b1out, P3ib, P3ob, M,
      wentb, bent, hent, Wrel, brel, out + (size_t)N * 200,
      nb_mf, gE, nb_gm, nb_we);

  k_node_att<<<gN4, 256, 0, stream>>>(pinIn, eIc, rsIn, pinOut, eOc, rsOut,
                                      PAb, PBb, PCb, PDb, P3ib, P3ob, Wa1, ba1,
                                      u2in, u2out, qA, qB, qC, qD,
                                      h1b, nullptr, nullptr, N);

  MEGA3<<<nb_mf + gE + nb_gm, 256, 0, stream>>>(
      h1b, wcat2, PAb, PBb, PCb, PDb, N,
      row, col, ety, qA, qB, q3i2, qC, qD, q3o2, invIn, invOut, eIc, eOc, E,
      g, W2in + 400, W2out + 400, b2in, b2out, P3ib, P3ob, M,
      nb_mf, gE);

  k_node_att<<<gN4, 256, 0, stream>>>(pinIn, eIc, rsIn, pinOut, eOc, rsOut,
                                      PAb, PBb, PCb, PDb, P3ib, P3ob, Wa2, ba2,
                                      nullptr, nullptr, qA, qB, qC, qD,
                                      nullptr, hent, out, N);
}

// Round 13
// 186.629 us; speedup vs baseline: 1.4847x; 1.0732x over previous
//
#include <hip/hip_runtime.h>
#include <math.h>

#define NSLOPE 0.2f

typedef unsigned short ushort_t;
typedef __attribute__((ext_vector_type(8))) short bf16x8;
typedef __attribute__((ext_vector_type(8))) unsigned short ushort8;
typedef __attribute__((ext_vector_type(4))) float f32x4;

__device__ __forceinline__ float elu1(float x) { return x > 0.f ? x : expm1f(x); }

__device__ __forceinline__ ushort_t f2bf(float f) {
  union { float f; unsigned int u; } v; v.f = f;
  unsigned int r = v.u + 0x7fffu + ((v.u >> 16) & 1u);
  return (ushort_t)(r >> 16);
}
__device__ __forceinline__ float bf2f(ushort_t u) {
  union { unsigned int i; float f; } v; v.i = ((unsigned int)u) << 16; return v.f;
}

// ================= device bodies =================

__device__ void dev_build_w(int idx,
                            const float* __restrict__ W1in, const float* __restrict__ W1out,
                            const float* __restrict__ W2in, const float* __restrict__ W2out,
                            const float* __restrict__ Went,
                            ushort_t* __restrict__ wcat1, ushort_t* __restrict__ wcat2,
                            ushort_t* __restrict__ wentb) {
  const int S1 = 832 * 128, S2 = 832 * 256, S3 = 256 * 128;
  if (idx < S1) {
    int ro = idx >> 7, k = idx & 127;
    float val = 0.f;
    if (ro < 800 && k < 100) {
      int o = ro / 200, cc = ro - o * 200;
      const float* W = (o < 2) ? W1in : W1out;
      val = W[(size_t)cc * 300 + (o & 1) * 100 + k];
    }
    wcat1[idx] = f2bf(val);
  } else if (idx < S1 + S2) {
    int i2 = idx - S1;
    int ro = i2 >> 8, k = i2 & 255;
    float val = 0.f;
    if (ro < 800 && k < 200) {
      int o = ro / 200, cc = ro - o * 200;
      const float* W = (o < 2) ? W2in : W2out;
      val = W[(size_t)cc * 500 + (o & 1) * 200 + k];
    }
    wcat2[i2] = f2bf(val);
  } else if (idx < S1 + S2 + S3) {
    int i3 = idx - S1 - S2;
    int ro = i3 >> 7, k = i3 & 127;
    float val = (ro < 200 && k < 100) ? Went[ro * 100 + k] : 0.f;
    wentb[i3] = f2bf(val);
  }
}

__device__ void dev_makeu(int idx,
                          const float* __restrict__ W1in, const float* __restrict__ a1in,
                          const float* __restrict__ W1out, const float* __restrict__ a1out,
                          const float* __restrict__ W2in, const float* __restrict__ a2in,
                          const float* __restrict__ W2out, const float* __restrict__ a2out,
                          float* __restrict__ u1in, float* __restrict__ u1out,
                          float* __restrict__ u2in, float* __restrict__ u2out) {
  if (idx >= 3200) return;
  const float* W; const float* avec; float* u; int Kp, local;
  if (idx < 600)       { W = W1in;  avec = a1in;  u = u1in;  Kp = 300; local = idx; }
  else if (idx < 1200) { W = W1out; avec = a1out; u = u1out; Kp = 300; local = idx - 600; }
  else if (idx < 2200) { W = W2in;  avec = a2in;  u = u2in;  Kp = 500; local = idx - 1200; }
  else                 { W = W2out; avec = a2out; u = u2out; Kp = 500; local = idx - 2200; }
  int h = local / Kp, kp = local - h * Kp;
  const float* Wb = W + (size_t)(h * 100) * Kp + kp;
  const float* ab = avec + h * 100;
  float s = 0.f;
  for (int k = 0; k < 100; ++k) s += ab[k] * Wb[(size_t)k * Kp];
  u[local] = s;
}

__device__ void dev_l2norm_q(int bb, int tid, const float* __restrict__ x,
                             ushort_t* __restrict__ xnb,
                             const float* __restrict__ u1in, const float* __restrict__ u1out,
                             float* __restrict__ qA, float* __restrict__ qB,
                             float* __restrict__ qC, float* __restrict__ qD, int N) {
  int wid = bb * 4 + (tid >> 6);
  int lane = tid & 63;
  if (wid >= N) return;
  const float* p = x + (size_t)wid * 100;
  float v0 = p[lane];
  bool t2 = lane < 36;
  float v1 = t2 ? p[lane + 64] : 0.f;
  float ss = v0 * v0 + v1 * v1;
#pragma unroll
  for (int m = 1; m < 64; m <<= 1) ss += __shfl_xor(ss, m, 64);
  float inv = 1.f / fmaxf(sqrtf(ss), 1e-12f);
  float a0 = v0 * inv, a1 = v1 * inv;
  ushort_t* ob = xnb + (size_t)wid * 128;
  ob[lane] = f2bf(a0);
  ob[64 + lane] = t2 ? f2bf(a1) : (ushort_t)0;
  int k0 = lane, k1 = 64 + lane;
  float s[8];
  s[0] = a0 * u1in[k0]        + (t2 ? a1 * u1in[k1]        : 0.f);
  s[1] = a0 * u1in[300 + k0]  + (t2 ? a1 * u1in[300 + k1]  : 0.f);
  s[2] = a0 * u1in[100 + k0]  + (t2 ? a1 * u1in[100 + k1]  : 0.f);
  s[3] = a0 * u1in[400 + k0]  + (t2 ? a1 * u1in[400 + k1]  : 0.f);
  s[4] = a0 * u1out[k0]       + (t2 ? a1 * u1out[k1]       : 0.f);
  s[5] = a0 * u1out[300 + k0] + (t2 ? a1 * u1out[300 + k1] : 0.f);
  s[6] = a0 * u1out[100 + k0] + (t2 ? a1 * u1out[100 + k1] : 0.f);
  s[7] = a0 * u1out[400 + k0] + (t2 ? a1 * u1out[400 + k1] : 0.f);
#pragma unroll
  for (int m = 1; m < 64; m <<= 1) {
#pragma unroll
    for (int i = 0; i < 8; ++i) s[i] += __shfl_xor(s[i], m, 64);
  }
  if (lane == 0) {
    qA[wid * 2] = s[0]; qA[wid * 2 + 1] = s[1];
    qB[wid * 2] = s[2]; qB[wid * 2 + 1] = s[3];
    qC[wid * 2] = s[4]; qC[wid * 2 + 1] = s[5];
    qD[wid * 2] = s[6]; qD[wid * 2 + 1] = s[7];
  }
}

__device__ void dev_qrel2(int bb, int tid, const float* __restrict__ g,
                          const float* __restrict__ u1in, const float* __restrict__ u1out,
                          const float* __restrict__ u2in, const float* __restrict__ u2out,
                          float* __restrict__ q3i1, float* __restrict__ q3o1,
                          float* __restrict__ q3i2, float* __restrict__ q3o2, int Mn) {
  int wid = bb * 4 + (tid >> 6);
  int lane = tid & 63;
  if (wid >= 2 * Mn) return;
  int lay = wid >= Mn;
  int m = wid - lay * Mn;
  const float* uin  = lay ? u2in  : u1in;
  const float* uout = lay ? u2out : u1out;
  int Kp = lay ? 500 : 300;
  int off3 = lay ? 400 : 200;
  float* q3i = lay ? q3i2 : q3i1;
  float* q3o = lay ? q3o2 : q3o1;
  const float* a = g + (size_t)m * 100;
  float s[4] = {0.f, 0.f, 0.f, 0.f};
  for (int k = lane; k < 100; k += 64) {
    float av = a[k];
    s[0] += av * uin[off3 + k];
    s[1] += av * uin[Kp + off3 + k];
    s[2] += av * uout[off3 + k];
    s[3] += av * uout[Kp + off3 + k];
  }
#pragma unroll
  for (int mm = 1; mm < 64; mm <<= 1) {
#pragma unroll
    for (int i = 0; i < 4; ++i) s[i] += __shfl_xor(s[i], mm, 64);
  }
  if (lane == 0) {
    q3i[m * 2] = s[0]; q3i[m * 2 + 1] = s[1];
    q3o[m * 2] = s[2]; q3o[m * 2 + 1] = s[3];
  }
}

__device__ void dev_count(int bb, int tid, const int* __restrict__ row,
                          const int* __restrict__ col,
                          int* __restrict__ cntIn, int* __restrict__ cntOut, int E) {
  int e = bb * 256 + tid;
  if (e >= E) return;
  atomicAdd(&cntIn[col[e]], 1);
  atomicAdd(&cntOut[row[e]], 1);
}

// scatter e-values into low 8B of CSR-ordered 16B records
__device__ void dev_edge_e(int bb, int tid,
                           const int* __restrict__ row, const int* __restrict__ col,
                           const int* __restrict__ ety,
                           const float* __restrict__ qA, const float* __restrict__ qB,
                           const float* __restrict__ q3i,
                           const float* __restrict__ qC, const float* __restrict__ qD,
                           const float* __restrict__ q3o,
                           const int* __restrict__ invIn, const int* __restrict__ invOut,
                           float4* __restrict__ recI, float4* __restrict__ recO, int E) {
  int e = bb * 256 + tid;
  if (e >= E) return;
  int r = row[e], c = col[e], t = ety[e];
  float2 vA = *(const float2*)(qA + (size_t)r * 2);
  float2 vB = *(const float2*)(qB + (size_t)c * 2);
  float2 v3 = *(const float2*)(q3i + (size_t)t * 2);
  float2 vC = *(const float2*)(qC + (size_t)r * 2);
  float2 vD = *(const float2*)(qD + (size_t)c * 2);
  float2 v4 = *(const float2*)(q3o + (size_t)t * 2);
  float a0 = vA.x + vB.x + v3.x, a1 = vA.y + vB.y + v3.y;
  float b0 = vC.x + vD.x + v4.x, b1 = vC.y + vD.y + v4.y;
  float2 rI, rO;
  rI.x = expf(-(a0 > 0.f ? a0 : NSLOPE * a0));
  rI.y = expf(-(a1 > 0.f ? a1 : NSLOPE * a1));
  rO.x = expf(-(b0 > 0.f ? b0 : NSLOPE * b0));
  rO.y = expf(-(b1 > 0.f ? b1 : NSLOPE * b1));
  *(float2*)(recI + invIn[e]) = rI;
  *(float2*)(recO + invOut[e]) = rO;
}

// 64x64 MFMA GEMM tile (proven body)
__device__ void dev_mfma(int bx, int by, int tid,
                         ushort_t* __restrict__ smA, ushort_t* __restrict__ smB,
                         const ushort_t* __restrict__ Ab, int lda,
                         const ushort_t* __restrict__ Bb, int Kpad,
                         int R, int NC, int OUTW, const float* __restrict__ bias,
                         float* __restrict__ C0,
                         ushort_t* __restrict__ Bd0, ushort_t* __restrict__ Bd1,
                         ushort_t* __restrict__ Bd2, ushort_t* __restrict__ Bd3) {
  const int lane = tid & 63;
  const int w = tid >> 6;
  const int wm = w >> 1, wn = w & 1;
  const int m0 = by * 64;
  const int n0 = bx * 64;
  const int srow = tid >> 2;
  const int sq = tid & 3;
  const int sw3 = srow & 7;
  const int sbase = srow * 64;
  const int so0 = sbase + ((((sq << 1) + 0) ^ sw3) << 3);
  const int so1 = sbase + ((((sq << 1) + 1) ^ sw3) << 3);
  const bool aok = (m0 + srow) < R;
  const ushort_t* Ag = Ab + (size_t)(m0 + srow) * lda + sq * 16;
  const ushort_t* Bg = Bb + (size_t)(n0 + srow) * Kpad + sq * 16;
  const int lswz = lane & 7;
  const int hi = lane >> 4;
  const int rA0 = (wm * 32 + (lane & 15)) * 64;
  const int rB0 = (wn * 32 + (lane & 15)) * 64;
  f32x4 acc[2][2] = {};
  for (int k0 = 0; k0 < Kpad; k0 += 64) {
    ushort8 a0 = {0, 0, 0, 0, 0, 0, 0, 0}, a1 = {0, 0, 0, 0, 0, 0, 0, 0};
    if (aok) {
      a0 = *(const ushort8*)(Ag + k0);
      a1 = *(const ushort8*)(Ag + k0 + 8);
    }
    ushort8 b0 = *(const ushort8*)(Bg + k0);
    ushort8 b1 = *(const ushort8*)(Bg + k0 + 8);
    __syncthreads();
    *(ushort8*)(smA + so0) = a0;
    *(ushort8*)(smA + so1) = a1;
    *(ushort8*)(smB + so0) = b0;
    *(ushort8*)(smB + so1) = b1;
    __syncthreads();
#pragma unroll
    for (int ks = 0; ks < 2; ++ks) {
      int co = (((ks << 2) + hi) ^ lswz) << 3;
      bf16x8 aA = *(const bf16x8*)(smA + rA0 + co);
      bf16x8 aB = *(const bf16x8*)(smA + rA0 + 1024 + co);
      bf16x8 bA = *(const bf16x8*)(smB + rB0 + co);
      bf16x8 bB = *(const bf16x8*)(smB + rB0 + 1024 + co);
      acc[0][0] = __builtin_amdgcn_mfma_f32_16x16x32_bf16(aA, bA, acc[0][0], 0, 0, 0);
      acc[0][1] = __builtin_amdgcn_mfma_f32_16x16x32_bf16(aA, bB, acc[0][1], 0, 0, 0);
      acc[1][0] = __builtin_amdgcn_mfma_f32_16x16x32_bf16(aB, bA, acc[1][0], 0, 0, 0);
      acc[1][1] = __builtin_amdgcn_mfma_f32_16x16x32_bf16(aB, bB, acc[1][1], 0, 0, 0);
    }
  }
  ushort_t* Bds[4] = {Bd0, Bd1, Bd2, Bd3};
#pragma unroll
  for (int mt = 0; mt < 2; ++mt) {
    int rr0 = m0 + wm * 32 + mt * 16 + (lane >> 4) * 4;
#pragma unroll
    for (int nt = 0; nt < 2; ++nt) {
      int cc = n0 + wn * 32 + nt * 16 + (lane & 15);
      if (cc < NC) {
        int o = cc / OUTW;
        int c2 = cc - o * OUTW;
        float bv = bias ? bias[c2] : 0.f;
        ushort_t* Bd = Bds[o];
        if (Bd) {
#pragma unroll
          for (int reg = 0; reg < 4; ++reg) {
            int r = rr0 + reg;
            if (r < R) Bd[(size_t)r * OUTW + c2] = f2bf(acc[mt][nt][reg] + bv);
          }
        } else {
#pragma unroll
          for (int reg = 0; reg < 4; ++reg) {
            int r = rr0 + reg;
            if (r < R) C0[(size_t)r * OUTW + c2] = acc[mt][nt][reg] + bv;
          }
        }
      }
    }
  }
}

template <int NOUT, int BF>
__device__ void dev_gemm_multi(int bx, int by, int tid, float4 (*As)[25],
                               const float* __restrict__ A, int lda,
                               const float* __restrict__ W0, const float* __restrict__ W1,
                               int ldw,
                               const float* __restrict__ b0, const float* __restrict__ b1,
                               void* __restrict__ C0v, void* __restrict__ C1v, int R) {
  const int K4 = 25;
  int row0 = by * 32;
  {
    int r = tid >> 3;
    int rr = row0 + r;
    const float4* Ar = (const float4*)(A + (size_t)rr * lda);
    for (int k4 = (tid & 7); k4 < K4; k4 += 8)
      As[r][k4] = (rr < R) ? Ar[k4] : make_float4(0.f, 0.f, 0.f, 0.f);
  }
  __syncthreads();
  int c = bx * 64 + (tid & 63);
  if (c < 200) {
    int rb = (tid >> 6) << 3;
    const float4* Wr[NOUT];
    Wr[0] = (const float4*)(W0 + (size_t)c * ldw);
    if (NOUT > 1) Wr[1] = (const float4*)(W1 + (size_t)c * ldw);
    float acc[NOUT][8];
#pragma unroll
    for (int o = 0; o < NOUT; ++o)
#pragma unroll
      for (int i = 0; i < 8; ++i) acc[o][i] = 0.f;
#pragma unroll 2
    for (int k4 = 0; k4 < K4; ++k4) {
      float4 a[8];
#pragma unroll
      for (int i = 0; i < 8; ++i) a[i] = As[rb + i][k4];
#pragma unroll
      for (int o = 0; o < NOUT; ++o) {
        float4 wv = Wr[o][k4];
#pragma unroll
        for (int i = 0; i < 8; ++i)
          acc[o][i] += a[i].x * wv.x + a[i].y * wv.y + a[i].z * wv.z + a[i].w * wv.w;
      }
    }
    float bv[NOUT];
    bv[0] = b0 ? b0[c] : 0.f;
    if (NOUT > 1) bv[1] = b1 ? b1[c] : 0.f;
    void* Cp[NOUT];
    Cp[0] = C0v;
    if (NOUT > 1) Cp[1] = C1v;
#pragma unroll
    for (int i = 0; i < 8; ++i) {
      int rr = row0 + rb + i;
      if (rr < R) {
#pragma unroll
        for (int o = 0; o < NOUT; ++o) {
          float val = acc[o][i] + bv[o];
          if (BF) ((ushort_t*)Cp[o])[(size_t)rr * 200 + c] = f2bf(val);
          else    ((float*)Cp[o])[(size_t)rr * 200 + c] = val;
        }
      }
    }
  }
}

// ================= kernels =================

__global__ __launch_bounds__(256) void MEGA0(
    const float* W1in, const float* W1out, const float* W2in, const float* W2out,
    const float* Went,
    ushort_t* wcat1, ushort_t* wcat2, ushort_t* wentb,
    const float* a1in, const float* a1out, const float* a2in, const float* a2out,
    float* u1in, float* u1out, float* u2in, float* u2out,
    int* cntIn, int* cntOut, int N, int nb_bw, int nb_mk) {
  int b = blockIdx.x, tid = threadIdx.x;
  if (b < nb_bw) {
    dev_build_w(b * 256 + tid, W1in, W1out, W2in, W2out, Went, wcat1, wcat2, wentb);
  } else if (b < nb_bw + nb_mk) {
    dev_makeu((b - nb_bw) * 256 + tid, W1in, a1in, W1out, a1out, W2in, a2in, W2out, a2out,
              u1in, u1out, u2in, u2out);
  } else {
    int idx = (b - nb_bw - nb_mk) * 256 + tid;
    if (idx < N) cntIn[idx] = 0;
    else if (idx < 2 * N) cntOut[idx - N] = 0;
  }
}

__global__ __launch_bounds__(256) void MEGA1(
    const float* x, ushort_t* xnb, const float* u1in, const float* u1out,
    float* qA, float* qB, float* qC, float* qD, int N,
    const float* g, const float* u2in, const float* u2out,
    float* q3i1, float* q3o1, float* q3i2, float* q3o2, int Mn,
    const int* row, const int* col, int* cntIn, int* cntOut, int E,
    int nb_l2, int nb_qr) {
  int b = blockIdx.x, tid = threadIdx.x;
  if (b < nb_l2) {
    dev_l2norm_q(b, tid, x, xnb, u1in, u1out, qA, qB, qC, qD, N);
  } else if (b < nb_l2 + nb_qr) {
    dev_qrel2(b - nb_l2, tid, g, u1in, u1out, u2in, u2out, q3i1, q3o1, q3i2, q3o2, Mn);
  } else {
    dev_count(b - nb_l2 - nb_qr, tid, row, col, cntIn, cntOut, E);
  }
}

// ---- parallel 3-phase scan ----
__global__ __launch_bounds__(256) void k_scanA(const int* __restrict__ cntIn,
                                               const int* __restrict__ cntOut,
                                               int* __restrict__ part, int N, int nbc) {
  __shared__ int wsum[4];
  int b = blockIdx.x;
  const int* cnt = (b < nbc) ? cntIn : cntOut;
  int cb = (b < nbc) ? b : b - nbc;
  int idx = cb * 256 + threadIdx.x;
  int v = (idx < N) ? cnt[idx] : 0;
#pragma unroll
  for (int m = 1; m < 64; m <<= 1) v += __shfl_xor(v, m, 64);
  if ((threadIdx.x & 63) == 0) wsum[threadIdx.x >> 6] = v;
  __syncthreads();
  if (threadIdx.x == 0) part[b] = wsum[0] + wsum[1] + wsum[2] + wsum[3];
}

__global__ __launch_bounds__(256) void k_scanB(int* __restrict__ part,
                                               int* __restrict__ rsIn, int* __restrict__ rsOut,
                                               int nbc, int N) {
  __shared__ int buf[512];
  int t = threadIdx.x;
  buf[t]       = (t < nbc) ? part[t] : 0;
  buf[256 + t] = (t < nbc) ? part[nbc + t] : 0;
  __syncthreads();
  for (int off = 1; off < 256; off <<= 1) {
    int v0 = (t >= off) ? buf[t - off] : 0;
    int v1 = (t >= off) ? buf[256 + t - off] : 0;
    __syncthreads();
    buf[t] += v0; buf[256 + t] += v1;
    __syncthreads();
  }
  if (t < nbc) {
    part[t]       = (t == 0) ? 0 : buf[t - 1];
    part[nbc + t] = (t == 0) ? 0 : buf[256 + t - 1];
  }
  if (t == 0) { rsIn[N] = buf[nbc - 1]; rsOut[N] = buf[256 + nbc - 1]; }
}

__global__ __launch_bounds__(256) void k_scanC(const int* __restrict__ cntIn,
                                               const int* __restrict__ cntOut,
                                               const int* __restrict__ part,
                                               int* __restrict__ rsIn, int* __restrict__ rsOut,
                                               int* __restrict__ posIn, int* __restrict__ posOut,
                                               int N, int nbc) {
  __shared__ int buf[256];
  int b = blockIdx.x;
  const int* cnt = (b < nbc) ? cntIn : cntOut;
  int* rs  = (b < nbc) ? rsIn : rsOut;
  int* pos = (b < nbc) ? posIn : posOut;
  int cb = (b < nbc) ? b : b - nbc;
  int base = part[b];
  int t = threadIdx.x;
  int idx = cb * 256 + t;
  buf[t] = (idx < N) ? cnt[idx] : 0;
  __syncthreads();
  for (int off = 1; off < 256; off <<= 1) {
    int v = (t >= off) ? buf[t - off] : 0;
    __syncthreads();
    buf[t] += v;
    __syncthreads();
  }
  if (idx < N) {
    int excl = base + ((t == 0) ? 0 : buf[t - 1]);
    rs[idx] = excl; pos[idx] = excl;
  }
}

// fill CSR records: partner/type into high 8B of 16B records
__global__ void k_fill(const int* __restrict__ row, const int* __restrict__ col,
                       const int* __restrict__ ety,
                       int* __restrict__ posIn, int* __restrict__ posOut,
                       float4* __restrict__ recI, float4* __restrict__ recO,
                       int* __restrict__ invIn, int* __restrict__ invOut, int E) {
  int e = blockIdx.x * blockDim.x + threadIdx.x;
  if (e >= E) return;
  int r = row[e], c = col[e], tt = ety[e];
  int p = atomicAdd(&posIn[c], 1);
  ((int2*)(recI + p))[1] = make_int2(r, tt);
  invIn[e] = p;
  int q = atomicAdd(&posOut[r], 1);
  ((int2*)(recO + q))[1] = make_int2(c, tt);
  invOut[e] = q;
}

__global__ __launch_bounds__(256) void MEGA2(
    const ushort_t* xnb, const ushort_t* wcat1,
    ushort_t* PAb, ushort_t* PBb, ushort_t* PCb, ushort_t* PDb, int N,
    const int* row, const int* col, const int* ety,
    const float* qA, const float* qB, const float* q3i1,
    const float* qC, const float* qD, const float* q3o1,
    const int* invIn, const int* invOut, float4* recI, float4* recO, int E,
    const float* g, const float* W1in200, const float* W1out200,
    const float* b1in, const float* b1out, ushort_t* P3ib, ushort_t* P3ob,
    const float* W2in400, const float* W2out400,
    const float* b2in, const float* b2out, ushort_t* P3ib2, ushort_t* P3ob2, int Mn,
    const ushort_t* wentb, const float* bent, ushort_t* hentb,
    const float* Wrel, const float* brel, float* outg,
    int nb_mf, int nb_ee, int nb_gm, int nb_we) {
  __shared__ float4 shbuf4[1024];
  ushort_t* smA = (ushort_t*)shbuf4;
  ushort_t* smB = smA + 64 * 64;
  float4 (*As)[25] = (float4(*)[25])shbuf4;
  int b = blockIdx.x, tid = threadIdx.x;
  if (b < nb_mf) {
    dev_mfma(b % 13, b / 13, tid, smA, smB, xnb, 128, wcat1, 128, N, 800, 200, nullptr,
             nullptr, PAb, PBb, PCb, PDb);
  } else if ((b -= nb_mf) < nb_ee) {
    dev_edge_e(b, tid, row, col, ety, qA, qB, q3i1, qC, qD, q3o1,
               invIn, invOut, recI, recO, E);
  } else if ((b -= nb_ee) < nb_gm) {
    dev_gemm_multi<2, 1>(b & 3, b >> 2, tid, As, g, 100, W1in200, W1out200, 300,
                         b1in, b1out, P3ib, P3ob, Mn);
  } else if ((b -= nb_gm) < nb_gm) {
    dev_gemm_multi<2, 1>(b & 3, b >> 2, tid, As, g, 100, W2in400, W2out400, 500,
                         b2in, b2out, P3ib2, P3ob2, Mn);
  } else if ((b -= nb_gm) < nb_we) {
    dev_mfma(b & 3, b >> 2, tid, smA, smB, xnb, 128, wentb, 128, N, 200, 200, bent,
             nullptr, hentb, nullptr, nullptr, nullptr);
  } else {
    b -= nb_we;
    dev_gemm_multi<1, 0>(b & 3, b >> 2, tid, As, g, 100, Wrel, nullptr, 100,
                         brel, nullptr, outg, nullptr, Mn);
  }
}

__global__ __launch_bounds__(256) void MEGA3(
    const ushort_t* h1b, const ushort_t* wcat2,
    ushort_t* PAb, ushort_t* PBb, ushort_t* PCb, ushort_t* PDb, int N,
    const int* row, const int* col, const int* ety,
    const float* qA, const float* qB, const float* q3i2,
    const float* qC, const float* qD, const float* q3o2,
    const int* invIn, const int* invOut, float4* recI, float4* recO, int E,
    int nb_mf) {
  __shared__ float4 shbuf4[1024];
  ushort_t* smA = (ushort_t*)shbuf4;
  ushort_t* smB = smA + 64 * 64;
  int b = blockIdx.x, tid = threadIdx.x;
  if (b < nb_mf) {
    dev_mfma(b % 13, b / 13, tid, smA, smB, h1b, 256, wcat2, 256, N, 800, 200, nullptr,
             nullptr, PAb, PBb, PCb, PDb);
  } else {
    dev_edge_e(b - nb_mf, tid, row, col, ety, qA, qB, q3i2, qC, qD, q3o2,
               invIn, invOut, recI, recO, E);
  }
}

// ---------------- fused per-node attention (R8 loop + LDS record broadcast) ----------------
__global__ void k_node_att(const float4* __restrict__ recI, const int* __restrict__ rsIn,
                           const float4* __restrict__ recO, const int* __restrict__ rsOut,
                           const ushort_t* __restrict__ PAb, const ushort_t* __restrict__ PBb,
                           const ushort_t* __restrict__ PCb, const ushort_t* __restrict__ PDb,
                           const ushort_t* __restrict__ P3ib, const ushort_t* __restrict__ P3ob,
                           const float* __restrict__ Wg, const float* __restrict__ bg,
                           const float* __restrict__ u2in, const float* __restrict__ u2out,
                           float* __restrict__ qA, float* __restrict__ qB,
                           float* __restrict__ qC, float* __restrict__ qD,
                           ushort_t* __restrict__ Hb,
                           const ushort_t* __restrict__ hentb, float* __restrict__ outp, int N) {
  __shared__ float4 sRecI[4][64];
  __shared__ float4 sRecO[4][64];
  int wv = threadIdx.x >> 6;
  int wid  = (int)((blockIdx.x * (unsigned)blockDim.x + threadIdx.x) >> 6);
  int lane = threadIdx.x & 63;
  if (wid >= N) return;
  int n = wid;
  int half = lane >> 5, i = lane & 31;
  bool act = i < 25;
  int j = half * 100 + i * 4;
  int sIn = rsIn[n], degIn = rsIn[n + 1] - sIn;
  int sOut = rsOut[n], degOut = rsOut[n + 1] - sOut;
  float4 accIn = {0.f, 0.f, 0.f, 0.f}, accOut = {0.f, 0.f, 0.f, 0.f};
  float dI0 = 0.f, dI1 = 0.f, dO0 = 0.f, dO1 = 0.f;
  int mx = max(degIn, degOut);
  for (int b = 0; b < mx; b += 64) {
    int l = b + lane;
    if (l < degIn) {
      float4 rc = recI[sIn + l];
      dI0 += rc.x; dI1 += rc.y;
      sRecI[wv][lane] = rc;
    }
    if (l < degOut) {
      float4 rc = recO[sOut + l];
      dO0 += rc.x; dO1 += rc.y;
      sRecO[wv][lane] = rc;
    }
    int mI = degIn - b;  if (mI > 64) mI = 64;
    int mO = degOut - b; if (mO > 64) mO = 64;
    int m2 = max(mI, mO);
    for (int jj = 0; jj < m2; ++jj) {
      if (act && jj < mI) {
        float4 rc = sRecI[wv][jj];
        int rI = __float_as_int(rc.z), tI = __float_as_int(rc.w);
        float wgt = half ? rc.y : rc.x;
        ushort4 pa = *(const ushort4*)(PAb + (size_t)rI * 200 + j);
        ushort4 p3 = *(const ushort4*)(P3ib + (size_t)tI * 200 + j);
        accIn.x += wgt * (bf2f(pa.x) + bf2f(p3.x));
        accIn.y += wgt * (bf2f(pa.y) + bf2f(p3.y));
        accIn.z += wgt * (bf2f(pa.z) + bf2f(p3.z));
        accIn.w += wgt * (bf2f(pa.w) + bf2f(p3.w));
      }
      if (act && jj < mO) {
        float4 rc = sRecO[wv][jj];
        int rO = __float_as_int(rc.z), tO = __float_as_int(rc.w);
        float wgt = half ? rc.y : rc.x;
        ushort4 pd = *(const ushort4*)(PDb + (size_t)rO * 200 + j);
        ushort4 p3 = *(const ushort4*)(P3ob + (size_t)tO * 200 + j);
        accOut.x += wgt * (bf2f(pd.x) + bf2f(p3.x));
        accOut.y += wgt * (bf2f(pd.y) + bf2f(p3.y));
        accOut.z += wgt * (bf2f(pd.z) + bf2f(p3.z));
        accOut.w += wgt * (bf2f(pd.w) + bf2f(p3.w));
      }
    }
  }
#pragma unroll
  for (int m = 1; m < 64; m <<= 1) {
    dI0 += __shfl_xor(dI0, m, 64); dI1 += __shfl_xor(dI1, m, 64);
    dO0 += __shfl_xor(dO0, m, 64); dO1 += __shfl_xor(dO1, m, 64);
  }
  float4 hin = {0.f, 0.f, 0.f, 0.f}, hout = {0.f, 0.f, 0.f, 0.f};
  if (degIn > 0 && act) {
    float invd = 1.f / (half ? dI1 : dI0);
    ushort4 ps = *(const ushort4*)(PBb + (size_t)n * 200 + j);
    hin.x = elu1(bf2f(ps.x) + accIn.x * invd);
    hin.y = elu1(bf2f(ps.y) + accIn.y * invd);
    hin.z = elu1(bf2f(ps.z) + accIn.z * invd);
    hin.w = elu1(bf2f(ps.w) + accIn.w * invd);
  }
  if (degOut > 0 && act) {
    float invd = 1.f / (half ? dO1 : dO0);
    ushort4 ps = *(const ushort4*)(PCb + (size_t)n * 200 + j);
    hout.x = elu1(bf2f(ps.x) + accOut.x * invd);
    hout.y = elu1(bf2f(ps.y) + accOut.y * invd);
    hout.z = elu1(bf2f(ps.z) + accOut.z * invd);
    hout.w = elu1(bf2f(ps.w) + accOut.w * invd);
  }
  float gp = 0.f;
  if (act) {
    int k = i * 4;
    gp = Wg[k] * hin.x + Wg[k + 1] * hin.y + Wg[k + 2] * hin.z + Wg[k + 3] * hin.w +
         Wg[100 + k] * hout.x + Wg[100 + k + 1] * hout.y +
         Wg[100 + k + 2] * hout.z + Wg[100 + k + 3] * hout.w;
  }
#pragma unroll
  for (int m = 1; m < 32; m <<= 1) gp += __shfl_xor(gp, m, 32);
  float al = 1.f / (1.f + expf(-(gp + bg[0])));
  float4 he;
  he.x = elu1(al * hin.x + (1.f - al) * hout.x);
  he.y = elu1(al * hin.y + (1.f - al) * hout.y);
  he.z = elu1(al * hin.z + (1.f - al) * hout.z);
  he.w = elu1(al * hin.w + (1.f - al) * hout.w);
  float ss = he.x * he.x + he.y * he.y + he.z * he.z + he.w * he.w;
#pragma unroll
  for (int m = 1; m < 32; m <<= 1) ss += __shfl_xor(ss, m, 32);
  float inv = 1.f / fmaxf(sqrtf(ss), 1e-12f);
  float4 o = {he.x * inv, he.y * inv, he.z * inv, he.w * inv};
  if (Hb) {
    if (act) {
      ushort4 ov; ov.x = f2bf(o.x); ov.y = f2bf(o.y); ov.z = f2bf(o.z); ov.w = f2bf(o.w);
      *(ushort4*)(Hb + (size_t)n * 256 + j) = ov;
    } else {
      int pi = half * 7 + (i - 25);
      ushort4 z = {0, 0, 0, 0};
      *(ushort4*)(Hb + (size_t)n * 256 + 200 + pi * 4) = z;
    }
  }
  if (outp) {
    float4 v = {0.f, 0.f, 0.f, 0.f};
    if (act) {
      ushort4 hv = *(const ushort4*)(hentb + (size_t)n * 200 + j);
      v.x = bf2f(hv.x) + o.x; v.y = bf2f(hv.y) + o.y;
      v.z = bf2f(hv.z) + o.z; v.w = bf2f(hv.w) + o.w;
    }
    float s2 = v.x * v.x + v.y * v.y + v.z * v.z + v.w * v.w;
#pragma unroll
    for (int m = 1; m < 32; m <<= 1) s2 += __shfl_xor(s2, m, 32);
    float inv2 = 1.f / fmaxf(sqrtf(s2), 1e-12f);
    if (act) {
      float4 ov = {v.x * inv2, v.y * inv2, v.z * inv2, v.w * inv2};
      *(float4*)(outp + (size_t)n * 200 + j) = ov;
    }
  }
  if (u2in) {
    float4 ov = act ? o : make_float4(0.f, 0.f, 0.f, 0.f);
    float s[8];
#pragma unroll
    for (int h = 0; h < 2; ++h) {
      float4 uA = *(const float4*)(u2in + h * 500 + j);
      float4 uB = *(const float4*)(u2in + h * 500 + 200 + j);
      float4 uC = *(const float4*)(u2out + h * 500 + j);
      float4 uD = *(const float4*)(u2out + h * 500 + 200 + j);
      s[0 + h] = ov.x * uA.x + ov.y * uA.y + ov.z * uA.z + ov.w * uA.w;
      s[2 + h] = ov.x * uB.x + ov.y * uB.y + ov.z * uB.z + ov.w * uB.w;
      s[4 + h] = ov.x * uC.x + ov.y * uC.y + ov.z * uC.z + ov.w * uC.w;
      s[6 + h] = ov.x * uD.x + ov.y * uD.y + ov.z * uD.z + ov.w * uD.w;
    }
#pragma unroll
    for (int m = 1; m < 64; m <<= 1) {
#pragma unroll
      for (int ii = 0; ii < 8; ++ii) s[ii] += __shfl_xor(s[ii], m, 64);
    }
    if (lane == 0) {
      qA[n * 2] = s[0]; qA[n * 2 + 1] = s[1];
      qB[n * 2] = s[2]; qB[n * 2 + 1] = s[3];
      qC[n * 2] = s[4]; qC[n * 2 + 1] = s[5];
      qD[n * 2] = s[6]; qD[n * 2 + 1] = s[7];
    }
  }
}

extern "C" void kernel_launch(void* const* d_in, const int* in_sizes, int n_in,
                              void* d_out, int out_size, void* d_ws, size_t ws_size,
                              hipStream_t stream) {
  const float* x    = (const float*)d_in[0];
  const float* g    = (const float*)d_in[1];
  const float* W1in = (const float*)d_in[2];
  const float* b1in = (const float*)d_in[3];
  const float* a1in = (const float*)d_in[4];
  const float* W1out= (const float*)d_in[5];
  const float* b1out= (const float*)d_in[6];
  const float* a1out= (const float*)d_in[7];
  const float* Wa1  = (const float*)d_in[8];
  const float* ba1  = (const float*)d_in[9];
  const float* W2in = (const float*)d_in[10];
  const float* b2in = (const float*)d_in[11];
  const float* a2in = (const float*)d_in[12];
  const float* W2out= (const float*)d_in[13];
  const float* b2out= (const float*)d_in[14];
  const float* a2out= (const float*)d_in[15];
  const float* Wa2  = (const float*)d_in[16];
  const float* ba2  = (const float*)d_in[17];
  const float* Went = (const float*)d_in[18];
  const float* bent = (const float*)d_in[19];
  const float* Wrel = (const float*)d_in[20];
  const float* brel = (const float*)d_in[21];
  const int*  eidx  = (const int*)d_in[22];
  const int*  ety   = (const int*)d_in[23];

  const int N = in_sizes[0] / 100;
  const int M = in_sizes[1] / 100;
  const int E = in_sizes[23];
  const int* row = eidx;
  const int* col = eidx + E;
  float* out = (float*)d_out;

  float* ws = (float*)d_ws;
  size_t off = 0;
  auto alloc = [&](size_t nf) { float* p = ws + off; off += (nf + 3) & ~(size_t)3; return p; };
  float4* recI = (float4*)alloc((size_t)E * 4);
  float4* recO = (float4*)alloc((size_t)E * 4);
  ushort_t* PAb = (ushort_t*)alloc((size_t)N * 100);
  ushort_t* PBb = (ushort_t*)alloc((size_t)N * 100);
  ushort_t* PCb = (ushort_t*)alloc((size_t)N * 100);
  ushort_t* PDb = (ushort_t*)alloc((size_t)N * 100);
  ushort_t* P3ib = (ushort_t*)alloc((size_t)M * 100);
  ushort_t* P3ob = (ushort_t*)alloc((size_t)M * 100);
  ushort_t* P3ib2 = (ushort_t*)alloc((size_t)M * 100);
  ushort_t* P3ob2 = (ushort_t*)alloc((size_t)M * 100);
  ushort_t* xnb = (ushort_t*)alloc((size_t)N * 64);
  ushort_t* h1b = (ushort_t*)alloc((size_t)N * 128);
  ushort_t* hentb = (ushort_t*)alloc((size_t)N * 100);
  ushort_t* wcat1 = (ushort_t*)alloc((size_t)832 * 64);
  ushort_t* wcat2 = (ushort_t*)alloc((size_t)832 * 128);
  ushort_t* wentb = (ushort_t*)alloc((size_t)256 * 64);
  float* qA  = alloc((size_t)N * 2);
  float* qB  = alloc((size_t)N * 2);
  float* qC  = alloc((size_t)N * 2);
  float* qD  = alloc((size_t)N * 2);
  float* q3i1 = alloc((size_t)M * 2);
  float* q3o1 = alloc((size_t)M * 2);
  float* q3i2 = alloc((size_t)M * 2);
  float* q3o2 = alloc((size_t)M * 2);
  int* invIn  = (int*)alloc((size_t)E);
  int* invOut = (int*)alloc((size_t)E);
  float* u1in  = alloc(600);
  float* u1out = alloc(600);
  float* u2in  = alloc(1000);
  float* u2out = alloc(1000);
  int* cntIn  = (int*)alloc((size_t)N);
  int* cntOut = (int*)alloc((size_t)N);
  int* rsIn   = (int*)alloc((size_t)N + 1);
  int* rsOut  = (int*)alloc((size_t)N + 1);
  int* posIn  = (int*)alloc((size_t)N);
  int* posOut = (int*)alloc((size_t)N);
  int* part   = (int*)alloc((size_t)512);

  const int gN4 = (N + 3) / 4;
  const int gE  = (E + 255) / 256;
  const int mT  = (N + 63) / 64;
  const int nbc = (N + 255) / 256;

  const int nb_bw = (832 * 128 + 832 * 256 + 256 * 128 + 255) / 256;
  const int nb_mk = 13;
  const int nb_z  = (2 * N + 255) / 256;
  const int nb_l2 = gN4;
  const int nb_qr = (2 * M + 3) / 4;
  const int nb_mf = 13 * mT;
  const int nb_gm = 4 * ((M + 31) / 32);
  const int nb_we = 4 * mT;

  MEGA0<<<nb_bw + nb_mk + nb_z, 256, 0, stream>>>(
      W1in, W1out, W2in, W2out, Went, wcat1, wcat2, wentb,
      a1in, a1out, a2in, a2out, u1in, u1out, u2in, u2out,
      cntIn, cntOut, N, nb_bw, nb_mk);

  MEGA1<<<nb_l2 + nb_qr + gE, 256, 0, stream>>>(
      x, xnb, u1in, u1out, qA, qB, qC, qD, N,
      g, u2in, u2out, q3i1, q3o1, q3i2, q3o2, M,
      row, col, cntIn, cntOut, E, nb_l2, nb_qr);

  k_scanA<<<2 * nbc, 256, 0, stream>>>(cntIn, cntOut, part, N, nbc);
  k_scanB<<<1, 256, 0, stream>>>(part, rsIn, rsOut, nbc, N);
  k_scanC<<<2 * nbc, 256, 0, stream>>>(cntIn, cntOut, part, rsIn, rsOut, posIn, posOut, N, nbc);
  k_fill<<<gE, 256, 0, stream>>>(row, col, ety, posIn, posOut, recI, recO, invIn, invOut, E);

  MEGA2<<<nb_mf + gE + nb_gm * 3 + nb_we, 256, 0, stream>>>(
      xnb, wcat1, PAb, PBb, PCb, PDb, N,
      row, col, ety, qA, qB, q3i1, qC, qD, q3o1, invIn, invOut, recI, recO, E,
      g, W1in + 200, W1out + 200, b1in, b1out, P3ib, P3ob,
      W2in + 400, W2out + 400, b2in, b2out, P3ib2, P3ob2, M,
      wentb, bent, hentb, Wrel, brel, out + (size_t)N * 200,
      nb_mf, gE, nb_gm, nb_we);

  k_node_att<<<gN4, 256, 0, stream>>>(recI, rsIn, recO, rsOut,
                                      PAb, PBb, PCb, PDb, P3ib, P3ob, Wa1, ba1,
                                      u2in, u2out, qA, qB, qC, qD,
                                      h1b, nullptr, nullptr, N);

  MEGA3<<<nb_mf + gE, 256, 0, stream>>>(
      h1b, wcat2, PAb, PBb, PCb, PDb, N,
      row, col, ety, qA, qB, q3i2, qC, qD, q3o2, invIn, invOut, recI, recO, E,
      nb_mf);

  k_node_att<<<gN4, 256, 0, stream>>>(recI, rsIn, recO, rsOut,
                                      PAb, PBb, PCb, PDb, P3ib2, P3ob2, Wa2, ba2,
                                      nullptr, nullptr, qA, qB, qC, qD,
                                      nullptr, hentb, out, N);
}

// Round 14
// 185.190 us; speedup vs baseline: 1.4963x; 1.0078x over previous
//
#include <hip/hip_runtime.h>
#include <math.h>

#define NSLOPE 0.2f

typedef unsigned short ushort_t;
typedef unsigned char uchar_t;
typedef __attribute__((ext_vector_type(8))) short bf16x8;
typedef __attribute__((ext_vector_type(8))) unsigned short ushort8;
typedef __attribute__((ext_vector_type(4))) float f32x4;

__device__ __forceinline__ float elu1(float x) { return x > 0.f ? x : expm1f(x); }

__device__ __forceinline__ ushort_t f2bf(float f) {
  union { float f; unsigned int u; } v; v.f = f;
  unsigned int r = v.u + 0x7fffu + ((v.u >> 16) & 1u);
  return (ushort_t)(r >> 16);
}
__device__ __forceinline__ float bf2f(ushort_t u) {
  union { unsigned int i; float f; } v; v.i = ((unsigned int)u) << 16; return v.f;
}
__device__ __forceinline__ uchar_t f2fp8(float f) {
  int pk = __builtin_amdgcn_cvt_pk_fp8_f32(f, f, 0, false);
  return (uchar_t)(pk & 0xff);
}

// ================= device bodies =================

__device__ void dev_build_w(int idx,
                            const float* __restrict__ W1in, const float* __restrict__ W1out,
                            const float* __restrict__ W2in, const float* __restrict__ W2out,
                            const float* __restrict__ Went,
                            ushort_t* __restrict__ wcat1, ushort_t* __restrict__ wcat2,
                            ushort_t* __restrict__ wentb) {
  const int S1 = 832 * 128, S2 = 832 * 256, S3 = 256 * 128;
  if (idx < S1) {
    int ro = idx >> 7, k = idx & 127;
    float val = 0.f;
    if (ro < 800 && k < 100) {
      int o = ro / 200, cc = ro - o * 200;
      const float* W = (o < 2) ? W1in : W1out;
      val = W[(size_t)cc * 300 + (o & 1) * 100 + k];
    }
    wcat1[idx] = f2bf(val);
  } else if (idx < S1 + S2) {
    int i2 = idx - S1;
    int ro = i2 >> 8, k = i2 & 255;
    float val = 0.f;
    if (ro < 800 && k < 200) {
      int o = ro / 200, cc = ro - o * 200;
      const float* W = (o < 2) ? W2in : W2out;
      val = W[(size_t)cc * 500 + (o & 1) * 200 + k];
    }
    wcat2[i2] = f2bf(val);
  } else if (idx < S1 + S2 + S3) {
    int i3 = idx - S1 - S2;
    int ro = i3 >> 7, k = i3 & 127;
    float val = (ro < 200 && k < 100) ? Went[ro * 100 + k] : 0.f;
    wentb[i3] = f2bf(val);
  }
}

__device__ void dev_makeu(int idx,
                          const float* __restrict__ W1in, const float* __restrict__ a1in,
                          const float* __restrict__ W1out, const float* __restrict__ a1out,
                          const float* __restrict__ W2in, const float* __restrict__ a2in,
                          const float* __restrict__ W2out, const float* __restrict__ a2out,
                          float* __restrict__ u1in, float* __restrict__ u1out,
                          float* __restrict__ u2in, float* __restrict__ u2out) {
  if (idx >= 3200) return;
  const float* W; const float* avec; float* u; int Kp, local;
  if (idx < 600)       { W = W1in;  avec = a1in;  u = u1in;  Kp = 300; local = idx; }
  else if (idx < 1200) { W = W1out; avec = a1out; u = u1out; Kp = 300; local = idx - 600; }
  else if (idx < 2200) { W = W2in;  avec = a2in;  u = u2in;  Kp = 500; local = idx - 1200; }
  else                 { W = W2out; avec = a2out; u = u2out; Kp = 500; local = idx - 2200; }
  int h = local / Kp, kp = local - h * Kp;
  const float* Wb = W + (size_t)(h * 100) * Kp + kp;
  const float* ab = avec + h * 100;
  float s = 0.f;
  for (int k = 0; k < 100; ++k) s += ab[k] * Wb[(size_t)k * Kp];
  u[local] = s;
}

__device__ void dev_l2norm_q(int bb, int tid, const float* __restrict__ x,
                             ushort_t* __restrict__ xnb,
                             const float* __restrict__ u1in, const float* __restrict__ u1out,
                             float* __restrict__ qA, float* __restrict__ qB,
                             float* __restrict__ qC, float* __restrict__ qD, int N) {
  int wid = bb * 4 + (tid >> 6);
  int lane = tid & 63;
  if (wid >= N) return;
  const float* p = x + (size_t)wid * 100;
  float v0 = p[lane];
  bool t2 = lane < 36;
  float v1 = t2 ? p[lane + 64] : 0.f;
  float ss = v0 * v0 + v1 * v1;
#pragma unroll
  for (int m = 1; m < 64; m <<= 1) ss += __shfl_xor(ss, m, 64);
  float inv = 1.f / fmaxf(sqrtf(ss), 1e-12f);
  float a0 = v0 * inv, a1 = v1 * inv;
  ushort_t* ob = xnb + (size_t)wid * 128;
  ob[lane] = f2bf(a0);
  ob[64 + lane] = t2 ? f2bf(a1) : (ushort_t)0;
  int k0 = lane, k1 = 64 + lane;
  float s[8];
  s[0] = a0 * u1in[k0]        + (t2 ? a1 * u1in[k1]        : 0.f);
  s[1] = a0 * u1in[300 + k0]  + (t2 ? a1 * u1in[300 + k1]  : 0.f);
  s[2] = a0 * u1in[100 + k0]  + (t2 ? a1 * u1in[100 + k1]  : 0.f);
  s[3] = a0 * u1in[400 + k0]  + (t2 ? a1 * u1in[400 + k1]  : 0.f);
  s[4] = a0 * u1out[k0]       + (t2 ? a1 * u1out[k1]       : 0.f);
  s[5] = a0 * u1out[300 + k0] + (t2 ? a1 * u1out[300 + k1] : 0.f);
  s[6] = a0 * u1out[100 + k0] + (t2 ? a1 * u1out[100 + k1] : 0.f);
  s[7] = a0 * u1out[400 + k0] + (t2 ? a1 * u1out[400 + k1] : 0.f);
#pragma unroll
  for (int m = 1; m < 64; m <<= 1) {
#pragma unroll
    for (int i = 0; i < 8; ++i) s[i] += __shfl_xor(s[i], m, 64);
  }
  if (lane == 0) {
    qA[wid * 2] = s[0]; qA[wid * 2 + 1] = s[1];
    qB[wid * 2] = s[2]; qB[wid * 2 + 1] = s[3];
    qC[wid * 2] = s[4]; qC[wid * 2 + 1] = s[5];
    qD[wid * 2] = s[6]; qD[wid * 2 + 1] = s[7];
  }
}

__device__ void dev_qrel2(int bb, int tid, const float* __restrict__ g,
                          const float* __restrict__ u1in, const float* __restrict__ u1out,
                          const float* __restrict__ u2in, const float* __restrict__ u2out,
                          float* __restrict__ q3i1, float* __restrict__ q3o1,
                          float* __restrict__ q3i2, float* __restrict__ q3o2, int Mn) {
  int wid = bb * 4 + (tid >> 6);
  int lane = tid & 63;
  if (wid >= 2 * Mn) return;
  int lay = wid >= Mn;
  int m = wid - lay * Mn;
  const float* uin  = lay ? u2in  : u1in;
  const float* uout = lay ? u2out : u1out;
  int Kp = lay ? 500 : 300;
  int off3 = lay ? 400 : 200;
  float* q3i = lay ? q3i2 : q3i1;
  float* q3o = lay ? q3o2 : q3o1;
  const float* a = g + (size_t)m * 100;
  float s[4] = {0.f, 0.f, 0.f, 0.f};
  for (int k = lane; k < 100; k += 64) {
    float av = a[k];
    s[0] += av * uin[off3 + k];
    s[1] += av * uin[Kp + off3 + k];
    s[2] += av * uout[off3 + k];
    s[3] += av * uout[Kp + off3 + k];
  }
#pragma unroll
  for (int mm = 1; mm < 64; mm <<= 1) {
#pragma unroll
    for (int i = 0; i < 4; ++i) s[i] += __shfl_xor(s[i], mm, 64);
  }
  if (lane == 0) {
    q3i[m * 2] = s[0]; q3i[m * 2 + 1] = s[1];
    q3o[m * 2] = s[2]; q3o[m * 2 + 1] = s[3];
  }
}

__device__ void dev_count(int bb, int tid, const int* __restrict__ row,
                          const int* __restrict__ col,
                          int* __restrict__ cntIn, int* __restrict__ cntOut, int E) {
  int e = bb * 256 + tid;
  if (e >= E) return;
  atomicAdd(&cntIn[col[e]], 1);
  atomicAdd(&cntOut[row[e]], 1);
}

__device__ void dev_edge_e(int bb, int tid,
                           const int* __restrict__ row, const int* __restrict__ col,
                           const int* __restrict__ ety,
                           const float* __restrict__ qA, const float* __restrict__ qB,
                           const float* __restrict__ q3i,
                           const float* __restrict__ qC, const float* __restrict__ qD,
                           const float* __restrict__ q3o,
                           const int* __restrict__ invIn, const int* __restrict__ invOut,
                           float4* __restrict__ recI, float4* __restrict__ recO, int E) {
  int e = bb * 256 + tid;
  if (e >= E) return;
  int r = row[e], c = col[e], t = ety[e];
  float2 vA = *(const float2*)(qA + (size_t)r * 2);
  float2 vB = *(const float2*)(qB + (size_t)c * 2);
  float2 v3 = *(const float2*)(q3i + (size_t)t * 2);
  float2 vC = *(const float2*)(qC + (size_t)r * 2);
  float2 vD = *(const float2*)(qD + (size_t)c * 2);
  float2 v4 = *(const float2*)(q3o + (size_t)t * 2);
  float a0 = vA.x + vB.x + v3.x, a1 = vA.y + vB.y + v3.y;
  float b0 = vC.x + vD.x + v4.x, b1 = vC.y + vD.y + v4.y;
  float2 rI, rO;
  rI.x = expf(-(a0 > 0.f ? a0 : NSLOPE * a0));
  rI.y = expf(-(a1 > 0.f ? a1 : NSLOPE * a1));
  rO.x = expf(-(b0 > 0.f ? b0 : NSLOPE * b0));
  rO.y = expf(-(b1 > 0.f ? b1 : NSLOPE * b1));
  *(float2*)(recI + invIn[e]) = rI;
  *(float2*)(recO + invOut[e]) = rO;
}

// 64x64 MFMA GEMM tile; o==0 -> fp8 Q0 (if set), o==3 -> fp8 Q3, else bf16 Bd / f32 C0
__device__ void dev_mfma(int bx, int by, int tid,
                         ushort_t* __restrict__ smA, ushort_t* __restrict__ smB,
                         const ushort_t* __restrict__ Ab, int lda,
                         const ushort_t* __restrict__ Bb, int Kpad,
                         int R, int NC, int OUTW, const float* __restrict__ bias,
                         float* __restrict__ C0,
                         ushort_t* __restrict__ Bd0, ushort_t* __restrict__ Bd1,
                         ushort_t* __restrict__ Bd2, ushort_t* __restrict__ Bd3,
                         uchar_t* __restrict__ Q0, uchar_t* __restrict__ Q3) {
  const int lane = tid & 63;
  const int w = tid >> 6;
  const int wm = w >> 1, wn = w & 1;
  const int m0 = by * 64;
  const int n0 = bx * 64;
  const int srow = tid >> 2;
  const int sq = tid & 3;
  const int sw3 = srow & 7;
  const int sbase = srow * 64;
  const int so0 = sbase + ((((sq << 1) + 0) ^ sw3) << 3);
  const int so1 = sbase + ((((sq << 1) + 1) ^ sw3) << 3);
  const bool aok = (m0 + srow) < R;
  const ushort_t* Ag = Ab + (size_t)(m0 + srow) * lda + sq * 16;
  const ushort_t* Bg = Bb + (size_t)(n0 + srow) * Kpad + sq * 16;
  const int lswz = lane & 7;
  const int hi = lane >> 4;
  const int rA0 = (wm * 32 + (lane & 15)) * 64;
  const int rB0 = (wn * 32 + (lane & 15)) * 64;
  f32x4 acc[2][2] = {};
  for (int k0 = 0; k0 < Kpad; k0 += 64) {
    ushort8 a0 = {0, 0, 0, 0, 0, 0, 0, 0}, a1 = {0, 0, 0, 0, 0, 0, 0, 0};
    if (aok) {
      a0 = *(const ushort8*)(Ag + k0);
      a1 = *(const ushort8*)(Ag + k0 + 8);
    }
    ushort8 b0 = *(const ushort8*)(Bg + k0);
    ushort8 b1 = *(const ushort8*)(Bg + k0 + 8);
    __syncthreads();
    *(ushort8*)(smA + so0) = a0;
    *(ushort8*)(smA + so1) = a1;
    *(ushort8*)(smB + so0) = b0;
    *(ushort8*)(smB + so1) = b1;
    __syncthreads();
#pragma unroll
    for (int ks = 0; ks < 2; ++ks) {
      int co = (((ks << 2) + hi) ^ lswz) << 3;
      bf16x8 aA = *(const bf16x8*)(smA + rA0 + co);
      bf16x8 aB = *(const bf16x8*)(smA + rA0 + 1024 + co);
      bf16x8 bA = *(const bf16x8*)(smB + rB0 + co);
      bf16x8 bB = *(const bf16x8*)(smB + rB0 + 1024 + co);
      acc[0][0] = __builtin_amdgcn_mfma_f32_16x16x32_bf16(aA, bA, acc[0][0], 0, 0, 0);
      acc[0][1] = __builtin_amdgcn_mfma_f32_16x16x32_bf16(aA, bB, acc[0][1], 0, 0, 0);
      acc[1][0] = __builtin_amdgcn_mfma_f32_16x16x32_bf16(aB, bA, acc[1][0], 0, 0, 0);
      acc[1][1] = __builtin_amdgcn_mfma_f32_16x16x32_bf16(aB, bB, acc[1][1], 0, 0, 0);
    }
  }
  ushort_t* Bds[4] = {Bd0, Bd1, Bd2, Bd3};
#pragma unroll
  for (int mt = 0; mt < 2; ++mt) {
    int rr0 = m0 + wm * 32 + mt * 16 + (lane >> 4) * 4;
#pragma unroll
    for (int nt = 0; nt < 2; ++nt) {
      int cc = n0 + wn * 32 + nt * 16 + (lane & 15);
      if (cc < NC) {
        int o = cc / OUTW;
        int c2 = cc - o * OUTW;
        float bv = bias ? bias[c2] : 0.f;
        uchar_t* Q = (o == 0) ? Q0 : ((o == 3) ? Q3 : nullptr);
        ushort_t* Bd = Bds[o];
        if (Q) {
#pragma unroll
          for (int reg = 0; reg < 4; ++reg) {
            int r = rr0 + reg;
            if (r < R) Q[(size_t)r * OUTW + c2] = f2fp8(acc[mt][nt][reg] + bv);
          }
        } else if (Bd) {
#pragma unroll
          for (int reg = 0; reg < 4; ++reg) {
            int r = rr0 + reg;
            if (r < R) Bd[(size_t)r * OUTW + c2] = f2bf(acc[mt][nt][reg] + bv);
          }
        } else {
#pragma unroll
          for (int reg = 0; reg < 4; ++reg) {
            int r = rr0 + reg;
            if (r < R) C0[(size_t)r * OUTW + c2] = acc[mt][nt][reg] + bv;
          }
        }
      }
    }
  }
}

template <int NOUT, int BF>
__device__ void dev_gemm_multi(int bx, int by, int tid, float4 (*As)[25],
                               const float* __restrict__ A, int lda,
                               const float* __restrict__ W0, const float* __restrict__ W1,
                               int ldw,
                               const float* __restrict__ b0, const float* __restrict__ b1,
                               void* __restrict__ C0v, void* __restrict__ C1v, int R) {
  const int K4 = 25;
  int row0 = by * 32;
  {
    int r = tid >> 3;
    int rr = row0 + r;
    const float4* Ar = (const float4*)(A + (size_t)rr * lda);
    for (int k4 = (tid & 7); k4 < K4; k4 += 8)
      As[r][k4] = (rr < R) ? Ar[k4] : make_float4(0.f, 0.f, 0.f, 0.f);
  }
  __syncthreads();
  int c = bx * 64 + (tid & 63);
  if (c < 200) {
    int rb = (tid >> 6) << 3;
    const float4* Wr[NOUT];
    Wr[0] = (const float4*)(W0 + (size_t)c * ldw);
    if (NOUT > 1) Wr[1] = (const float4*)(W1 + (size_t)c * ldw);
    float acc[NOUT][8];
#pragma unroll
    for (int o = 0; o < NOUT; ++o)
#pragma unroll
      for (int i = 0; i < 8; ++i) acc[o][i] = 0.f;
#pragma unroll 2
    for (int k4 = 0; k4 < K4; ++k4) {
      float4 a[8];
#pragma unroll
      for (int i = 0; i < 8; ++i) a[i] = As[rb + i][k4];
#pragma unroll
      for (int o = 0; o < NOUT; ++o) {
        float4 wv = Wr[o][k4];
#pragma unroll
        for (int i = 0; i < 8; ++i)
          acc[o][i] += a[i].x * wv.x + a[i].y * wv.y + a[i].z * wv.z + a[i].w * wv.w;
      }
    }
    float bv[NOUT];
    bv[0] = b0 ? b0[c] : 0.f;
    if (NOUT > 1) bv[1] = b1 ? b1[c] : 0.f;
    void* Cp[NOUT];
    Cp[0] = C0v;
    if (NOUT > 1) Cp[1] = C1v;
#pragma unroll
    for (int i = 0; i < 8; ++i) {
      int rr = row0 + rb + i;
      if (rr < R) {
#pragma unroll
        for (int o = 0; o < NOUT; ++o) {
          float val = acc[o][i] + bv[o];
          if (BF) ((ushort_t*)Cp[o])[(size_t)rr * 200 + c] = f2bf(val);
          else    ((float*)Cp[o])[(size_t)rr * 200 + c] = val;
        }
      }
    }
  }
}

// ================= kernels =================

__global__ __launch_bounds__(256) void MEGA0(
    const float* W1in, const float* W1out, const float* W2in, const float* W2out,
    const float* Went,
    ushort_t* wcat1, ushort_t* wcat2, ushort_t* wentb,
    const float* a1in, const float* a1out, const float* a2in, const float* a2out,
    float* u1in, float* u1out, float* u2in, float* u2out,
    int* cntIn, int* cntOut, int N, int nb_bw, int nb_mk) {
  int b = blockIdx.x, tid = threadIdx.x;
  if (b < nb_bw) {
    dev_build_w(b * 256 + tid, W1in, W1out, W2in, W2out, Went, wcat1, wcat2, wentb);
  } else if (b < nb_bw + nb_mk) {
    dev_makeu((b - nb_bw) * 256 + tid, W1in, a1in, W1out, a1out, W2in, a2in, W2out, a2out,
              u1in, u1out, u2in, u2out);
  } else {
    int idx = (b - nb_bw - nb_mk) * 256 + tid;
    if (idx < N) cntIn[idx] = 0;
    else if (idx < 2 * N) cntOut[idx - N] = 0;
  }
}

__global__ __launch_bounds__(256) void MEGA1(
    const float* x, ushort_t* xnb, const float* u1in, const float* u1out,
    float* qA, float* qB, float* qC, float* qD, int N,
    const float* g, const float* u2in, const float* u2out,
    float* q3i1, float* q3o1, float* q3i2, float* q3o2, int Mn,
    const int* row, const int* col, int* cntIn, int* cntOut, int E,
    int nb_l2, int nb_qr) {
  int b = blockIdx.x, tid = threadIdx.x;
  if (b < nb_l2) {
    dev_l2norm_q(b, tid, x, xnb, u1in, u1out, qA, qB, qC, qD, N);
  } else if (b < nb_l2 + nb_qr) {
    dev_qrel2(b - nb_l2, tid, g, u1in, u1out, u2in, u2out, q3i1, q3o1, q3i2, q3o2, Mn);
  } else {
    dev_count(b - nb_l2 - nb_qr, tid, row, col, cntIn, cntOut, E);
  }
}

// ---- parallel 3-phase scan ----
__global__ __launch_bounds__(256) void k_scanA(const int* __restrict__ cntIn,
                                               const int* __restrict__ cntOut,
                                               int* __restrict__ part, int N, int nbc) {
  __shared__ int wsum[4];
  int b = blockIdx.x;
  const int* cnt = (b < nbc) ? cntIn : cntOut;
  int cb = (b < nbc) ? b : b - nbc;
  int idx = cb * 256 + threadIdx.x;
  int v = (idx < N) ? cnt[idx] : 0;
#pragma unroll
  for (int m = 1; m < 64; m <<= 1) v += __shfl_xor(v, m, 64);
  if ((threadIdx.x & 63) == 0) wsum[threadIdx.x >> 6] = v;
  __syncthreads();
  if (threadIdx.x == 0) part[b] = wsum[0] + wsum[1] + wsum[2] + wsum[3];
}

__global__ __launch_bounds__(256) void k_scanB(int* __restrict__ part,
                                               int* __restrict__ rsIn, int* __restrict__ rsOut,
                                               int nbc, int N) {
  __shared__ int buf[512];
  int t = threadIdx.x;
  buf[t]       = (t < nbc) ? part[t] : 0;
  buf[256 + t] = (t < nbc) ? part[nbc + t] : 0;
  __syncthreads();
  for (int off = 1; off < 256; off <<= 1) {
    int v0 = (t >= off) ? buf[t - off] : 0;
    int v1 = (t >= off) ? buf[256 + t - off] : 0;
    __syncthreads();
    buf[t] += v0; buf[256 + t] += v1;
    __syncthreads();
  }
  if (t < nbc) {
    part[t]       = (t == 0) ? 0 : buf[t - 1];
    part[nbc + t] = (t == 0) ? 0 : buf[256 + t - 1];
  }
  if (t == 0) { rsIn[N] = buf[nbc - 1]; rsOut[N] = buf[256 + nbc - 1]; }
}

__global__ __launch_bounds__(256) void k_scanC(const int* __restrict__ cntIn,
                                               const int* __restrict__ cntOut,
                                               const int* __restrict__ part,
                                               int* __restrict__ rsIn, int* __restrict__ rsOut,
                                               int* __restrict__ posIn, int* __restrict__ posOut,
                                               int N, int nbc) {
  __shared__ int buf[256];
  int b = blockIdx.x;
  const int* cnt = (b < nbc) ? cntIn : cntOut;
  int* rs  = (b < nbc) ? rsIn : rsOut;
  int* pos = (b < nbc) ? posIn : posOut;
  int cb = (b < nbc) ? b : b - nbc;
  int base = part[b];
  int t = threadIdx.x;
  int idx = cb * 256 + t;
  buf[t] = (idx < N) ? cnt[idx] : 0;
  __syncthreads();
  for (int off = 1; off < 256; off <<= 1) {
    int v = (t >= off) ? buf[t - off] : 0;
    __syncthreads();
    buf[t] += v;
    __syncthreads();
  }
  if (idx < N) {
    int excl = base + ((t == 0) ? 0 : buf[t - 1]);
    rs[idx] = excl; pos[idx] = excl;
  }
}

__global__ void k_fill(const int* __restrict__ row, const int* __restrict__ col,
                       const int* __restrict__ ety,
                       int* __restrict__ posIn, int* __restrict__ posOut,
                       float4* __restrict__ recI, float4* __restrict__ recO,
                       int* __restrict__ invIn, int* __restrict__ invOut, int E) {
  int e = blockIdx.x * blockDim.x + threadIdx.x;
  if (e >= E) return;
  int r = row[e], c = col[e], tt = ety[e];
  int p = atomicAdd(&posIn[c], 1);
  ((int2*)(recI + p))[1] = make_int2(r, tt);
  invIn[e] = p;
  int q = atomicAdd(&posOut[r], 1);
  ((int2*)(recO + q))[1] = make_int2(c, tt);
  invOut[e] = q;
}

__global__ __launch_bounds__(256) void MEGA2(
    const ushort_t* xnb, const ushort_t* wcat1,
    uchar_t* PA8, ushort_t* PBb, ushort_t* PCb, uchar_t* PD8, int N,
    const int* row, const int* col, const int* ety,
    const float* qA, const float* qB, const float* q3i1,
    const float* qC, const float* qD, const float* q3o1,
    const int* invIn, const int* invOut, float4* recI, float4* recO, int E,
    const float* g, const float* W1in200, const float* W1out200,
    const float* b1in, const float* b1out, ushort_t* P3ib, ushort_t* P3ob,
    const float* W2in400, const float* W2out400,
    const float* b2in, const float* b2out, ushort_t* P3ib2, ushort_t* P3ob2, int Mn,
    const ushort_t* wentb, const float* bent, ushort_t* hentb,
    const float* Wrel, const float* brel, float* outg,
    int nb_mf, int nb_ee, int nb_gm, int nb_we) {
  __shared__ float4 shbuf4[1024];
  ushort_t* smA = (ushort_t*)shbuf4;
  ushort_t* smB = smA + 64 * 64;
  float4 (*As)[25] = (float4(*)[25])shbuf4;
  int b = blockIdx.x, tid = threadIdx.x;
  if (b < nb_mf) {
    dev_mfma(b % 13, b / 13, tid, smA, smB, xnb, 128, wcat1, 128, N, 800, 200, nullptr,
             nullptr, nullptr, PBb, PCb, nullptr, PA8, PD8);
  } else if ((b -= nb_mf) < nb_ee) {
    dev_edge_e(b, tid, row, col, ety, qA, qB, q3i1, qC, qD, q3o1,
               invIn, invOut, recI, recO, E);
  } else if ((b -= nb_ee) < nb_gm) {
    dev_gemm_multi<2, 1>(b & 3, b >> 2, tid, As, g, 100, W1in200, W1out200, 300,
                         b1in, b1out, P3ib, P3ob, Mn);
  } else if ((b -= nb_gm) < nb_gm) {
    dev_gemm_multi<2, 1>(b & 3, b >> 2, tid, As, g, 100, W2in400, W2out400, 500,
                         b2in, b2out, P3ib2, P3ob2, Mn);
  } else if ((b -= nb_gm) < nb_we) {
    dev_mfma(b & 3, b >> 2, tid, smA, smB, xnb, 128, wentb, 128, N, 200, 200, bent,
             nullptr, hentb, nullptr, nullptr, nullptr, nullptr, nullptr);
  } else {
    b -= nb_we;
    dev_gemm_multi<1, 0>(b & 3, b >> 2, tid, As, g, 100, Wrel, nullptr, 100,
                         brel, nullptr, outg, nullptr, Mn);
  }
}

__global__ __launch_bounds__(256) void MEGA3(
    const ushort_t* h1b, const ushort_t* wcat2,
    uchar_t* PA8, ushort_t* PBb, ushort_t* PCb, uchar_t* PD8, int N,
    const int* row, const int* col, const int* ety,
    const float* qA, const float* qB, const float* q3i2,
    const float* qC, const float* qD, const float* q3o2,
    const int* invIn, const int* invOut, float4* recI, float4* recO, int E,
    int nb_mf) {
  __shared__ float4 shbuf4[1024];
  ushort_t* smA = (ushort_t*)shbuf4;
  ushort_t* smB = smA + 64 * 64;
  int b = blockIdx.x, tid = threadIdx.x;
  if (b < nb_mf) {
    dev_mfma(b % 13, b / 13, tid, smA, smB, h1b, 256, wcat2, 256, N, 800, 200, nullptr,
             nullptr, nullptr, PBb, PCb, nullptr, PA8, PD8);
  } else {
    dev_edge_e(b - nb_mf, tid, row, col, ety, qA, qB, q3i2, qC, qD, q3o2,
               invIn, invOut, recI, recO, E);
  }
}

// ---------------- fused per-node attention (LDS record broadcast + fp8 gathers) ----------------
__global__ void k_node_att(const float4* __restrict__ recI, const int* __restrict__ rsIn,
                           const float4* __restrict__ recO, const int* __restrict__ rsOut,
                           const uchar_t* __restrict__ PA8, const ushort_t* __restrict__ PBb,
                           const ushort_t* __restrict__ PCb, const uchar_t* __restrict__ PD8,
                           const ushort_t* __restrict__ P3ib, const ushort_t* __restrict__ P3ob,
                           const float* __restrict__ Wg, const float* __restrict__ bg,
                           const float* __restrict__ u2in, const float* __restrict__ u2out,
                           float* __restrict__ qA, float* __restrict__ qB,
                           float* __restrict__ qC, float* __restrict__ qD,
                           ushort_t* __restrict__ Hb,
                           const ushort_t* __restrict__ hentb, float* __restrict__ outp, int N) {
  __shared__ float4 sRecI[4][64];
  __shared__ float4 sRecO[4][64];
  int wv = threadIdx.x >> 6;
  int wid  = (int)((blockIdx.x * (unsigned)blockDim.x + threadIdx.x) >> 6);
  int lane = threadIdx.x & 63;
  if (wid >= N) return;
  int n = wid;
  int half = lane >> 5, i = lane & 31;
  bool act = i < 25;
  int j = half * 100 + i * 4;
  int sIn = rsIn[n], degIn = rsIn[n + 1] - sIn;
  int sOut = rsOut[n], degOut = rsOut[n + 1] - sOut;
  float4 accIn = {0.f, 0.f, 0.f, 0.f}, accOut = {0.f, 0.f, 0.f, 0.f};
  float dI0 = 0.f, dI1 = 0.f, dO0 = 0.f, dO1 = 0.f;
  int mx = max(degIn, degOut);
  for (int b = 0; b < mx; b += 64) {
    int l = b + lane;
    if (l < degIn) {
      float4 rc = recI[sIn + l];
      dI0 += rc.x; dI1 += rc.y;
      sRecI[wv][lane] = rc;
    }
    if (l < degOut) {
      float4 rc = recO[sOut + l];
      dO0 += rc.x; dO1 += rc.y;
      sRecO[wv][lane] = rc;
    }
    int mI = degIn - b;  if (mI > 64) mI = 64;
    int mO = degOut - b; if (mO > 64) mO = 64;
    int m2 = max(mI, mO);
    for (int jj = 0; jj < m2; ++jj) {
      if (act && jj < mI) {
        float4 rc = sRecI[wv][jj];
        int rI = __float_as_int(rc.z), tI = __float_as_int(rc.w);
        float wgt = half ? rc.y : rc.x;
        int paw = *(const int*)(PA8 + (size_t)rI * 200 + j);
        ushort4 p3 = *(const ushort4*)(P3ib + (size_t)tI * 200 + j);
        accIn.x += wgt * (__builtin_amdgcn_cvt_f32_fp8(paw, 0) + bf2f(p3.x));
        accIn.y += wgt * (__builtin_amdgcn_cvt_f32_fp8(paw, 1) + bf2f(p3.y));
        accIn.z += wgt * (__builtin_amdgcn_cvt_f32_fp8(paw, 2) + bf2f(p3.z));
        accIn.w += wgt * (__builtin_amdgcn_cvt_f32_fp8(paw, 3) + bf2f(p3.w));
      }
      if (act && jj < mO) {
        float4 rc = sRecO[wv][jj];
        int rO = __float_as_int(rc.z), tO = __float_as_int(rc.w);
        float wgt = half ? rc.y : rc.x;
        int pdw = *(const int*)(PD8 + (size_t)rO * 200 + j);
        ushort4 p3 = *(const ushort4*)(P3ob + (size_t)tO * 200 + j);
        accOut.x += wgt * (__builtin_amdgcn_cvt_f32_fp8(pdw, 0) + bf2f(p3.x));
        accOut.y += wgt * (__builtin_amdgcn_cvt_f32_fp8(pdw, 1) + bf2f(p3.y));
        accOut.z += wgt * (__builtin_amdgcn_cvt_f32_fp8(pdw, 2) + bf2f(p3.z));
        accOut.w += wgt * (__builtin_amdgcn_cvt_f32_fp8(pdw, 3) + bf2f(p3.w));
      }
    }
  }
#pragma unroll
  for (int m = 1; m < 64; m <<= 1) {
    dI0 += __shfl_xor(dI0, m, 64); dI1 += __shfl_xor(dI1, m, 64);
    dO0 += __shfl_xor(dO0, m, 64); dO1 += __shfl_xor(dO1, m, 64);
  }
  float4 hin = {0.f, 0.f, 0.f, 0.f}, hout = {0.f, 0.f, 0.f, 0.f};
  if (degIn > 0 && act) {
    float invd = 1.f / (half ? dI1 : dI0);
    ushort4 ps = *(const ushort4*)(PBb + (size_t)n * 200 + j);
    hin.x = elu1(bf2f(ps.x) + accIn.x * invd);
    hin.y = elu1(bf2f(ps.y) + accIn.y * invd);
    hin.z = elu1(bf2f(ps.z) + accIn.z * invd);
    hin.w = elu1(bf2f(ps.w) + accIn.w * invd);
  }
  if (degOut > 0 && act) {
    float invd = 1.f / (half ? dO1 : dO0);
    ushort4 ps = *(const ushort4*)(PCb + (size_t)n * 200 + j);
    hout.x = elu1(bf2f(ps.x) + accOut.x * invd);
    hout.y = elu1(bf2f(ps.y) + accOut.y * invd);
    hout.z = elu1(bf2f(ps.z) + accOut.z * invd);
    hout.w = elu1(bf2f(ps.w) + accOut.w * invd);
  }
  float gp = 0.f;
  if (act) {
    int k = i * 4;
    gp = Wg[k] * hin.x + Wg[k + 1] * hin.y + Wg[k + 2] * hin.z + Wg[k + 3] * hin.w +
         Wg[100 + k] * hout.x + Wg[100 + k + 1] * hout.y +
         Wg[100 + k + 2] * hout.z + Wg[100 + k + 3] * hout.w;
  }
#pragma unroll
  for (int m = 1; m < 32; m <<= 1) gp += __shfl_xor(gp, m, 32);
  float al = 1.f / (1.f + expf(-(gp + bg[0])));
  float4 he;
  he.x = elu1(al * hin.x + (1.f - al) * hout.x);
  he.y = elu1(al * hin.y + (1.f - al) * hout.y);
  he.z = elu1(al * hin.z + (1.f - al) * hout.z);
  he.w = elu1(al * hin.w + (1.f - al) * hout.w);
  float ss = he.x * he.x + he.y * he.y + he.z * he.z + he.w * he.w;
#pragma unroll
  for (int m = 1; m < 32; m <<= 1) ss += __shfl_xor(ss, m, 32);
  float inv = 1.f / fmaxf(sqrtf(ss), 1e-12f);
  float4 o = {he.x * inv, he.y * inv, he.z * inv, he.w * inv};
  if (Hb) {
    if (act) {
      ushort4 ov; ov.x = f2bf(o.x); ov.y = f2bf(o.y); ov.z = f2bf(o.z); ov.w = f2bf(o.w);
      *(ushort4*)(Hb + (size_t)n * 256 + j) = ov;
    } else {
      int pi = half * 7 + (i - 25);
      ushort4 z = {0, 0, 0, 0};
      *(ushort4*)(Hb + (size_t)n * 256 + 200 + pi * 4) = z;
    }
  }
  if (outp) {
    float4 v = {0.f, 0.f, 0.f, 0.f};
    if (act) {
      ushort4 hv = *(const ushort4*)(hentb + (size_t)n * 200 + j);
      v.x = bf2f(hv.x) + o.x; v.y = bf2f(hv.y) + o.y;
      v.z = bf2f(hv.z) + o.z; v.w = bf2f(hv.w) + o.w;
    }
    float s2 = v.x * v.x + v.y * v.y + v.z * v.z + v.w * v.w;
#pragma unroll
    for (int m = 1; m < 32; m <<= 1) s2 += __shfl_xor(s2, m, 32);
    float inv2 = 1.f / fmaxf(sqrtf(s2), 1e-12f);
    if (act) {
      float4 ov = {v.x * inv2, v.y * inv2, v.z * inv2, v.w * inv2};
      *(float4*)(outp + (size_t)n * 200 + j) = ov;
    }
  }
  if (u2in) {
    float4 ov = act ? o : make_float4(0.f, 0.f, 0.f, 0.f);
    float s[8];
#pragma unroll
    for (int h = 0; h < 2; ++h) {
      float4 uA = *(const float4*)(u2in + h * 500 + j);
      float4 uB = *(const float4*)(u2in + h * 500 + 200 + j);
      float4 uC = *(const float4*)(u2out + h * 500 + j);
      float4 uD = *(const float4*)(u2out + h * 500 + 200 + j);
      s[0 + h] = ov.x * uA.x + ov.y * uA.y + ov.z * uA.z + ov.w * uA.w;
      s[2 + h] = ov.x * uB.x + ov.y * uB.y + ov.z * uB.z + ov.w * uB.w;
      s[4 + h] = ov.x * uC.x + ov.y * uC.y + ov.z * uC.z + ov.w * uC.w;
      s[6 + h] = ov.x * uD.x + ov.y * uD.y + ov.z * uD.z + ov.w * uD.w;
    }
#pragma unroll
    for (int m = 1; m < 64; m <<= 1) {
#pragma unroll
      for (int ii = 0; ii < 8; ++ii) s[ii] += __shfl_xor(s[ii], m, 64);
    }
    if (lane == 0) {
      qA[n * 2] = s[0]; qA[n * 2 + 1] = s[1];
      qB[n * 2] = s[2]; qB[n * 2 + 1] = s[3];
      qC[n * 2] = s[4]; qC[n * 2 + 1] = s[5];
      qD[n * 2] = s[6]; qD[n * 2 + 1] = s[7];
    }
  }
}

extern "C" void kernel_launch(void* const* d_in, const int* in_sizes, int n_in,
                              void* d_out, int out_size, void* d_ws, size_t ws_size,
                              hipStream_t stream) {
  const float* x    = (const float*)d_in[0];
  const float* g    = (const float*)d_in[1];
  const float* W1in = (const float*)d_in[2];
  const float* b1in = (const float*)d_in[3];
  const float* a1in = (const float*)d_in[4];
  const float* W1out= (const float*)d_in[5];
  const float* b1out= (const float*)d_in[6];
  const float* a1out= (const float*)d_in[7];
  const float* Wa1  = (const float*)d_in[8];
  const float* ba1  = (const float*)d_in[9];
  const float* W2in = (const float*)d_in[10];
  const float* b2in = (const float*)d_in[11];
  const float* a2in = (const float*)d_in[12];
  const float* W2out= (const float*)d_in[13];
  const float* b2out= (const float*)d_in[14];
  const float* a2out= (const float*)d_in[15];
  const float* Wa2  = (const float*)d_in[16];
  const float* ba2  = (const float*)d_in[17];
  const float* Went = (const float*)d_in[18];
  const float* bent = (const float*)d_in[19];
  const float* Wrel = (const float*)d_in[20];
  const float* brel = (const float*)d_in[21];
  const int*  eidx  = (const int*)d_in[22];
  const int*  ety   = (const int*)d_in[23];

  const int N = in_sizes[0] / 100;
  const int M = in_sizes[1] / 100;
  const int E = in_sizes[23];
  const int* row = eidx;
  const int* col = eidx + E;
  float* out = (float*)d_out;

  float* ws = (float*)d_ws;
  size_t off = 0;
  auto alloc = [&](size_t nf) { float* p = ws + off; off += (nf + 3) & ~(size_t)3; return p; };
  float4* recI = (float4*)alloc((size_t)E * 4);
  float4* recO = (float4*)alloc((size_t)E * 4);
  uchar_t* PA8 = (uchar_t*)alloc((size_t)N * 50);
  uchar_t* PD8 = (uchar_t*)alloc((size_t)N * 50);
  ushort_t* PBb = (ushort_t*)alloc((size_t)N * 100);
  ushort_t* PCb = (ushort_t*)alloc((size_t)N * 100);
  ushort_t* P3ib = (ushort_t*)alloc((size_t)M * 100);
  ushort_t* P3ob = (ushort_t*)alloc((size_t)M * 100);
  ushort_t* P3ib2 = (ushort_t*)alloc((size_t)M * 100);
  ushort_t* P3ob2 = (ushort_t*)alloc((size_t)M * 100);
  ushort_t* xnb = (ushort_t*)alloc((size_t)N * 64);
  ushort_t* h1b = (ushort_t*)alloc((size_t)N * 128);
  ushort_t* hentb = (ushort_t*)alloc((size_t)N * 100);
  ushort_t* wcat1 = (ushort_t*)alloc((size_t)832 * 64);
  ushort_t* wcat2 = (ushort_t*)alloc((size_t)832 * 128);
  ushort_t* wentb = (ushort_t*)alloc((size_t)256 * 64);
  float* qA  = alloc((size_t)N * 2);
  float* qB  = alloc((size_t)N * 2);
  float* qC  = alloc((size_t)N * 2);
  float* qD  = alloc((size_t)N * 2);
  float* q3i1 = alloc((size_t)M * 2);
  float* q3o1 = alloc((size_t)M * 2);
  float* q3i2 = alloc((size_t)M * 2);
  float* q3o2 = alloc((size_t)M * 2);
  int* invIn  = (int*)alloc((size_t)E);
  int* invOut = (int*)alloc((size_t)E);
  float* u1in  = alloc(600);
  float* u1out = alloc(600);
  float* u2in  = alloc(1000);
  float* u2out = alloc(1000);
  int* cntIn  = (int*)alloc((size_t)N);
  int* cntOut = (int*)alloc((size_t)N);
  int* rsIn   = (int*)alloc((size_t)N + 1);
  int* rsOut  = (int*)alloc((size_t)N + 1);
  int* posIn  = (int*)alloc((size_t)N);
  int* posOut = (int*)alloc((size_t)N);
  int* part   = (int*)alloc((size_t)512);

  const int gN4 = (N + 3) / 4;
  const int gE  = (E + 255) / 256;
  const int mT  = (N + 63) / 64;
  const int nbc = (N + 255) / 256;

  const int nb_bw = (832 * 128 + 832 * 256 + 256 * 128 + 255) / 256;
  const int nb_mk = 13;
  const int nb_z  = (2 * N + 255) / 256;
  const int nb_l2 = gN4;
  const int nb_qr = (2 * M + 3) / 4;
  const int nb_mf = 13 * mT;
  const int nb_gm = 4 * ((M + 31) / 32);
  const int nb_we = 4 * mT;

  MEGA0<<<nb_bw + nb_mk + nb_z, 256, 0, stream>>>(
      W1in, W1out, W2in, W2out, Went, wcat1, wcat2, wentb,
      a1in, a1out, a2in, a2out, u1in, u1out, u2in, u2out,
      cntIn, cntOut, N, nb_bw, nb_mk);

  MEGA1<<<nb_l2 + nb_qr + gE, 256, 0, stream>>>(
      x, xnb, u1in, u1out, qA, qB, qC, qD, N,
      g, u2in, u2out, q3i1, q3o1, q3i2, q3o2, M,
      row, col, cntIn, cntOut, E, nb_l2, nb_qr);

  k_scanA<<<2 * nbc, 256, 0, stream>>>(cntIn, cntOut, part, N, nbc);
  k_scanB<<<1, 256, 0, stream>>>(part, rsIn, rsOut, nbc, N);
  k_scanC<<<2 * nbc, 256, 0, stream>>>(cntIn, cntOut, part, rsIn, rsOut, posIn, posOut, N, nbc);
  k_fill<<<gE, 256, 0, stream>>>(row, col, ety, posIn, posOut, recI, recO, invIn, invOut, E);

  MEGA2<<<nb_mf + gE + nb_gm * 3 + nb_we, 256, 0, stream>>>(
      xnb, wcat1, PA8, PBb, PCb, PD8, N,
      row, col, ety, qA, qB, q3i1, qC, qD, q3o1, invIn, invOut, recI, recO, E,
      g, W1in + 200, W1out + 200, b1in, b1out, P3ib, P3ob,
      W2in + 400, W2out + 400, b2in, b2out, P3ib2, P3ob2, M,
      wentb, bent, hentb, Wrel, brel, out + (size_t)N * 200,
      nb_mf, gE, nb_gm, nb_we);

  k_node_att<<<gN4, 256, 0, stream>>>(recI, rsIn, recO, rsOut,
                                      PA8, PBb, PCb, PD8, P3ib, P3ob, Wa1, ba1,
                                      u2in, u2out, qA, qB, qC, qD,
                                      h1b, nullptr, nullptr, N);

  MEGA3<<<nb_mf + gE, 256, 0, stream>>>(
      h1b, wcat2, PA8, PBb, PCb, PD8, N,
      row, col, ety, qA, qB, q3i2, qC, qD, q3o2, invIn, invOut, recI, recO, E,
      nb_mf);

  k_node_att<<<gN4, 256, 0, stream>>>(recI, rsIn, recO, rsOut,
                                      PA8, PBb, PCb, PD8, P3ib2, P3ob2, Wa2, ba2,
                                      nullptr, nullptr, qA, qB, qC, qD,
                                      nullptr, hentb, out, N);
}

// Round 15
// 182.197 us; speedup vs baseline: 1.5209x; 1.0164x over previous
//
#include <hip/hip_runtime.h>
#include <math.h>

#define NSLOPE 0.2f

typedef unsigned short ushort_t;
typedef unsigned char uchar_t;
typedef __attribute__((ext_vector_type(8))) short bf16x8;
typedef __attribute__((ext_vector_type(8))) unsigned short ushort8;
typedef __attribute__((ext_vector_type(4))) float f32x4;

__device__ __forceinline__ float elu1(float x) { return x > 0.f ? x : expm1f(x); }

__device__ __forceinline__ ushort_t f2bf(float f) {
  union { float f; unsigned int u; } v; v.f = f;
  unsigned int r = v.u + 0x7fffu + ((v.u >> 16) & 1u);
  return (ushort_t)(r >> 16);
}
__device__ __forceinline__ float bf2f(ushort_t u) {
  union { unsigned int i; float f; } v; v.i = ((unsigned int)u) << 16; return v.f;
}
__device__ __forceinline__ uchar_t f2fp8(float f) {
  int pk = __builtin_amdgcn_cvt_pk_fp8_f32(f, f, 0, false);
  return (uchar_t)(pk & 0xff);
}

// ================= device bodies =================

__device__ void dev_build_w(int idx,
                            const float* __restrict__ W1in, const float* __restrict__ W1out,
                            const float* __restrict__ W2in, const float* __restrict__ W2out,
                            const float* __restrict__ Went,
                            ushort_t* __restrict__ wcat1, ushort_t* __restrict__ wcat2,
                            ushort_t* __restrict__ wentb) {
  const int S1 = 832 * 128, S2 = 832 * 256, S3 = 256 * 128;
  if (idx < S1) {
    int ro = idx >> 7, k = idx & 127;
    float val = 0.f;
    if (ro < 800 && k < 100) {
      int o = ro / 200, cc = ro - o * 200;
      const float* W = (o < 2) ? W1in : W1out;
      val = W[(size_t)cc * 300 + (o & 1) * 100 + k];
    }
    wcat1[idx] = f2bf(val);
  } else if (idx < S1 + S2) {
    int i2 = idx - S1;
    int ro = i2 >> 8, k = i2 & 255;
    float val = 0.f;
    if (ro < 800 && k < 200) {
      int o = ro / 200, cc = ro - o * 200;
      const float* W = (o < 2) ? W2in : W2out;
      val = W[(size_t)cc * 500 + (o & 1) * 200 + k];
    }
    wcat2[i2] = f2bf(val);
  } else if (idx < S1 + S2 + S3) {
    int i3 = idx - S1 - S2;
    int ro = i3 >> 7, k = i3 & 127;
    float val = (ro < 200 && k < 100) ? Went[ro * 100 + k] : 0.f;
    wentb[i3] = f2bf(val);
  }
}

__device__ void dev_makeu(int idx,
                          const float* __restrict__ W1in, const float* __restrict__ a1in,
                          const float* __restrict__ W1out, const float* __restrict__ a1out,
                          const float* __restrict__ W2in, const float* __restrict__ a2in,
                          const float* __restrict__ W2out, const float* __restrict__ a2out,
                          float* __restrict__ u1in, float* __restrict__ u1out,
                          float* __restrict__ u2in, float* __restrict__ u2out) {
  if (idx >= 3200) return;
  const float* W; const float* avec; float* u; int Kp, local;
  if (idx < 600)       { W = W1in;  avec = a1in;  u = u1in;  Kp = 300; local = idx; }
  else if (idx < 1200) { W = W1out; avec = a1out; u = u1out; Kp = 300; local = idx - 600; }
  else if (idx < 2200) { W = W2in;  avec = a2in;  u = u2in;  Kp = 500; local = idx - 1200; }
  else                 { W = W2out; avec = a2out; u = u2out; Kp = 500; local = idx - 2200; }
  int h = local / Kp, kp = local - h * Kp;
  const float* Wb = W + (size_t)(h * 100) * Kp + kp;
  const float* ab = avec + h * 100;
  float s = 0.f;
  for (int k = 0; k < 100; ++k) s += ab[k] * Wb[(size_t)k * Kp];
  u[local] = s;
}

__device__ void dev_l2norm_q(int bb, int tid, const float* __restrict__ x,
                             ushort_t* __restrict__ xnb,
                             const float* __restrict__ u1in, const float* __restrict__ u1out,
                             float* __restrict__ qA, float* __restrict__ qB,
                             float* __restrict__ qC, float* __restrict__ qD, int N) {
  int wid = bb * 4 + (tid >> 6);
  int lane = tid & 63;
  if (wid >= N) return;
  const float* p = x + (size_t)wid * 100;
  float v0 = p[lane];
  bool t2 = lane < 36;
  float v1 = t2 ? p[lane + 64] : 0.f;
  float ss = v0 * v0 + v1 * v1;
#pragma unroll
  for (int m = 1; m < 64; m <<= 1) ss += __shfl_xor(ss, m, 64);
  float inv = 1.f / fmaxf(sqrtf(ss), 1e-12f);
  float a0 = v0 * inv, a1 = v1 * inv;
  ushort_t* ob = xnb + (size_t)wid * 128;
  ob[lane] = f2bf(a0);
  ob[64 + lane] = t2 ? f2bf(a1) : (ushort_t)0;
  int k0 = lane, k1 = 64 + lane;
  float s[8];
  s[0] = a0 * u1in[k0]        + (t2 ? a1 * u1in[k1]        : 0.f);
  s[1] = a0 * u1in[300 + k0]  + (t2 ? a1 * u1in[300 + k1]  : 0.f);
  s[2] = a0 * u1in[100 + k0]  + (t2 ? a1 * u1in[100 + k1]  : 0.f);
  s[3] = a0 * u1in[400 + k0]  + (t2 ? a1 * u1in[400 + k1]  : 0.f);
  s[4] = a0 * u1out[k0]       + (t2 ? a1 * u1out[k1]       : 0.f);
  s[5] = a0 * u1out[300 + k0] + (t2 ? a1 * u1out[300 + k1] : 0.f);
  s[6] = a0 * u1out[100 + k0] + (t2 ? a1 * u1out[100 + k1] : 0.f);
  s[7] = a0 * u1out[400 + k0] + (t2 ? a1 * u1out[400 + k1] : 0.f);
#pragma unroll
  for (int m = 1; m < 64; m <<= 1) {
#pragma unroll
    for (int i = 0; i < 8; ++i) s[i] += __shfl_xor(s[i], m, 64);
  }
  if (lane == 0) {
    qA[wid * 2] = s[0]; qA[wid * 2 + 1] = s[1];
    qB[wid * 2] = s[2]; qB[wid * 2 + 1] = s[3];
    qC[wid * 2] = s[4]; qC[wid * 2 + 1] = s[5];
    qD[wid * 2] = s[6]; qD[wid * 2 + 1] = s[7];
  }
}

__device__ void dev_qrel2(int bb, int tid, const float* __restrict__ g,
                          const float* __restrict__ u1in, const float* __restrict__ u1out,
                          const float* __restrict__ u2in, const float* __restrict__ u2out,
                          float* __restrict__ q3i1, float* __restrict__ q3o1,
                          float* __restrict__ q3i2, float* __restrict__ q3o2, int Mn) {
  int wid = bb * 4 + (tid >> 6);
  int lane = tid & 63;
  if (wid >= 2 * Mn) return;
  int lay = wid >= Mn;
  int m = wid - lay * Mn;
  const float* uin  = lay ? u2in  : u1in;
  const float* uout = lay ? u2out : u1out;
  int Kp = lay ? 500 : 300;
  int off3 = lay ? 400 : 200;
  float* q3i = lay ? q3i2 : q3i1;
  float* q3o = lay ? q3o2 : q3o1;
  const float* a = g + (size_t)m * 100;
  float s[4] = {0.f, 0.f, 0.f, 0.f};
  for (int k = lane; k < 100; k += 64) {
    float av = a[k];
    s[0] += av * uin[off3 + k];
    s[1] += av * uin[Kp + off3 + k];
    s[2] += av * uout[off3 + k];
    s[3] += av * uout[Kp + off3 + k];
  }
#pragma unroll
  for (int mm = 1; mm < 64; mm <<= 1) {
#pragma unroll
    for (int i = 0; i < 4; ++i) s[i] += __shfl_xor(s[i], mm, 64);
  }
  if (lane == 0) {
    q3i[m * 2] = s[0]; q3i[m * 2 + 1] = s[1];
    q3o[m * 2] = s[2]; q3o[m * 2 + 1] = s[3];
  }
}

__device__ void dev_count(int bb, int tid, const int* __restrict__ row,
                          const int* __restrict__ col,
                          int* __restrict__ cntIn, int* __restrict__ cntOut, int E) {
  int e = bb * 256 + tid;
  if (e >= E) return;
  atomicAdd(&cntIn[col[e]], 1);
  atomicAdd(&cntOut[row[e]], 1);
}

// 64x64 MFMA GEMM tile; o==0 -> fp8 Q0 (if set), o==3 -> fp8 Q3, else bf16 Bd / f32 C0
__device__ void dev_mfma(int bx, int by, int tid,
                         ushort_t* __restrict__ smA, ushort_t* __restrict__ smB,
                         const ushort_t* __restrict__ Ab, int lda,
                         const ushort_t* __restrict__ Bb, int Kpad,
                         int R, int NC, int OUTW, const float* __restrict__ bias,
                         float* __restrict__ C0,
                         ushort_t* __restrict__ Bd0, ushort_t* __restrict__ Bd1,
                         ushort_t* __restrict__ Bd2, ushort_t* __restrict__ Bd3,
                         uchar_t* __restrict__ Q0, uchar_t* __restrict__ Q3) {
  const int lane = tid & 63;
  const int w = tid >> 6;
  const int wm = w >> 1, wn = w & 1;
  const int m0 = by * 64;
  const int n0 = bx * 64;
  const int srow = tid >> 2;
  const int sq = tid & 3;
  const int sw3 = srow & 7;
  const int sbase = srow * 64;
  const int so0 = sbase + ((((sq << 1) + 0) ^ sw3) << 3);
  const int so1 = sbase + ((((sq << 1) + 1) ^ sw3) << 3);
  const bool aok = (m0 + srow) < R;
  const ushort_t* Ag = Ab + (size_t)(m0 + srow) * lda + sq * 16;
  const ushort_t* Bg = Bb + (size_t)(n0 + srow) * Kpad + sq * 16;
  const int lswz = lane & 7;
  const int hi = lane >> 4;
  const int rA0 = (wm * 32 + (lane & 15)) * 64;
  const int rB0 = (wn * 32 + (lane & 15)) * 64;
  f32x4 acc[2][2] = {};
  for (int k0 = 0; k0 < Kpad; k0 += 64) {
    ushort8 a0 = {0, 0, 0, 0, 0, 0, 0, 0}, a1 = {0, 0, 0, 0, 0, 0, 0, 0};
    if (aok) {
      a0 = *(const ushort8*)(Ag + k0);
      a1 = *(const ushort8*)(Ag + k0 + 8);
    }
    ushort8 b0 = *(const ushort8*)(Bg + k0);
    ushort8 b1 = *(const ushort8*)(Bg + k0 + 8);
    __syncthreads();
    *(ushort8*)(smA + so0) = a0;
    *(ushort8*)(smA + so1) = a1;
    *(ushort8*)(smB + so0) = b0;
    *(ushort8*)(smB + so1) = b1;
    __syncthreads();
#pragma unroll
    for (int ks = 0; ks < 2; ++ks) {
      int co = (((ks << 2) + hi) ^ lswz) << 3;
      bf16x8 aA = *(const bf16x8*)(smA + rA0 + co);
      bf16x8 aB = *(const bf16x8*)(smA + rA0 + 1024 + co);
      bf16x8 bA = *(const bf16x8*)(smB + rB0 + co);
      bf16x8 bB = *(const bf16x8*)(smB + rB0 + 1024 + co);
      acc[0][0] = __builtin_amdgcn_mfma_f32_16x16x32_bf16(aA, bA, acc[0][0], 0, 0, 0);
      acc[0][1] = __builtin_amdgcn_mfma_f32_16x16x32_bf16(aA, bB, acc[0][1], 0, 0, 0);
      acc[1][0] = __builtin_amdgcn_mfma_f32_16x16x32_bf16(aB, bA, acc[1][0], 0, 0, 0);
      acc[1][1] = __builtin_amdgcn_mfma_f32_16x16x32_bf16(aB, bB, acc[1][1], 0, 0, 0);
    }
  }
  ushort_t* Bds[4] = {Bd0, Bd1, Bd2, Bd3};
#pragma unroll
  for (int mt = 0; mt < 2; ++mt) {
    int rr0 = m0 + wm * 32 + mt * 16 + (lane >> 4) * 4;
#pragma unroll
    for (int nt = 0; nt < 2; ++nt) {
      int cc = n0 + wn * 32 + nt * 16 + (lane & 15);
      if (cc < NC) {
        int o = cc / OUTW;
        int c2 = cc - o * OUTW;
        float bv = bias ? bias[c2] : 0.f;
        uchar_t* Q = (o == 0) ? Q0 : ((o == 3) ? Q3 : nullptr);
        ushort_t* Bd = Bds[o];
        if (Q) {
#pragma unroll
          for (int reg = 0; reg < 4; ++reg) {
            int r = rr0 + reg;
            if (r < R) Q[(size_t)r * OUTW + c2] = f2fp8(acc[mt][nt][reg] + bv);
          }
        } else if (Bd) {
#pragma unroll
          for (int reg = 0; reg < 4; ++reg) {
            int r = rr0 + reg;
            if (r < R) Bd[(size_t)r * OUTW + c2] = f2bf(acc[mt][nt][reg] + bv);
          }
        } else {
#pragma unroll
          for (int reg = 0; reg < 4; ++reg) {
            int r = rr0 + reg;
            if (r < R) C0[(size_t)r * OUTW + c2] = acc[mt][nt][reg] + bv;
          }
        }
      }
    }
  }
}

template <int NOUT, int BF>
__device__ void dev_gemm_multi(int bx, int by, int tid, float4 (*As)[25],
                               const float* __restrict__ A, int lda,
                               const float* __restrict__ W0, const float* __restrict__ W1,
                               int ldw,
                               const float* __restrict__ b0, const float* __restrict__ b1,
                               void* __restrict__ C0v, void* __restrict__ C1v, int R) {
  const int K4 = 25;
  int row0 = by * 32;
  {
    int r = tid >> 3;
    int rr = row0 + r;
    const float4* Ar = (const float4*)(A + (size_t)rr * lda);
    for (int k4 = (tid & 7); k4 < K4; k4 += 8)
      As[r][k4] = (rr < R) ? Ar[k4] : make_float4(0.f, 0.f, 0.f, 0.f);
  }
  __syncthreads();
  int c = bx * 64 + (tid & 63);
  if (c < 200) {
    int rb = (tid >> 6) << 3;
    const float4* Wr[NOUT];
    Wr[0] = (const float4*)(W0 + (size_t)c * ldw);
    if (NOUT > 1) Wr[1] = (const float4*)(W1 + (size_t)c * ldw);
    float acc[NOUT][8];
#pragma unroll
    for (int o = 0; o < NOUT; ++o)
#pragma unroll
      for (int i = 0; i < 8; ++i) acc[o][i] = 0.f;
#pragma unroll 2
    for (int k4 = 0; k4 < K4; ++k4) {
      float4 a[8];
#pragma unroll
      for (int i = 0; i < 8; ++i) a[i] = As[rb + i][k4];
#pragma unroll
      for (int o = 0; o < NOUT; ++o) {
        float4 wv = Wr[o][k4];
#pragma unroll
        for (int i = 0; i < 8; ++i)
          acc[o][i] += a[i].x * wv.x + a[i].y * wv.y + a[i].z * wv.z + a[i].w * wv.w;
      }
    }
    float bv[NOUT];
    bv[0] = b0 ? b0[c] : 0.f;
    if (NOUT > 1) bv[1] = b1 ? b1[c] : 0.f;
    void* Cp[NOUT];
    Cp[0] = C0v;
    if (NOUT > 1) Cp[1] = C1v;
#pragma unroll
    for (int i = 0; i < 8; ++i) {
      int rr = row0 + rb + i;
      if (rr < R) {
#pragma unroll
        for (int o = 0; o < NOUT; ++o) {
          float val = acc[o][i] + bv[o];
          if (BF) ((ushort_t*)Cp[o])[(size_t)rr * 200 + c] = f2bf(val);
          else    ((float*)Cp[o])[(size_t)rr * 200 + c] = val;
        }
      }
    }
  }
}

// ================= kernels =================

__global__ __launch_bounds__(256) void MEGA0(
    const float* W1in, const float* W1out, const float* W2in, const float* W2out,
    const float* Went,
    ushort_t* wcat1, ushort_t* wcat2, ushort_t* wentb,
    const float* a1in, const float* a1out, const float* a2in, const float* a2out,
    float* u1in, float* u1out, float* u2in, float* u2out,
    int* cntIn, int* cntOut, int N, int nb_bw, int nb_mk) {
  int b = blockIdx.x, tid = threadIdx.x;
  if (b < nb_bw) {
    dev_build_w(b * 256 + tid, W1in, W1out, W2in, W2out, Went, wcat1, wcat2, wentb);
  } else if (b < nb_bw + nb_mk) {
    dev_makeu((b - nb_bw) * 256 + tid, W1in, a1in, W1out, a1out, W2in, a2in, W2out, a2out,
              u1in, u1out, u2in, u2out);
  } else {
    int idx = (b - nb_bw - nb_mk) * 256 + tid;
    if (idx < N) cntIn[idx] = 0;
    else if (idx < 2 * N) cntOut[idx - N] = 0;
  }
}

__global__ __launch_bounds__(256) void MEGA1(
    const float* x, ushort_t* xnb, const float* u1in, const float* u1out,
    float* qA, float* qB, float* qC, float* qD, int N,
    const float* g, const float* u2in, const float* u2out,
    float* q3i1, float* q3o1, float* q3i2, float* q3o2, int Mn,
    const int* row, const int* col, int* cntIn, int* cntOut, int E,
    int nb_l2, int nb_qr) {
  int b = blockIdx.x, tid = threadIdx.x;
  if (b < nb_l2) {
    dev_l2norm_q(b, tid, x, xnb, u1in, u1out, qA, qB, qC, qD, N);
  } else if (b < nb_l2 + nb_qr) {
    dev_qrel2(b - nb_l2, tid, g, u1in, u1out, u2in, u2out, q3i1, q3o1, q3i2, q3o2, Mn);
  } else {
    dev_count(b - nb_l2 - nb_qr, tid, row, col, cntIn, cntOut, E);
  }
}

// ---- parallel 3-phase scan ----
__global__ __launch_bounds__(256) void k_scanA(const int* __restrict__ cntIn,
                                               const int* __restrict__ cntOut,
                                               int* __restrict__ part, int N, int nbc) {
  __shared__ int wsum[4];
  int b = blockIdx.x;
  const int* cnt = (b < nbc) ? cntIn : cntOut;
  int cb = (b < nbc) ? b : b - nbc;
  int idx = cb * 256 + threadIdx.x;
  int v = (idx < N) ? cnt[idx] : 0;
#pragma unroll
  for (int m = 1; m < 64; m <<= 1) v += __shfl_xor(v, m, 64);
  if ((threadIdx.x & 63) == 0) wsum[threadIdx.x >> 6] = v;
  __syncthreads();
  if (threadIdx.x == 0) part[b] = wsum[0] + wsum[1] + wsum[2] + wsum[3];
}

__global__ __launch_bounds__(256) void k_scanB(int* __restrict__ part,
                                               int* __restrict__ rsIn, int* __restrict__ rsOut,
                                               int nbc, int N) {
  __shared__ int buf[512];
  int t = threadIdx.x;
  buf[t]       = (t < nbc) ? part[t] : 0;
  buf[256 + t] = (t < nbc) ? part[nbc + t] : 0;
  __syncthreads();
  for (int off = 1; off < 256; off <<= 1) {
    int v0 = (t >= off) ? buf[t - off] : 0;
    int v1 = (t >= off) ? buf[256 + t - off] : 0;
    __syncthreads();
    buf[t] += v0; buf[256 + t] += v1;
    __syncthreads();
  }
  if (t < nbc) {
    part[t]       = (t == 0) ? 0 : buf[t - 1];
    part[nbc + t] = (t == 0) ? 0 : buf[256 + t - 1];
  }
  if (t == 0) { rsIn[N] = buf[nbc - 1]; rsOut[N] = buf[256 + nbc - 1]; }
}

__global__ __launch_bounds__(256) void k_scanC(const int* __restrict__ cntIn,
                                               const int* __restrict__ cntOut,
                                               const int* __restrict__ part,
                                               int* __restrict__ rsIn, int* __restrict__ rsOut,
                                               int* __restrict__ posIn, int* __restrict__ posOut,
                                               int N, int nbc) {
  __shared__ int buf[256];
  int b = blockIdx.x;
  const int* cnt = (b < nbc) ? cntIn : cntOut;
  int* rs  = (b < nbc) ? rsIn : rsOut;
  int* pos = (b < nbc) ? posIn : posOut;
  int cb = (b < nbc) ? b : b - nbc;
  int base = part[b];
  int t = threadIdx.x;
  int idx = cb * 256 + t;
  buf[t] = (idx < N) ? cnt[idx] : 0;
  __syncthreads();
  for (int off = 1; off < 256; off <<= 1) {
    int v = (t >= off) ? buf[t - off] : 0;
    __syncthreads();
    buf[t] += v;
    __syncthreads();
  }
  if (idx < N) {
    int excl = base + ((t == 0) ? 0 : buf[t - 1]);
    rs[idx] = excl; pos[idx] = excl;
  }
}

__global__ void k_fill(const int* __restrict__ row, const int* __restrict__ col,
                       const int* __restrict__ ety,
                       int* __restrict__ posIn, int* __restrict__ posOut,
                       int2* __restrict__ pinIn, int2* __restrict__ pinOut, int E) {
  int e = blockIdx.x * blockDim.x + threadIdx.x;
  if (e >= E) return;
  int r = row[e], c = col[e], tt = ety[e];
  int p = atomicAdd(&posIn[c], 1);
  pinIn[p] = make_int2(r, tt);
  int q = atomicAdd(&posOut[r], 1);
  pinOut[q] = make_int2(c, tt);
}

__global__ __launch_bounds__(256) void MEGA2(
    const ushort_t* xnb, const ushort_t* wcat1,
    uchar_t* PA8, ushort_t* PBb, ushort_t* PCb, uchar_t* PD8, int N,
    const float* g, const float* W1in200, const float* W1out200,
    const float* b1in, const float* b1out, ushort_t* P3ib, ushort_t* P3ob,
    const float* W2in400, const float* W2out400,
    const float* b2in, const float* b2out, ushort_t* P3ib2, ushort_t* P3ob2, int Mn,
    const ushort_t* wentb, const float* bent, ushort_t* hentb,
    const float* Wrel, const float* brel, float* outg,
    int nb_mf, int nb_gm, int nb_we) {
  __shared__ float4 shbuf4[1024];
  ushort_t* smA = (ushort_t*)shbuf4;
  ushort_t* smB = smA + 64 * 64;
  float4 (*As)[25] = (float4(*)[25])shbuf4;
  int b = blockIdx.x, tid = threadIdx.x;
  if (b < nb_mf) {
    dev_mfma(b % 13, b / 13, tid, smA, smB, xnb, 128, wcat1, 128, N, 800, 200, nullptr,
             nullptr, nullptr, PBb, PCb, nullptr, PA8, PD8);
  } else if ((b -= nb_mf) < nb_gm) {
    dev_gemm_multi<2, 1>(b & 3, b >> 2, tid, As, g, 100, W1in200, W1out200, 300,
                         b1in, b1out, P3ib, P3ob, Mn);
  } else if ((b -= nb_gm) < nb_gm) {
    dev_gemm_multi<2, 1>(b & 3, b >> 2, tid, As, g, 100, W2in400, W2out400, 500,
                         b2in, b2out, P3ib2, P3ob2, Mn);
  } else if ((b -= nb_gm) < nb_we) {
    dev_mfma(b & 3, b >> 2, tid, smA, smB, xnb, 128, wentb, 128, N, 200, 200, bent,
             nullptr, hentb, nullptr, nullptr, nullptr, nullptr, nullptr);
  } else {
    b -= nb_we;
    dev_gemm_multi<1, 0>(b & 3, b >> 2, tid, As, g, 100, Wrel, nullptr, 100,
                         brel, nullptr, outg, nullptr, Mn);
  }
}

// MEGA3: pure layer-2 MFMA GEMM
__global__ __launch_bounds__(256) void MEGA3(
    const ushort_t* h1b, const ushort_t* wcat2,
    uchar_t* PA8, ushort_t* PBb, ushort_t* PCb, uchar_t* PD8, int N) {
  __shared__ float4 shbuf4[1024];
  ushort_t* smA = (ushort_t*)shbuf4;
  ushort_t* smB = smA + 64 * 64;
  dev_mfma(blockIdx.x % 13, blockIdx.x / 13, threadIdx.x, smA, smB, h1b, 256, wcat2, 256,
           N, 800, 200, nullptr, nullptr, nullptr, PBb, PCb, nullptr, PA8, PD8);
}

// ---------------- fused per-node attention: inline e-values + LDS record broadcast ----------------
__global__ void k_node_att(const int2* __restrict__ pinIn, const int* __restrict__ rsIn,
                           const int2* __restrict__ pinOut, const int* __restrict__ rsOut,
                           const uchar_t* __restrict__ PA8, const ushort_t* __restrict__ PBb,
                           const ushort_t* __restrict__ PCb, const uchar_t* __restrict__ PD8,
                           const ushort_t* __restrict__ P3ib, const ushort_t* __restrict__ P3ob,
                           const float* __restrict__ qAin, const float* __restrict__ qBin,
                           const float* __restrict__ qCin, const float* __restrict__ qDin,
                           const float* __restrict__ q3i, const float* __restrict__ q3o,
                           const float* __restrict__ Wg, const float* __restrict__ bg,
                           const float* __restrict__ u2in, const float* __restrict__ u2out,
                           float* __restrict__ qAo, float* __restrict__ qBo,
                           float* __restrict__ qCo, float* __restrict__ qDo,
                           ushort_t* __restrict__ Hb,
                           const ushort_t* __restrict__ hentb, float* __restrict__ outp, int N) {
  __shared__ float4 sRecI[4][64];
  __shared__ float4 sRecO[4][64];
  int wv = threadIdx.x >> 6;
  int wid  = (int)((blockIdx.x * (unsigned)blockDim.x + threadIdx.x) >> 6);
  int lane = threadIdx.x & 63;
  if (wid >= N) return;
  int n = wid;
  int half = lane >> 5, i = lane & 31;
  bool act = i < 25;
  int j = half * 100 + i * 4;
  int sIn = rsIn[n], degIn = rsIn[n + 1] - sIn;
  int sOut = rsOut[n], degOut = rsOut[n + 1] - sOut;
  float2 qBn = *(const float2*)(qBin + (size_t)n * 2);
  float2 qCn = *(const float2*)(qCin + (size_t)n * 2);
  float4 accIn = {0.f, 0.f, 0.f, 0.f}, accOut = {0.f, 0.f, 0.f, 0.f};
  float dI0 = 0.f, dI1 = 0.f, dO0 = 0.f, dO1 = 0.f;
  int mx = max(degIn, degOut);
  for (int b = 0; b < mx; b += 64) {
    int l = b + lane;
    if (l < degIn) {
      int2 pt = pinIn[sIn + l];
      float2 qp = *(const float2*)(qAin + (size_t)pt.x * 2);
      float2 q3 = *(const float2*)(q3i + (size_t)pt.y * 2);
      float a0 = qp.x + qBn.x + q3.x, a1 = qp.y + qBn.y + q3.y;
      float e0 = expf(-(a0 > 0.f ? a0 : NSLOPE * a0));
      float e1 = expf(-(a1 > 0.f ? a1 : NSLOPE * a1));
      dI0 += e0; dI1 += e1;
      float4 rc = {e0, e1, __int_as_float(pt.x), __int_as_float(pt.y)};
      sRecI[wv][lane] = rc;
    }
    if (l < degOut) {
      int2 pt = pinOut[sOut + l];
      float2 qp = *(const float2*)(qDin + (size_t)pt.x * 2);
      float2 q3 = *(const float2*)(q3o + (size_t)pt.y * 2);
      float b0 = qCn.x + qp.x + q3.x, b1 = qCn.y + qp.y + q3.y;
      float e0 = expf(-(b0 > 0.f ? b0 : NSLOPE * b0));
      float e1 = expf(-(b1 > 0.f ? b1 : NSLOPE * b1));
      dO0 += e0; dO1 += e1;
      float4 rc = {e0, e1, __int_as_float(pt.x), __int_as_float(pt.y)};
      sRecO[wv][lane] = rc;
    }
    int mI = degIn - b;  if (mI > 64) mI = 64;
    int mO = degOut - b; if (mO > 64) mO = 64;
    int m2 = max(mI, mO);
    for (int jj = 0; jj < m2; ++jj) {
      if (act && jj < mI) {
        float4 rc = sRecI[wv][jj];
        int rI = __float_as_int(rc.z), tI = __float_as_int(rc.w);
        float wgt = half ? rc.y : rc.x;
        int paw = *(const int*)(PA8 + (size_t)rI * 200 + j);
        ushort4 p3 = *(const ushort4*)(P3ib + (size_t)tI * 200 + j);
        accIn.x += wgt * (__builtin_amdgcn_cvt_f32_fp8(paw, 0) + bf2f(p3.x));
        accIn.y += wgt * (__builtin_amdgcn_cvt_f32_fp8(paw, 1) + bf2f(p3.y));
        accIn.z += wgt * (__builtin_amdgcn_cvt_f32_fp8(paw, 2) + bf2f(p3.z));
        accIn.w += wgt * (__builtin_amdgcn_cvt_f32_fp8(paw, 3) + bf2f(p3.w));
      }
      if (act && jj < mO) {
        float4 rc = sRecO[wv][jj];
        int rO = __float_as_int(rc.z), tO = __float_as_int(rc.w);
        float wgt = half ? rc.y : rc.x;
        int pdw = *(const int*)(PD8 + (size_t)rO * 200 + j);
        ushort4 p3 = *(const ushort4*)(P3ob + (size_t)tO * 200 + j);
        accOut.x += wgt * (__builtin_amdgcn_cvt_f32_fp8(pdw, 0) + bf2f(p3.x));
        accOut.y += wgt * (__builtin_amdgcn_cvt_f32_fp8(pdw, 1) + bf2f(p3.y));
        accOut.z += wgt * (__builtin_amdgcn_cvt_f32_fp8(pdw, 2) + bf2f(p3.z));
        accOut.w += wgt * (__builtin_amdgcn_cvt_f32_fp8(pdw, 3) + bf2f(p3.w));
      }
    }
  }
#pragma unroll
  for (int m = 1; m < 64; m <<= 1) {
    dI0 += __shfl_xor(dI0, m, 64); dI1 += __shfl_xor(dI1, m, 64);
    dO0 += __shfl_xor(dO0, m, 64); dO1 += __shfl_xor(dO1, m, 64);
  }
  float4 hin = {0.f, 0.f, 0.f, 0.f}, hout = {0.f, 0.f, 0.f, 0.f};
  if (degIn > 0 && act) {
    float invd = 1.f / (half ? dI1 : dI0);
    ushort4 ps = *(const ushort4*)(PBb + (size_t)n * 200 + j);
    hin.x = elu1(bf2f(ps.x) + accIn.x * invd);
    hin.y = elu1(bf2f(ps.y) + accIn.y * invd);
    hin.z = elu1(bf2f(ps.z) + accIn.z * invd);
    hin.w = elu1(bf2f(ps.w) + accIn.w * invd);
  }
  if (degOut > 0 && act) {
    float invd = 1.f / (half ? dO1 : dO0);
    ushort4 ps = *(const ushort4*)(PCb + (size_t)n * 200 + j);
    hout.x = elu1(bf2f(ps.x) + accOut.x * invd);
    hout.y = elu1(bf2f(ps.y) + accOut.y * invd);
    hout.z = elu1(bf2f(ps.z) + accOut.z * invd);
    hout.w = elu1(bf2f(ps.w) + accOut.w * invd);
  }
  float gp = 0.f;
  if (act) {
    int k = i * 4;
    gp = Wg[k] * hin.x + Wg[k + 1] * hin.y + Wg[k + 2] * hin.z + Wg[k + 3] * hin.w +
         Wg[100 + k] * hout.x + Wg[100 + k + 1] * hout.y +
         Wg[100 + k + 2] * hout.z + Wg[100 + k + 3] * hout.w;
  }
#pragma unroll
  for (int m = 1; m < 32; m <<= 1) gp += __shfl_xor(gp, m, 32);
  float al = 1.f / (1.f + expf(-(gp + bg[0])));
  float4 he;
  he.x = elu1(al * hin.x + (1.f - al) * hout.x);
  he.y = elu1(al * hin.y + (1.f - al) * hout.y);
  he.z = elu1(al * hin.z + (1.f - al) * hout.z);
  he.w = elu1(al * hin.w + (1.f - al) * hout.w);
  float ss = he.x * he.x + he.y * he.y + he.z * he.z + he.w * he.w;
#pragma unroll
  for (int m = 1; m < 32; m <<= 1) ss += __shfl_xor(ss, m, 32);
  float inv = 1.f / fmaxf(sqrtf(ss), 1e-12f);
  float4 o = {he.x * inv, he.y * inv, he.z * inv, he.w * inv};
  if (Hb) {
    if (act) {
      ushort4 ov; ov.x = f2bf(o.x); ov.y = f2bf(o.y); ov.z = f2bf(o.z); ov.w = f2bf(o.w);
      *(ushort4*)(Hb + (size_t)n * 256 + j) = ov;
    } else {
      int pi = half * 7 + (i - 25);
      ushort4 z = {0, 0, 0, 0};
      *(ushort4*)(Hb + (size_t)n * 256 + 200 + pi * 4) = z;
    }
  }
  if (outp) {
    float4 v = {0.f, 0.f, 0.f, 0.f};
    if (act) {
      ushort4 hv = *(const ushort4*)(hentb + (size_t)n * 200 + j);
      v.x = bf2f(hv.x) + o.x; v.y = bf2f(hv.y) + o.y;
      v.z = bf2f(hv.z) + o.z; v.w = bf2f(hv.w) + o.w;
    }
    float s2 = v.x * v.x + v.y * v.y + v.z * v.z + v.w * v.w;
#pragma unroll
    for (int m = 1; m < 32; m <<= 1) s2 += __shfl_xor(s2, m, 32);
    float inv2 = 1.f / fmaxf(sqrtf(s2), 1e-12f);
    if (act) {
      float4 ov = {v.x * inv2, v.y * inv2, v.z * inv2, v.w * inv2};
      *(float4*)(outp + (size_t)n * 200 + j) = ov;
    }
  }
  if (u2in) {
    float4 ov = act ? o : make_float4(0.f, 0.f, 0.f, 0.f);
    float s[8];
#pragma unroll
    for (int h = 0; h < 2; ++h) {
      float4 uA = *(const float4*)(u2in + h * 500 + j);
      float4 uB = *(const float4*)(u2in + h * 500 + 200 + j);
      float4 uC = *(const float4*)(u2out + h * 500 + j);
      float4 uD = *(const float4*)(u2out + h * 500 + 200 + j);
      s[0 + h] = ov.x * uA.x + ov.y * uA.y + ov.z * uA.z + ov.w * uA.w;
      s[2 + h] = ov.x * uB.x + ov.y * uB.y + ov.z * uB.z + ov.w * uB.w;
      s[4 + h] = ov.x * uC.x + ov.y * uC.y + ov.z * uC.z + ov.w * uC.w;
      s[6 + h] = ov.x * uD.x + ov.y * uD.y + ov.z * uD.z + ov.w * uD.w;
    }
#pragma unroll
    for (int m = 1; m < 64; m <<= 1) {
#pragma unroll
      for (int ii = 0; ii < 8; ++ii) s[ii] += __shfl_xor(s[ii], m, 64);
    }
    if (lane == 0) {
      qAo[n * 2] = s[0]; qAo[n * 2 + 1] = s[1];
      qBo[n * 2] = s[2]; qBo[n * 2 + 1] = s[3];
      qCo[n * 2] = s[4]; qCo[n * 2 + 1] = s[5];
      qDo[n * 2] = s[6]; qDo[n * 2 + 1] = s[7];
    }
  }
}

extern "C" void kernel_launch(void* const* d_in, const int* in_sizes, int n_in,
                              void* d_out, int out_size, void* d_ws, size_t ws_size,
                              hipStream_t stream) {
  const float* x    = (const float*)d_in[0];
  const float* g    = (const float*)d_in[1];
  const float* W1in = (const float*)d_in[2];
  const float* b1in = (const float*)d_in[3];
  const float* a1in = (const float*)d_in[4];
  const float* W1out= (const float*)d_in[5];
  const float* b1out= (const float*)d_in[6];
  const float* a1out= (const float*)d_in[7];
  const float* Wa1  = (const float*)d_in[8];
  const float* ba1  = (const float*)d_in[9];
  const float* W2in = (const float*)d_in[10];
  const float* b2in = (const float*)d_in[11];
  const float* a2in = (const float*)d_in[12];
  const float* W2out= (const float*)d_in[13];
  const float* b2out= (const float*)d_in[14];
  const float* a2out= (const float*)d_in[15];
  const float* Wa2  = (const float*)d_in[16];
  const float* ba2  = (const float*)d_in[17];
  const float* Went = (const float*)d_in[18];
  const float* bent = (const float*)d_in[19];
  const float* Wrel = (const float*)d_in[20];
  const float* brel = (const float*)d_in[21];
  const int*  eidx  = (const int*)d_in[22];
  const int*  ety   = (const int*)d_in[23];

  const int N = in_sizes[0] / 100;
  const int M = in_sizes[1] / 100;
  const int E = in_sizes[23];
  const int* row = eidx;
  const int* col = eidx + E;
  float* out = (float*)d_out;

  float* ws = (float*)d_ws;
  size_t off = 0;
  auto alloc = [&](size_t nf) { float* p = ws + off; off += (nf + 3) & ~(size_t)3; return p; };
  int2* pinIn  = (int2*)alloc((size_t)E * 2);
  int2* pinOut = (int2*)alloc((size_t)E * 2);
  uchar_t* PA8 = (uchar_t*)alloc((size_t)N * 50);
  uchar_t* PD8 = (uchar_t*)alloc((size_t)N * 50);
  ushort_t* PBb = (ushort_t*)alloc((size_t)N * 100);
  ushort_t* PCb = (ushort_t*)alloc((size_t)N * 100);
  ushort_t* P3ib = (ushort_t*)alloc((size_t)M * 100);
  ushort_t* P3ob = (ushort_t*)alloc((size_t)M * 100);
  ushort_t* P3ib2 = (ushort_t*)alloc((size_t)M * 100);
  ushort_t* P3ob2 = (ushort_t*)alloc((size_t)M * 100);
  ushort_t* xnb = (ushort_t*)alloc((size_t)N * 64);
  ushort_t* h1b = (ushort_t*)alloc((size_t)N * 128);
  ushort_t* hentb = (ushort_t*)alloc((size_t)N * 100);
  ushort_t* wcat1 = (ushort_t*)alloc((size_t)832 * 64);
  ushort_t* wcat2 = (ushort_t*)alloc((size_t)832 * 128);
  ushort_t* wentb = (ushort_t*)alloc((size_t)256 * 64);
  float* qA  = alloc((size_t)N * 2);
  float* qB  = alloc((size_t)N * 2);
  float* qC  = alloc((size_t)N * 2);
  float* qD  = alloc((size_t)N * 2);
  float* qA2 = alloc((size_t)N * 2);
  float* qB2 = alloc((size_t)N * 2);
  float* qC2 = alloc((size_t)N * 2);
  float* qD2 = alloc((size_t)N * 2);
  float* q3i1 = alloc((size_t)M * 2);
  float* q3o1 = alloc((size_t)M * 2);
  float* q3i2 = alloc((size_t)M * 2);
  float* q3o2 = alloc((size_t)M * 2);
  float* u1in  = alloc(600);
  float* u1out = alloc(600);
  float* u2in  = alloc(1000);
  float* u2out = alloc(1000);
  int* cntIn  = (int*)alloc((size_t)N);
  int* cntOut = (int*)alloc((size_t)N);
  int* rsIn   = (int*)alloc((size_t)N + 1);
  int* rsOut  = (int*)alloc((size_t)N + 1);
  int* posIn  = (int*)alloc((size_t)N);
  int* posOut = (int*)alloc((size_t)N);
  int* part   = (int*)alloc((size_t)512);

  const int gN4 = (N + 3) / 4;
  const int gE  = (E + 255) / 256;
  const int mT  = (N + 63) / 64;
  const int nbc = (N + 255) / 256;

  const int nb_bw = (832 * 128 + 832 * 256 + 256 * 128 + 255) / 256;
  const int nb_mk = 13;
  const int nb_z  = (2 * N + 255) / 256;
  const int nb_l2 = gN4;
  const int nb_qr = (2 * M + 3) / 4;
  const int nb_mf = 13 * mT;
  const int nb_gm = 4 * ((M + 31) / 32);
  const int nb_we = 4 * mT;

  MEGA0<<<nb_bw + nb_mk + nb_z, 256, 0, stream>>>(
      W1in, W1out, W2in, W2out, Went, wcat1, wcat2, wentb,
      a1in, a1out, a2in, a2out, u1in, u1out, u2in, u2out,
      cntIn, cntOut, N, nb_bw, nb_mk);

  MEGA1<<<nb_l2 + nb_qr + gE, 256, 0, stream>>>(
      x, xnb, u1in, u1out, qA, qB, qC, qD, N,
      g, u2in, u2out, q3i1, q3o1, q3i2, q3o2, M,
      row, col, cntIn, cntOut, E, nb_l2, nb_qr);

  k_scanA<<<2 * nbc, 256, 0, stream>>>(cntIn, cntOut, part, N, nbc);
  k_scanB<<<1, 256, 0, stream>>>(part, rsIn, rsOut, nbc, N);
  k_scanC<<<2 * nbc, 256, 0, stream>>>(cntIn, cntOut, part, rsIn, rsOut, posIn, posOut, N, nbc);
  k_fill<<<gE, 256, 0, stream>>>(row, col, ety, posIn, posOut, pinIn, pinOut, E);

  MEGA2<<<nb_mf + nb_gm * 3 + nb_we, 256, 0, stream>>>(
      xnb, wcat1, PA8, PBb, PCb, PD8, N,
      g, W1in + 200, W1out + 200, b1in, b1out, P3ib, P3ob,
      W2in + 400, W2out + 400, b2in, b2out, P3ib2, P3ob2, M,
      wentb, bent, hentb, Wrel, brel, out + (size_t)N * 200,
      nb_mf, nb_gm, nb_we);

  k_node_att<<<gN4, 256, 0, stream>>>(pinIn, rsIn, pinOut, rsOut,
                                      PA8, PBb, PCb, PD8, P3ib, P3ob,
                                      qA, qB, qC, qD, q3i1, q3o1, Wa1, ba1,
                                      u2in, u2out, qA2, qB2, qC2, qD2,
                                      h1b, nullptr, nullptr, N);

  MEGA3<<<nb_mf, 256, 0, stream>>>(h1b, wcat2, PA8, PBb, PCb, PD8, N);

  k_node_att<<<gN4, 256, 0, stream>>>(pinIn, rsIn, pinOut, rsOut,
                                      PA8, PBb, PCb, PD8, P3ib2, P3ob2,
                                      qA2, qB2, qC2, qD2, q3i2, q3o2, Wa2, ba2,
                                      nullptr, nullptr, nullptr, nullptr, nullptr, nullptr,
                                      nullptr, hentb, out, N);
}